// Round 1
// baseline (1509.093 us; speedup 1.0000x reference)
//
#include <hip/hip_runtime.h>
#include <math.h>

// ---------------------------------------------------------------------------
// GIN network: 3x GINConv (sum-aggregate + 2-layer MLP + ReLU) + fc1+ReLU +
// fc2+sigmoid.  N=100000 nodes, E=1.6M edges, D=128.
//
// Strategy this round (fp32 correctness baseline):
//  - Build CSR (dst-bucketed src lists) once per call: count -> scan -> fill.
//  - Aggregation = gather per node (1 wave/node, float2 per lane), no float
//    atomics. h fits in L3 (51 MB) so gathers are cache-served.
//  - GEMMs: fp32 vector SGEMM, 128x128 tile, K=128 fully LDS-resident,
//    pitch-132 LDS to avoid bank conflicts, strided 8x8 micro-tile.
//  - fc1+fc2+sigmoid fused in one kernel (no hidden buffer materialized).
// ---------------------------------------------------------------------------

__global__ void count_kernel(const int* __restrict__ dst, int* __restrict__ deg, int E) {
    int stride = gridDim.x * blockDim.x;
    for (int e = blockIdx.x * blockDim.x + threadIdx.x; e < E; e += stride)
        atomicAdd(&deg[dst[e]], 1);
}

__global__ __launch_bounds__(1024) void scan_kernel(const int* __restrict__ deg,
                                                    int* __restrict__ offs, int n) {
    __shared__ int sums[1024];
    int t = threadIdx.x;
    int chunk = (n + 1023) >> 10;
    int lo = t * chunk;
    int hi = min(lo + chunk, n);
    int s = 0;
    for (int i = lo; i < hi; ++i) s += deg[i];
    sums[t] = s;
    __syncthreads();
    // Hillis-Steele inclusive scan over the 1024 per-thread sums
    for (int d = 1; d < 1024; d <<= 1) {
        int v = (t >= d) ? sums[t - d] : 0;
        __syncthreads();
        sums[t] += v;
        __syncthreads();
    }
    int base = (t > 0) ? sums[t - 1] : 0;
    for (int i = lo; i < hi; ++i) { offs[i] = base; base += deg[i]; }
    if (t == 1023) offs[n] = sums[1023];
}

__global__ void fill_kernel(const int* __restrict__ src, const int* __restrict__ dst,
                            int* __restrict__ cursor, int* __restrict__ col, int E) {
    int stride = gridDim.x * blockDim.x;
    for (int e = blockIdx.x * blockDim.x + threadIdx.x; e < E; e += stride) {
        int d = dst[e];
        int p = atomicAdd(&cursor[d], 1);
        col[p] = src[e];
    }
}

// z[n] = (1+eps)*h[n] + sum_{s in nbrs(n)} h[s]   (one 64-lane wave per node,
// each lane owns 2 consecutive feats -> 512B coalesced row reads)
__global__ void agg_kernel(const float* __restrict__ h, const int* __restrict__ offs,
                           const int* __restrict__ col, const float* __restrict__ epsp,
                           float* __restrict__ z, int n) {
    int wid = blockIdx.x * (blockDim.x >> 6) + (threadIdx.x >> 6);
    if (wid >= n) return;
    int lane = threadIdx.x & 63;
    float e1 = 1.0f + epsp[0];
    float2 acc = *(const float2*)(h + (size_t)wid * 128 + lane * 2);
    acc.x *= e1; acc.y *= e1;
    int lo = offs[wid], hi = offs[wid + 1];
    for (int e = lo; e < hi; ++e) {
        int s = col[e];
        float2 v = *(const float2*)(h + (size_t)s * 128 + lane * 2);
        acc.x += v.x; acc.y += v.y;
    }
    *(float2*)(z + (size_t)wid * 128 + lane * 2) = acc;
}

// C[M x NCOL] = relu(A[M x 128] @ W[NCOL x 128]^T + bias)
// FC2 variant: instead of storing C, fold with fc2 (64->1) + sigmoid -> out.
// 256 threads, 128-row tile, K=128 fully resident in LDS.
// pitch 132: strided micro-tile (rows ty+16i, cols tx+16j) keeps LDS reads
// at <=2-way bank aliasing (free on CDNA4).
template <int NJ, bool FC2>
__global__ __launch_bounds__(256, 1) void gemm_kernel(
    const float* __restrict__ A, const float* __restrict__ W,
    const float* __restrict__ bias, float* __restrict__ C, int M,
    const float* __restrict__ fc2w, const float* __restrict__ fc2b,
    float* __restrict__ out) {
    constexpr int NCOL = NJ * 16;
    constexpr int PITCH = 132;
    __shared__ float Alds[128 * PITCH];
    __shared__ float Wlds[NCOL * PITCH];
    __shared__ float Red[FC2 ? 128 * 17 : 1];

    const int tid = threadIdx.x;
    const int ty = tid & 15;
    const int tx = tid >> 4;
    const int m0 = blockIdx.x * 128;

    // stage W (row-major [o][k]) into LDS
    for (int idx = tid; idx < NCOL * 32; idx += 256) {
        int r = idx >> 5, c = (idx & 31) << 2;
        *(float4*)&Wlds[r * PITCH + c] = *(const float4*)&W[r * 128 + c];
    }
    // stage A tile
    for (int idx = tid; idx < 128 * 32; idx += 256) {
        int r = idx >> 5, c = (idx & 31) << 2;
        int m = m0 + r;
        float4 v = make_float4(0.f, 0.f, 0.f, 0.f);
        if (m < M) v = *(const float4*)&A[(size_t)m * 128 + c];
        *(float4*)&Alds[r * PITCH + c] = v;
    }
    __syncthreads();

    float acc[8][NJ];
#pragma unroll
    for (int i = 0; i < 8; ++i)
#pragma unroll
        for (int j = 0; j < NJ; ++j) acc[i][j] = 0.f;

#pragma unroll 2
    for (int k = 0; k < 128; k += 4) {
        float4 a[8], w[NJ];
#pragma unroll
        for (int i = 0; i < 8; ++i)
            a[i] = *(const float4*)&Alds[(ty + 16 * i) * PITCH + k];
#pragma unroll
        for (int j = 0; j < NJ; ++j)
            w[j] = *(const float4*)&Wlds[(tx + 16 * j) * PITCH + k];
#pragma unroll
        for (int i = 0; i < 8; ++i)
#pragma unroll
            for (int j = 0; j < NJ; ++j) {
                acc[i][j] += a[i].x * w[j].x;
                acc[i][j] += a[i].y * w[j].y;
                acc[i][j] += a[i].z * w[j].z;
                acc[i][j] += a[i].w * w[j].w;
            }
    }

    if (!FC2) {
        __syncthreads();  // done reading Alds; reuse as output staging
#pragma unroll
        for (int i = 0; i < 8; ++i)
#pragma unroll
            for (int j = 0; j < NJ; ++j) {
                int r = ty + 16 * i, o = tx + 16 * j;
                float c = acc[i][j] + bias[o];
                Alds[r * PITCH + o] = fmaxf(c, 0.f);
            }
        __syncthreads();
        for (int idx = tid; idx < 128 * 32; idx += 256) {
            int r = idx >> 5, c = (idx & 31) << 2;
            int m = m0 + r;
            if (m < M) *(float4*)&C[(size_t)m * 128 + c] = *(const float4*)&Alds[r * PITCH + c];
        }
    } else {
        // hidden = relu(acc + b1); logit partial = hidden . fc2w
        float partial[8];
#pragma unroll
        for (int i = 0; i < 8; ++i) partial[i] = 0.f;
#pragma unroll
        for (int j = 0; j < NJ; ++j) {
            int o = tx + 16 * j;
            float bo = bias[o];
            float f2 = fc2w[o];
#pragma unroll
            for (int i = 0; i < 8; ++i) {
                float hcol = fmaxf(acc[i][j] + bo, 0.f);
                partial[i] += hcol * f2;
            }
        }
#pragma unroll
        for (int i = 0; i < 8; ++i) Red[(ty + 16 * i) * 17 + tx] = partial[i];
        __syncthreads();
        if (tid < 128) {
            float s = 0.f;
#pragma unroll
            for (int q = 0; q < 16; ++q) s += Red[tid * 17 + q];
            s += fc2b[0];
            int m = m0 + tid;
            if (m < M) out[m] = 1.f / (1.f + expf(-s));
        }
    }
}

extern "C" void kernel_launch(void* const* d_in, const int* in_sizes, int n_in,
                              void* d_out, int out_size, void* d_ws, size_t ws_size,
                              hipStream_t stream) {
    const float* x = (const float*)d_in[0];
    const int* ei = (const int*)d_in[1];
    const int N = in_sizes[0] / 128;
    const int E = in_sizes[1] / 2;
    const int* src = ei;
    const int* dst = ei + E;

    const float* w1[3] = {(const float*)d_in[2], (const float*)d_in[7], (const float*)d_in[12]};
    const float* b1[3] = {(const float*)d_in[3], (const float*)d_in[8], (const float*)d_in[13]};
    const float* w2[3] = {(const float*)d_in[4], (const float*)d_in[9], (const float*)d_in[14]};
    const float* b2[3] = {(const float*)d_in[5], (const float*)d_in[10], (const float*)d_in[15]};
    const float* eps[3] = {(const float*)d_in[6], (const float*)d_in[11], (const float*)d_in[16]};
    const float* fc1w = (const float*)d_in[17];
    const float* fc1b = (const float*)d_in[18];
    const float* fc2w = (const float*)d_in[19];
    const float* fc2b = (const float*)d_in[20];

    // workspace carve
    char* ws = (char*)d_ws;
    size_t p = 0;
    auto carve = [&](size_t bytes) -> char* {
        char* r = ws + p;
        p = (p + bytes + 255) & ~(size_t)255;
        return r;
    };
    int* offs = (int*)carve((size_t)(N + 1) * 4);
    int* cursor = (int*)carve((size_t)N * 4);
    int* col = (int*)carve((size_t)E * 4);
    float* A = (float*)carve((size_t)N * 128 * 4);
    float* B = (float*)carve((size_t)N * 128 * 4);
    float* C = (float*)carve((size_t)N * 128 * 4);
    (void)ws_size;

    // ---- build CSR (once; shared by all 3 convs) ----
    hipMemsetAsync(cursor, 0, (size_t)N * 4, stream);
    count_kernel<<<1024, 256, 0, stream>>>(dst, cursor, E);
    scan_kernel<<<1, 1024, 0, stream>>>(cursor, offs, N);
    hipMemcpyAsync(cursor, offs, (size_t)N * 4, hipMemcpyDeviceToDevice, stream);
    fill_kernel<<<1024, 256, 0, stream>>>(src, dst, cursor, col, E);

    const int aggGrid = (N + 3) / 4;       // 4 waves (nodes) per 256-thr block
    const int gemmGrid = (N + 127) / 128;  // 128-row tiles

    const float* hin = x;
    for (int i = 0; i < 3; ++i) {
        agg_kernel<<<aggGrid, 256, 0, stream>>>(hin, offs, col, eps[i], B, N);
        gemm_kernel<8, false><<<gemmGrid, 256, 0, stream>>>(B, w1[i], b1[i], C, N,
                                                            nullptr, nullptr, nullptr);
        gemm_kernel<8, false><<<gemmGrid, 256, 0, stream>>>(C, w2[i], b2[i], A, N,
                                                            nullptr, nullptr, nullptr);
        hin = A;
    }
    // fused fc1 (128->64, relu) + fc2 (64->1) + sigmoid
    gemm_kernel<4, true><<<gemmGrid, 256, 0, stream>>>(A, fc1w, fc1b, nullptr, N,
                                                       fc2w, fc2b, (float*)d_out);
}

// Round 2
// 663.470 us; speedup vs baseline: 2.2745x; 2.2745x over previous
//
#include <hip/hip_runtime.h>
#include <math.h>

// ---------------------------------------------------------------------------
// GIN network on MI355X — round 2: f16 features + f16 MFMA GEMMs.
//  - CSR build (count/scan/fill) unchanged (once per call, shared by 3 convs).
//  - h stored as _Float16 rows (256 B): halves gather bytes in aggregation.
//  - GEMMs: mfma_f32_16x16x32_f16, 128-row tile, K=128 LDS-resident,
//    global_load_lds(16B) staging with XOR-swizzled source (rule #21),
//    swizzled ds_read_b128 fragment loads (2-way conflicts only).
//  - fc1+relu+fc2+sigmoid fused in MFMA epilogue (no hidden buffer).
// ---------------------------------------------------------------------------

using f16   = _Float16;
using f16x2 = __attribute__((ext_vector_type(2))) _Float16;
using f16x4 = __attribute__((ext_vector_type(4))) _Float16;
using f16x8 = __attribute__((ext_vector_type(8))) _Float16;
using f32x4 = __attribute__((ext_vector_type(4))) float;

__device__ inline void glds16(const void* g, void* l) {
    __builtin_amdgcn_global_load_lds(
        (const __attribute__((address_space(1))) void*)g,
        (__attribute__((address_space(3))) void*)l, 16, 0, 0);
}

// ---------------- CSR build ----------------
__global__ void count_kernel(const int* __restrict__ dst, int* __restrict__ deg, int E) {
    int stride = gridDim.x * blockDim.x;
    for (int e = blockIdx.x * blockDim.x + threadIdx.x; e < E; e += stride)
        atomicAdd(&deg[dst[e]], 1);
}

__global__ __launch_bounds__(1024) void scan_kernel(const int* __restrict__ deg,
                                                    int* __restrict__ offs, int n) {
    __shared__ int sums[1024];
    int t = threadIdx.x;
    int chunk = (n + 1023) >> 10;
    int lo = t * chunk;
    int hi = min(lo + chunk, n);
    int s = 0;
    for (int i = lo; i < hi; ++i) s += deg[i];
    sums[t] = s;
    __syncthreads();
    for (int d = 1; d < 1024; d <<= 1) {
        int v = (t >= d) ? sums[t - d] : 0;
        __syncthreads();
        sums[t] += v;
        __syncthreads();
    }
    int base = (t > 0) ? sums[t - 1] : 0;
    for (int i = lo; i < hi; ++i) { offs[i] = base; base += deg[i]; }
    if (t == 1023) offs[n] = sums[1023];
}

__global__ void fill_kernel(const int* __restrict__ src, const int* __restrict__ dst,
                            int* __restrict__ cursor, int* __restrict__ col, int E) {
    int stride = gridDim.x * blockDim.x;
    for (int e = blockIdx.x * blockDim.x + threadIdx.x; e < E; e += stride) {
        int d = dst[e];
        int p = atomicAdd(&cursor[d], 1);
        col[p] = src[e];
    }
}

// ---------------- fp32 -> f16 conversions ----------------
__global__ void cvt4_kernel(const float* __restrict__ in, f16* __restrict__ out, int nq) {
    int stride = gridDim.x * blockDim.x;
    for (int i = blockIdx.x * blockDim.x + threadIdx.x; i < nq; i += stride) {
        float4 v = *(const float4*)(in + (size_t)i * 4);
        f16x4 o = {(f16)v.x, (f16)v.y, (f16)v.z, (f16)v.w};
        *(f16x4*)(out + (size_t)i * 4) = o;
    }
}

struct CvtPack {
    const float* s[7];
    f16* d[7];
    int nq[7];
};
__global__ void cvt_pack_kernel(CvtPack p) {
    int seg = blockIdx.y;
    int nq = p.nq[seg];
    const float* in = p.s[seg];
    f16* out = p.d[seg];
    int stride = gridDim.x * blockDim.x;
    for (int i = blockIdx.x * blockDim.x + threadIdx.x; i < nq; i += stride) {
        float4 v = *(const float4*)(in + (size_t)i * 4);
        f16x4 o = {(f16)v.x, (f16)v.y, (f16)v.z, (f16)v.w};
        *(f16x4*)(out + (size_t)i * 4) = o;
    }
}

// ---------------- aggregation: z[n] = (1+eps)*h[n] + sum h[nbr] ----------------
// One 64-lane wave per node, lane owns 2 feats (f16x2 = 4B). Unroll x4 for MLP.
__global__ __launch_bounds__(256) void agg_kernel(const f16* __restrict__ h,
                                                  const int* __restrict__ offs,
                                                  const int* __restrict__ col,
                                                  const float* __restrict__ epsp,
                                                  f16* __restrict__ z, int n) {
    int wid = blockIdx.x * 4 + (threadIdx.x >> 6);
    if (wid >= n) return;
    int lane = threadIdx.x & 63;
    const f16x2* hp = (const f16x2*)h;  // row stride = 64 f16x2
    float e1 = 1.0f + epsp[0];
    f16x2 self = hp[(size_t)wid * 64 + lane];
    float ax = (float)self.x * e1, ay = (float)self.y * e1;
    int lo = offs[wid], hi = offs[wid + 1];
    int e = lo;
    for (; e + 4 <= hi; e += 4) {
        int s0 = col[e], s1 = col[e + 1], s2 = col[e + 2], s3 = col[e + 3];
        f16x2 v0 = hp[(size_t)s0 * 64 + lane];
        f16x2 v1 = hp[(size_t)s1 * 64 + lane];
        f16x2 v2 = hp[(size_t)s2 * 64 + lane];
        f16x2 v3 = hp[(size_t)s3 * 64 + lane];
        ax += (float)v0.x + (float)v1.x + (float)v2.x + (float)v3.x;
        ay += (float)v0.y + (float)v1.y + (float)v2.y + (float)v3.y;
    }
    for (; e < hi; ++e) {
        f16x2 v = hp[(size_t)col[e] * 64 + lane];
        ax += (float)v.x;
        ay += (float)v.y;
    }
    f16x2 o = {(f16)ax, (f16)ay};
    ((f16x2*)z)[(size_t)wid * 64 + lane] = o;
}

// ---------------- MFMA GEMM: C = relu(A[Mx128] @ W[NCOLx128]^T + b) ----------
// FC variant: logit = relu(A@fc1^T+b) . fc2w + fc2b -> sigmoid -> out.
// 256 thr = 4 waves; wave w owns rows [w*32, w*32+32). K=128 LDS-resident.
// LDS content XOR-swizzled on 16B units: LDS[r][u] = G[r][u ^ (r&7)].
template <int NCOL, bool FC>
__global__ __launch_bounds__(256) void mfma_gemm_kernel(
    const f16* __restrict__ A, const f16* __restrict__ W,
    const float* __restrict__ bias, f16* __restrict__ C, int M,
    const float* __restrict__ fc2w, const float* __restrict__ fc2b,
    float* __restrict__ out) {
    constexpr int NJ = NCOL / 16;
    __shared__ __align__(16) f16 As[128 * 128];
    __shared__ __align__(16) f16 Ws[NCOL * 128];
    __shared__ float Red[FC ? 128 * 17 : 1];

    const int tid = threadIdx.x;
    const int w = tid >> 6, lane = tid & 63;
    const int frow = lane & 15, kgrp = lane >> 4;
    const int m0 = blockIdx.x * 128;

    // ---- stage A tile (128 rows x 256B): wave does 8 iters of 4 rows
    {
        int u = lane & 15;
        int rsub = lane >> 4;
#pragma unroll
        for (int i = 0; i < 8; ++i) {
            int rowbase = (w * 8 + i) * 4;
            int r = rowbase + rsub;
            int gr = m0 + r;
            if (gr >= M) gr = M - 1;
            glds16(A + (size_t)gr * 128 + ((u ^ (r & 7)) << 3), &As[rowbase * 128]);
        }
        // ---- stage W (NCOL rows): wave does NCOL/16 iters
#pragma unroll
        for (int i = 0; i < NCOL / 16; ++i) {
            int rowbase = (w * (NCOL / 16) + i) * 4;
            int r = rowbase + rsub;
            glds16(W + (size_t)r * 128 + ((u ^ (r & 7)) << 3), &Ws[rowbase * 128]);
        }
    }
    __syncthreads();

    f32x4 acc[2][NJ];
#pragma unroll
    for (int mi = 0; mi < 2; ++mi)
#pragma unroll
        for (int nj = 0; nj < NJ; ++nj) acc[mi][nj] = (f32x4){0.f, 0.f, 0.f, 0.f};

    const int arow0 = w * 32 + frow;
#pragma unroll
    for (int kk = 0; kk < 4; ++kk) {
        int kb = kk * 4 + kgrp;  // 16B-unit index along K
        f16x8 a[2], b[NJ];
#pragma unroll
        for (int mi = 0; mi < 2; ++mi) {
            int r = arow0 + mi * 16;
            a[mi] = *(const f16x8*)&As[r * 128 + ((kb ^ (r & 7)) << 3)];
        }
#pragma unroll
        for (int nj = 0; nj < NJ; ++nj) {
            int r = nj * 16 + frow;
            b[nj] = *(const f16x8*)&Ws[r * 128 + ((kb ^ (r & 7)) << 3)];
        }
#pragma unroll
        for (int mi = 0; mi < 2; ++mi)
#pragma unroll
            for (int nj = 0; nj < NJ; ++nj)
                acc[mi][nj] = __builtin_amdgcn_mfma_f32_16x16x32_f16(a[mi], b[nj],
                                                                     acc[mi][nj], 0, 0, 0);
    }

    float bv[NJ];
#pragma unroll
    for (int nj = 0; nj < NJ; ++nj) bv[nj] = bias[nj * 16 + frow];

    if (!FC) {
        __syncthreads();  // done reading As; reuse as output staging (linear)
#pragma unroll
        for (int mi = 0; mi < 2; ++mi)
#pragma unroll
            for (int nj = 0; nj < NJ; ++nj) {
                int row = w * 32 + mi * 16 + kgrp * 4;
                int colc = nj * 16 + frow;
#pragma unroll
                for (int r = 0; r < 4; ++r)
                    As[(row + r) * 128 + colc] = (f16)fmaxf(acc[mi][nj][r] + bv[nj], 0.f);
            }
        __syncthreads();
        for (int idx = tid; idx < 128 * 16; idx += 256) {
            int r = idx >> 4, u = idx & 15;
            int gm = m0 + r;
            if (gm < M)
                *(float4*)(C + (size_t)gm * 128 + u * 8) = *(const float4*)&As[r * 128 + u * 8];
        }
    } else {
        float f2[NJ];
#pragma unroll
        for (int nj = 0; nj < NJ; ++nj) f2[nj] = fc2w[nj * 16 + frow];
        float part[2][4];
#pragma unroll
        for (int mi = 0; mi < 2; ++mi)
#pragma unroll
            for (int r = 0; r < 4; ++r) part[mi][r] = 0.f;
#pragma unroll
        for (int mi = 0; mi < 2; ++mi)
#pragma unroll
            for (int nj = 0; nj < NJ; ++nj)
#pragma unroll
                for (int r = 0; r < 4; ++r)
                    part[mi][r] += fmaxf(acc[mi][nj][r] + bv[nj], 0.f) * f2[nj];
#pragma unroll
        for (int mi = 0; mi < 2; ++mi)
#pragma unroll
            for (int r = 0; r < 4; ++r)
                Red[(w * 32 + mi * 16 + kgrp * 4 + r) * 17 + frow] = part[mi][r];
        __syncthreads();
        if (tid < 128) {
            float s = fc2b[0];
#pragma unroll
            for (int q = 0; q < 16; ++q) s += Red[tid * 17 + q];
            int m = m0 + tid;
            if (m < M) out[m] = 1.f / (1.f + expf(-s));
        }
    }
}

// ---------------------------------------------------------------------------
extern "C" void kernel_launch(void* const* d_in, const int* in_sizes, int n_in,
                              void* d_out, int out_size, void* d_ws, size_t ws_size,
                              hipStream_t stream) {
    const float* x = (const float*)d_in[0];
    const int* ei = (const int*)d_in[1];
    const int N = in_sizes[0] / 128;
    const int E = in_sizes[1] / 2;
    const int* srcIdx = ei;
    const int* dstIdx = ei + E;

    const float* w1[3] = {(const float*)d_in[2], (const float*)d_in[7], (const float*)d_in[12]};
    const float* b1[3] = {(const float*)d_in[3], (const float*)d_in[8], (const float*)d_in[13]};
    const float* w2[3] = {(const float*)d_in[4], (const float*)d_in[9], (const float*)d_in[14]};
    const float* b2[3] = {(const float*)d_in[5], (const float*)d_in[10], (const float*)d_in[15]};
    const float* eps[3] = {(const float*)d_in[6], (const float*)d_in[11], (const float*)d_in[16]};
    const float* fc1w = (const float*)d_in[17];
    const float* fc1b = (const float*)d_in[18];
    const float* fc2w = (const float*)d_in[19];
    const float* fc2b = (const float*)d_in[20];

    // workspace carve
    char* ws = (char*)d_ws;
    size_t p = 0;
    auto carve = [&](size_t bytes) -> char* {
        char* r = ws + p;
        p = (p + bytes + 255) & ~(size_t)255;
        return r;
    };
    int* offs = (int*)carve((size_t)(N + 1) * 4);
    int* cursor = (int*)carve((size_t)N * 4);
    int* col = (int*)carve((size_t)E * 4);
    f16* H0 = (f16*)carve((size_t)N * 128 * 2);
    f16* H1 = (f16*)carve((size_t)N * 128 * 2);
    f16* Z = (f16*)carve((size_t)N * 128 * 2);
    f16* T = (f16*)carve((size_t)N * 128 * 2);
    f16* w1f[3], *w2f[3];
    for (int i = 0; i < 3; ++i) {
        w1f[i] = (f16*)carve(128 * 128 * 2);
        w2f[i] = (f16*)carve(128 * 128 * 2);
    }
    f16* fc1wf = (f16*)carve(64 * 128 * 2);
    (void)ws_size;

    // ---- build CSR (once; shared by all 3 convs) ----
    hipMemsetAsync(cursor, 0, (size_t)N * 4, stream);
    count_kernel<<<1024, 256, 0, stream>>>(dstIdx, cursor, E);
    scan_kernel<<<1, 1024, 0, stream>>>(cursor, offs, N);
    hipMemcpyAsync(cursor, offs, (size_t)N * 4, hipMemcpyDeviceToDevice, stream);
    fill_kernel<<<1024, 256, 0, stream>>>(srcIdx, dstIdx, cursor, col, E);

    // ---- fp32 -> f16: x and all MFMA weights ----
    cvt4_kernel<<<2048, 256, 0, stream>>>(x, H0, N * 128 / 4);
    CvtPack cp;
    for (int i = 0; i < 3; ++i) {
        cp.s[i] = w1[i];     cp.d[i] = w1f[i];     cp.nq[i] = 128 * 128 / 4;
        cp.s[3 + i] = w2[i]; cp.d[3 + i] = w2f[i]; cp.nq[3 + i] = 128 * 128 / 4;
    }
    cp.s[6] = fc1w; cp.d[6] = fc1wf; cp.nq[6] = 64 * 128 / 4;
    cvt_pack_kernel<<<dim3(16, 7), 256, 0, stream>>>(cp);

    const int aggGrid = (N + 3) / 4;
    const int gemmGrid = (N + 127) / 128;

    const f16* hin = H0;
    f16* hout = H1;
    for (int i = 0; i < 3; ++i) {
        agg_kernel<<<aggGrid, 256, 0, stream>>>(hin, offs, col, eps[i], Z, N);
        mfma_gemm_kernel<128, false><<<gemmGrid, 256, 0, stream>>>(
            Z, w1f[i], b1[i], T, N, nullptr, nullptr, nullptr);
        mfma_gemm_kernel<128, false><<<gemmGrid, 256, 0, stream>>>(
            T, w2f[i], b2[i], hout, N, nullptr, nullptr, nullptr);
        const f16* tmp = hin;
        hin = hout;
        hout = (f16*)tmp;
        if (i == 0) hout = H0;  // H0's x-copy no longer needed
    }
    // fused fc1(128->64)+relu + fc2(64->1)+sigmoid
    mfma_gemm_kernel<64, true><<<gemmGrid, 256, 0, stream>>>(
        (const f16*)hin, fc1wf, fc1b, nullptr, N, fc2w, fc2b, (float*)d_out);
}

// Round 3
// 484.361 us; speedup vs baseline: 3.1156x; 1.3698x over previous
//
#include <hip/hip_runtime.h>
#include <math.h>

// ---------------------------------------------------------------------------
// GIN network on MI355X — round 3.
//  - Multi-block scan replaces the 160us single-block scan.
//  - Conv MLP fused: GEMM1+ReLU+GEMM2(+ReLU) one kernel, W2 re-staged into
//    the same LDS (64KB, 2 blocks/CU). Conv2 also fuses fc1+ReLU+fc2+sigmoid.
//  - Aggregation: f16x4 per lane, 2 neighbor rows per wave-iter (half-split),
//    cross-half shfl_xor combine, x4 pair unroll.
// ---------------------------------------------------------------------------

using f16   = _Float16;
using f16x4 = __attribute__((ext_vector_type(4))) _Float16;
using f16x8 = __attribute__((ext_vector_type(8))) _Float16;
using f32x4 = __attribute__((ext_vector_type(4))) float;

__device__ inline void glds16(const void* g, void* l) {
    __builtin_amdgcn_global_load_lds(
        (const __attribute__((address_space(1))) void*)g,
        (__attribute__((address_space(3))) void*)l, 16, 0, 0);
}

// ---------------- CSR build ----------------
__global__ void count_kernel(const int* __restrict__ dst, int* __restrict__ deg, int E) {
    int stride = gridDim.x * blockDim.x;
    for (int e = blockIdx.x * blockDim.x + threadIdx.x; e < E; e += stride)
        atomicAdd(&deg[dst[e]], 1);
}

// per-1024-chunk sums
__global__ __launch_bounds__(256) void scan_partial(const int* __restrict__ deg,
                                                    int* __restrict__ bsum, int n) {
    __shared__ int red[256];
    int b = blockIdx.x, t = threadIdx.x;
    int base = b * 1024;
    int s = 0;
#pragma unroll
    for (int j = 0; j < 4; ++j) {
        int idx = base + j * 256 + t;
        if (idx < n) s += deg[idx];
    }
    red[t] = s;
    __syncthreads();
    for (int d = 128; d > 0; d >>= 1) {
        if (t < d) red[t] += red[t + d];
        __syncthreads();
    }
    if (t == 0) bsum[b] = red[0];
}

// scan the (<=128) chunk sums; also writes offs[n] = total
__global__ __launch_bounds__(128) void scan_bsum(const int* __restrict__ bsum,
                                                 int* __restrict__ bbase, int nb,
                                                 int* __restrict__ offs_n) {
    __shared__ int s[128];
    int t = threadIdx.x;
    s[t] = (t < nb) ? bsum[t] : 0;
    __syncthreads();
    for (int d = 1; d < 128; d <<= 1) {
        int v = (t >= d) ? s[t - d] : 0;
        __syncthreads();
        s[t] += v;
        __syncthreads();
    }
    bbase[t] = (t > 0) ? s[t - 1] : 0;
    if (t == 127) offs_n[0] = s[127];
}

// final: exclusive offsets for each element; writes offs AND cursor copies
__global__ __launch_bounds__(256) void scan_final(const int* __restrict__ deg,
                                                  const int* __restrict__ bbase,
                                                  int* __restrict__ offs,
                                                  int* __restrict__ cursor, int n) {
    __shared__ int red[256];
    int b = blockIdx.x, t = threadIdx.x;
    int base = b * 1024 + t * 4;
    int d0 = 0, d1 = 0, d2 = 0, d3 = 0;
    if (base + 3 < n) {
        int4 v = *(const int4*)&deg[base];
        d0 = v.x; d1 = v.y; d2 = v.z; d3 = v.w;
    } else {
        if (base < n) d0 = deg[base];
        if (base + 1 < n) d1 = deg[base + 1];
        if (base + 2 < n) d2 = deg[base + 2];
    }
    red[t] = d0 + d1 + d2 + d3;
    __syncthreads();
    for (int d = 1; d < 256; d <<= 1) {
        int v = (t >= d) ? red[t - d] : 0;
        __syncthreads();
        red[t] += v;
        __syncthreads();
    }
    int ex = bbase[b] + ((t > 0) ? red[t - 1] : 0);
    int o0 = ex, o1 = ex + d0, o2 = o1 + d1, o3 = o2 + d2;
    if (base + 3 < n) {
        *(int4*)&offs[base] = make_int4(o0, o1, o2, o3);
        *(int4*)&cursor[base] = make_int4(o0, o1, o2, o3);
    } else {
        if (base < n) { offs[base] = o0; cursor[base] = o0; }
        if (base + 1 < n) { offs[base + 1] = o1; cursor[base + 1] = o1; }
        if (base + 2 < n) { offs[base + 2] = o2; cursor[base + 2] = o2; }
    }
}

__global__ void fill_kernel(const int* __restrict__ src, const int* __restrict__ dst,
                            int* __restrict__ cursor, int* __restrict__ col, int E) {
    int stride = gridDim.x * blockDim.x;
    for (int e = blockIdx.x * blockDim.x + threadIdx.x; e < E; e += stride) {
        int d = dst[e];
        int p = atomicAdd(&cursor[d], 1);
        col[p] = src[e];
    }
}

// ---------------- fp32 -> f16 conversions ----------------
__global__ void cvt4_kernel(const float* __restrict__ in, f16* __restrict__ out, int nq) {
    int stride = gridDim.x * blockDim.x;
    for (int i = blockIdx.x * blockDim.x + threadIdx.x; i < nq; i += stride) {
        float4 v = *(const float4*)(in + (size_t)i * 4);
        f16x4 o = {(f16)v.x, (f16)v.y, (f16)v.z, (f16)v.w};
        *(f16x4*)(out + (size_t)i * 4) = o;
    }
}

struct CvtPack {
    const float* s[7];
    f16* d[7];
    int nq[7];
};
__global__ void cvt_pack_kernel(CvtPack p) {
    int seg = blockIdx.y;
    int nq = p.nq[seg];
    const float* in = p.s[seg];
    f16* out = p.d[seg];
    int stride = gridDim.x * blockDim.x;
    for (int i = blockIdx.x * blockDim.x + threadIdx.x; i < nq; i += stride) {
        float4 v = *(const float4*)(in + (size_t)i * 4);
        f16x4 o = {(f16)v.x, (f16)v.y, (f16)v.z, (f16)v.w};
        *(f16x4*)(out + (size_t)i * 4) = o;
    }
}

// ---------------- aggregation: z[n] = (1+eps)*h[n] + sum h[nbr] ----------------
// One wave per node; lane half (0/1) owns alternating neighbors; f16x4 (8B)
// per lane so 32 lanes cover one 256B row. Cross-half shfl_xor combine.
__global__ __launch_bounds__(256) void agg_kernel(const f16* __restrict__ h,
                                                  const int* __restrict__ offs,
                                                  const int* __restrict__ col,
                                                  const float* __restrict__ epsp,
                                                  f16* __restrict__ z, int n) {
    int wid = blockIdx.x * 4 + (threadIdx.x >> 6);
    if (wid >= n) return;
    int lane = threadIdx.x & 63;
    int half = lane >> 5, li = lane & 31;
    const f16x4* hp = (const f16x4*)h;  // row stride = 32 f16x4
    float e1 = 1.0f + epsp[0];
    f16x4 self = hp[(size_t)wid * 32 + li];
    float sc = half ? 0.f : e1;
    float a0 = (float)self.x * sc, a1 = (float)self.y * sc;
    float a2 = (float)self.z * sc, a3 = (float)self.w * sc;
    int lo = offs[wid], hi = offs[wid + 1];
    int e = lo + half;
    for (; e + 6 < hi; e += 8) {
        int s0 = col[e], s1 = col[e + 2], s2 = col[e + 4], s3 = col[e + 6];
        f16x4 v0 = hp[(size_t)s0 * 32 + li];
        f16x4 v1 = hp[(size_t)s1 * 32 + li];
        f16x4 v2 = hp[(size_t)s2 * 32 + li];
        f16x4 v3 = hp[(size_t)s3 * 32 + li];
        a0 += (float)v0.x + (float)v1.x + (float)v2.x + (float)v3.x;
        a1 += (float)v0.y + (float)v1.y + (float)v2.y + (float)v3.y;
        a2 += (float)v0.z + (float)v1.z + (float)v2.z + (float)v3.z;
        a3 += (float)v0.w + (float)v1.w + (float)v2.w + (float)v3.w;
    }
    for (; e < hi; e += 2) {
        f16x4 v = hp[(size_t)col[e] * 32 + li];
        a0 += (float)v.x; a1 += (float)v.y; a2 += (float)v.z; a3 += (float)v.w;
    }
    a0 += __shfl_xor(a0, 32, 64);
    a1 += __shfl_xor(a1, 32, 64);
    a2 += __shfl_xor(a2, 32, 64);
    a3 += __shfl_xor(a3, 32, 64);
    if (half == 0) {
        f16x4 o = {(f16)a0, (f16)a1, (f16)a2, (f16)a3};
        ((f16x4*)z)[(size_t)wid * 32 + li] = o;
    }
}

// ---------------- fused conv MLP (+ optional fc tail) ----------------
// Hout = relu( relu(Z@W1^T+b1) @ W2^T + b2 )   [128 rows per block]
// LAST: out = sigmoid( relu(Hout@fc1^T+fc1b) . fc2w + fc2b )
// LDS: As(32KB) + Ws(32KB); W2 / fc1w re-staged into Ws mid-kernel.
// XOR swizzle on 16B units: LDS[r][u] = G[r][u ^ (r&7)].
template <bool LAST>
__global__ __launch_bounds__(256) void conv_mlp_kernel(
    const f16* __restrict__ Z, const f16* __restrict__ W1f,
    const float* __restrict__ b1, const f16* __restrict__ W2f,
    const float* __restrict__ b2, f16* __restrict__ Hout, int M,
    const f16* __restrict__ fc1wf, const float* __restrict__ fc1b,
    const float* __restrict__ fc2w, const float* __restrict__ fc2b,
    float* __restrict__ out) {
    __shared__ __align__(16) f16 As[128 * 128];
    __shared__ __align__(16) f16 Ws[128 * 128];
    __shared__ float Red[LAST ? 128 * 17 : 1];

    const int tid = threadIdx.x;
    const int w = tid >> 6, lane = tid & 63;
    const int frow = lane & 15, kgrp = lane >> 4;
    const int m0 = blockIdx.x * 128;
    const int u = lane & 15, rsub = lane >> 4;

    // stage Z tile + W1 (both swizzled via pre-swizzled global source)
#pragma unroll
    for (int i = 0; i < 8; ++i) {
        int rowbase = (w * 8 + i) * 4;
        int r = rowbase + rsub;
        int gr = m0 + r;
        if (gr >= M) gr = M - 1;
        glds16(Z + (size_t)gr * 128 + ((u ^ (r & 7)) << 3), &As[rowbase * 128]);
    }
#pragma unroll
    for (int i = 0; i < 8; ++i) {
        int rowbase = (w * 8 + i) * 4;
        int r = rowbase + rsub;
        glds16(W1f + (size_t)r * 128 + ((u ^ (r & 7)) << 3), &Ws[rowbase * 128]);
    }
    __syncthreads();

    const int arow0 = w * 32 + frow;
    f32x4 acc[2][8];
#pragma unroll
    for (int mi = 0; mi < 2; ++mi)
#pragma unroll
        for (int nj = 0; nj < 8; ++nj) acc[mi][nj] = (f32x4){0.f, 0.f, 0.f, 0.f};

    // ---- GEMM1 ----
#pragma unroll
    for (int kk = 0; kk < 4; ++kk) {
        int kb = kk * 4 + kgrp;
        f16x8 a[2], b[8];
#pragma unroll
        for (int mi = 0; mi < 2; ++mi) {
            int r = arow0 + mi * 16;
            a[mi] = *(const f16x8*)&As[r * 128 + ((kb ^ (r & 7)) << 3)];
        }
#pragma unroll
        for (int nj = 0; nj < 8; ++nj) {
            int r = nj * 16 + frow;
            b[nj] = *(const f16x8*)&Ws[r * 128 + ((kb ^ (r & 7)) << 3)];
        }
#pragma unroll
        for (int mi = 0; mi < 2; ++mi)
#pragma unroll
            for (int nj = 0; nj < 8; ++nj)
                acc[mi][nj] = __builtin_amdgcn_mfma_f32_16x16x32_f16(a[mi], b[nj],
                                                                     acc[mi][nj], 0, 0, 0);
    }
    __syncthreads();  // all As/Ws reads done

    // re-stage W2 into Ws (overlaps with the As epilogue writes below)
#pragma unroll
    for (int i = 0; i < 8; ++i) {
        int rowbase = (w * 8 + i) * 4;
        int r = rowbase + rsub;
        glds16(W2f + (size_t)r * 128 + ((u ^ (r & 7)) << 3), &Ws[rowbase * 128]);
    }
    // relu(acc + b1) -> As (swizzled, so GEMM2 fragment reads reuse the pattern)
    {
        float bv[8];
#pragma unroll
        for (int nj = 0; nj < 8; ++nj) bv[nj] = b1[nj * 16 + frow];
#pragma unroll
        for (int mi = 0; mi < 2; ++mi)
#pragma unroll
            for (int nj = 0; nj < 8; ++nj) {
                int row0 = w * 32 + mi * 16 + kgrp * 4;
                int c = nj * 16 + frow;
                int cu = c >> 3, cl = c & 7;
#pragma unroll
                for (int r = 0; r < 4; ++r) {
                    int rr = row0 + r;
                    As[rr * 128 + ((cu ^ (rr & 7)) << 3) + cl] =
                        (f16)fmaxf(acc[mi][nj][r] + bv[nj], 0.f);
                }
            }
    }
    __syncthreads();  // W2 staged + As epilogue visible

    // ---- GEMM2 ----
#pragma unroll
    for (int mi = 0; mi < 2; ++mi)
#pragma unroll
        for (int nj = 0; nj < 8; ++nj) acc[mi][nj] = (f32x4){0.f, 0.f, 0.f, 0.f};
#pragma unroll
    for (int kk = 0; kk < 4; ++kk) {
        int kb = kk * 4 + kgrp;
        f16x8 a[2], b[8];
#pragma unroll
        for (int mi = 0; mi < 2; ++mi) {
            int r = arow0 + mi * 16;
            a[mi] = *(const f16x8*)&As[r * 128 + ((kb ^ (r & 7)) << 3)];
        }
#pragma unroll
        for (int nj = 0; nj < 8; ++nj) {
            int r = nj * 16 + frow;
            b[nj] = *(const f16x8*)&Ws[r * 128 + ((kb ^ (r & 7)) << 3)];
        }
#pragma unroll
        for (int mi = 0; mi < 2; ++mi)
#pragma unroll
            for (int nj = 0; nj < 8; ++nj)
                acc[mi][nj] = __builtin_amdgcn_mfma_f32_16x16x32_f16(a[mi], b[nj],
                                                                     acc[mi][nj], 0, 0, 0);
    }

    float bv2[8];
#pragma unroll
    for (int nj = 0; nj < 8; ++nj) bv2[nj] = b2[nj * 16 + frow];

    if (!LAST) {
        __syncthreads();  // done reading As
        // relu(acc + b2) -> As linear -> coalesced store
#pragma unroll
        for (int mi = 0; mi < 2; ++mi)
#pragma unroll
            for (int nj = 0; nj < 8; ++nj) {
                int row0 = w * 32 + mi * 16 + kgrp * 4;
                int c = nj * 16 + frow;
#pragma unroll
                for (int r = 0; r < 4; ++r)
                    As[(row0 + r) * 128 + c] = (f16)fmaxf(acc[mi][nj][r] + bv2[nj], 0.f);
            }
        __syncthreads();
        for (int idx = tid; idx < 128 * 16; idx += 256) {
            int r = idx >> 4, q = idx & 15;
            int gm = m0 + r;
            if (gm < M)
                *(float4*)(Hout + (size_t)gm * 128 + q * 8) = *(const float4*)&As[r * 128 + q * 8];
        }
    } else {
        __syncthreads();  // done reading As/Ws
        // stage fc1w (64 rows) into Ws
#pragma unroll
        for (int i = 0; i < 4; ++i) {
            int rowbase = (w * 4 + i) * 4;
            int r = rowbase + rsub;
            glds16(fc1wf + (size_t)r * 128 + ((u ^ (r & 7)) << 3), &Ws[rowbase * 128]);
        }
        // h = relu(acc + b2) -> As swizzled
#pragma unroll
        for (int mi = 0; mi < 2; ++mi)
#pragma unroll
            for (int nj = 0; nj < 8; ++nj) {
                int row0 = w * 32 + mi * 16 + kgrp * 4;
                int c = nj * 16 + frow;
                int cu = c >> 3, cl = c & 7;
#pragma unroll
                for (int r = 0; r < 4; ++r) {
                    int rr = row0 + r;
                    As[rr * 128 + ((cu ^ (rr & 7)) << 3) + cl] =
                        (f16)fmaxf(acc[mi][nj][r] + bv2[nj], 0.f);
                }
            }
        __syncthreads();

        // ---- GEMM3: h @ fc1^T (NCOL=64) ----
        f32x4 acc3[2][4];
#pragma unroll
        for (int mi = 0; mi < 2; ++mi)
#pragma unroll
            for (int nj = 0; nj < 4; ++nj) acc3[mi][nj] = (f32x4){0.f, 0.f, 0.f, 0.f};
#pragma unroll
        for (int kk = 0; kk < 4; ++kk) {
            int kb = kk * 4 + kgrp;
            f16x8 a[2], b[4];
#pragma unroll
            for (int mi = 0; mi < 2; ++mi) {
                int r = arow0 + mi * 16;
                a[mi] = *(const f16x8*)&As[r * 128 + ((kb ^ (r & 7)) << 3)];
            }
#pragma unroll
            for (int nj = 0; nj < 4; ++nj) {
                int r = nj * 16 + frow;
                b[nj] = *(const f16x8*)&Ws[r * 128 + ((kb ^ (r & 7)) << 3)];
            }
#pragma unroll
            for (int mi = 0; mi < 2; ++mi)
#pragma unroll
                for (int nj = 0; nj < 4; ++nj)
                    acc3[mi][nj] = __builtin_amdgcn_mfma_f32_16x16x32_f16(a[mi], b[nj],
                                                                          acc3[mi][nj], 0, 0, 0);
        }
        float bvf[4], f2[4];
#pragma unroll
        for (int nj = 0; nj < 4; ++nj) {
            bvf[nj] = fc1b[nj * 16 + frow];
            f2[nj] = fc2w[nj * 16 + frow];
        }
        float part[2][4];
#pragma unroll
        for (int mi = 0; mi < 2; ++mi)
#pragma unroll
            for (int r = 0; r < 4; ++r) part[mi][r] = 0.f;
#pragma unroll
        for (int mi = 0; mi < 2; ++mi)
#pragma unroll
            for (int nj = 0; nj < 4; ++nj)
#pragma unroll
                for (int r = 0; r < 4; ++r)
                    part[mi][r] += fmaxf(acc3[mi][nj][r] + bvf[nj], 0.f) * f2[nj];
#pragma unroll
        for (int mi = 0; mi < 2; ++mi)
#pragma unroll
            for (int r = 0; r < 4; ++r)
                Red[(w * 32 + mi * 16 + kgrp * 4 + r) * 17 + frow] = part[mi][r];
        __syncthreads();
        if (tid < 128) {
            float s = fc2b[0];
#pragma unroll
            for (int q = 0; q < 16; ++q) s += Red[tid * 17 + q];
            int m = m0 + tid;
            if (m < M) out[m] = 1.f / (1.f + expf(-s));
        }
    }
}

// ---------------------------------------------------------------------------
extern "C" void kernel_launch(void* const* d_in, const int* in_sizes, int n_in,
                              void* d_out, int out_size, void* d_ws, size_t ws_size,
                              hipStream_t stream) {
    const float* x = (const float*)d_in[0];
    const int* ei = (const int*)d_in[1];
    const int N = in_sizes[0] / 128;
    const int E = in_sizes[1] / 2;
    const int* srcIdx = ei;
    const int* dstIdx = ei + E;

    const float* w1[3] = {(const float*)d_in[2], (const float*)d_in[7], (const float*)d_in[12]};
    const float* b1[3] = {(const float*)d_in[3], (const float*)d_in[8], (const float*)d_in[13]};
    const float* w2[3] = {(const float*)d_in[4], (const float*)d_in[9], (const float*)d_in[14]};
    const float* b2[3] = {(const float*)d_in[5], (const float*)d_in[10], (const float*)d_in[15]};
    const float* eps[3] = {(const float*)d_in[6], (const float*)d_in[11], (const float*)d_in[16]};
    const float* fc1w = (const float*)d_in[17];
    const float* fc1b = (const float*)d_in[18];
    const float* fc2w = (const float*)d_in[19];
    const float* fc2b = (const float*)d_in[20];

    // workspace carve
    char* ws = (char*)d_ws;
    size_t p = 0;
    auto carve = [&](size_t bytes) -> char* {
        char* r = ws + p;
        p = (p + bytes + 255) & ~(size_t)255;
        return r;
    };
    int* deg = (int*)carve((size_t)N * 4);
    int* offs = (int*)carve((size_t)(N + 1) * 4);
    int* cursor = (int*)carve((size_t)N * 4);
    int* col = (int*)carve((size_t)E * 4);
    int* bsum = (int*)carve(128 * 4);
    int* bbase = (int*)carve(128 * 4);
    f16* H0 = (f16*)carve((size_t)N * 128 * 2);
    f16* H1 = (f16*)carve((size_t)N * 128 * 2);
    f16* Z = (f16*)carve((size_t)N * 128 * 2);
    f16* w1f[3], *w2f[3];
    for (int i = 0; i < 3; ++i) {
        w1f[i] = (f16*)carve(128 * 128 * 2);
        w2f[i] = (f16*)carve(128 * 128 * 2);
    }
    f16* fc1wf = (f16*)carve(64 * 128 * 2);
    (void)ws_size;

    const int SB = (N + 1023) / 1024;  // scan chunks (<=128)

    // ---- build CSR (once; shared by all 3 convs) ----
    hipMemsetAsync(deg, 0, (size_t)N * 4, stream);
    count_kernel<<<1024, 256, 0, stream>>>(dstIdx, deg, E);
    scan_partial<<<SB, 256, 0, stream>>>(deg, bsum, N);
    scan_bsum<<<1, 128, 0, stream>>>(bsum, bbase, SB, offs + N);
    scan_final<<<SB, 256, 0, stream>>>(deg, bbase, offs, cursor, N);
    fill_kernel<<<1024, 256, 0, stream>>>(srcIdx, dstIdx, cursor, col, E);

    // ---- fp32 -> f16: x and all MFMA weights ----
    cvt4_kernel<<<2048, 256, 0, stream>>>(x, H0, N * 128 / 4);
    CvtPack cp;
    for (int i = 0; i < 3; ++i) {
        cp.s[i] = w1[i];     cp.d[i] = w1f[i];     cp.nq[i] = 128 * 128 / 4;
        cp.s[3 + i] = w2[i]; cp.d[3 + i] = w2f[i]; cp.nq[3 + i] = 128 * 128 / 4;
    }
    cp.s[6] = fc1w; cp.d[6] = fc1wf; cp.nq[6] = 64 * 128 / 4;
    cvt_pack_kernel<<<dim3(16, 7), 256, 0, stream>>>(cp);

    const int aggGrid = (N + 3) / 4;
    const int gemmGrid = (N + 127) / 128;

    // conv0: H0 -> Z -> H1 ; conv1: H1 -> Z -> H0 ; conv2: H0 -> Z -> out
    agg_kernel<<<aggGrid, 256, 0, stream>>>(H0, offs, col, eps[0], Z, N);
    conv_mlp_kernel<false><<<gemmGrid, 256, 0, stream>>>(
        Z, w1f[0], b1[0], w2f[0], b2[0], H1, N, nullptr, nullptr, nullptr, nullptr, nullptr);
    agg_kernel<<<aggGrid, 256, 0, stream>>>(H1, offs, col, eps[1], Z, N);
    conv_mlp_kernel<false><<<gemmGrid, 256, 0, stream>>>(
        Z, w1f[1], b1[1], w2f[1], b2[1], H0, N, nullptr, nullptr, nullptr, nullptr, nullptr);
    agg_kernel<<<aggGrid, 256, 0, stream>>>(H0, offs, col, eps[2], Z, N);
    conv_mlp_kernel<true><<<gemmGrid, 256, 0, stream>>>(
        Z, w1f[2], b1[2], w2f[2], b2[2], nullptr, N, fc1wf, fc1b, fc2w, fc2b, (float*)d_out);
}

// Round 4
// 424.148 us; speedup vs baseline: 3.5579x; 1.1420x over previous
//
#include <hip/hip_runtime.h>
#include <math.h>

// ---------------------------------------------------------------------------
// GIN network on MI355X — round 4.
//  - fill_kernel: 8 range-partitioned passes in one launch. Restricting each
//    pass's dst range to ~12.5K nodes keeps the col[] write window ~800KB
//    (L2-resident), killing the 16x write amplification (105MB -> ~12MB).
//  - agg_kernel: 8 row-loads in flight per lane (16 edges/iter).
//  - Everything else as round 3 (fused conv MLP, multi-block scan, f16 MFMA).
// ---------------------------------------------------------------------------

using f16   = _Float16;
using f16x4 = __attribute__((ext_vector_type(4))) _Float16;
using f16x8 = __attribute__((ext_vector_type(8))) _Float16;
using f32x4 = __attribute__((ext_vector_type(4))) float;

__device__ inline void glds16(const void* g, void* l) {
    __builtin_amdgcn_global_load_lds(
        (const __attribute__((address_space(1))) void*)g,
        (__attribute__((address_space(3))) void*)l, 16, 0, 0);
}

// ---------------- CSR build ----------------
__global__ void count_kernel(const int* __restrict__ dst, int* __restrict__ deg, int E) {
    int stride = gridDim.x * blockDim.x;
    for (int e = blockIdx.x * blockDim.x + threadIdx.x; e < E; e += stride)
        atomicAdd(&deg[dst[e]], 1);
}

// per-1024-chunk sums
__global__ __launch_bounds__(256) void scan_partial(const int* __restrict__ deg,
                                                    int* __restrict__ bsum, int n) {
    __shared__ int red[256];
    int b = blockIdx.x, t = threadIdx.x;
    int base = b * 1024;
    int s = 0;
#pragma unroll
    for (int j = 0; j < 4; ++j) {
        int idx = base + j * 256 + t;
        if (idx < n) s += deg[idx];
    }
    red[t] = s;
    __syncthreads();
    for (int d = 128; d > 0; d >>= 1) {
        if (t < d) red[t] += red[t + d];
        __syncthreads();
    }
    if (t == 0) bsum[b] = red[0];
}

// scan the (<=128) chunk sums; also writes offs[n] = total
__global__ __launch_bounds__(128) void scan_bsum(const int* __restrict__ bsum,
                                                 int* __restrict__ bbase, int nb,
                                                 int* __restrict__ offs_n) {
    __shared__ int s[128];
    int t = threadIdx.x;
    s[t] = (t < nb) ? bsum[t] : 0;
    __syncthreads();
    for (int d = 1; d < 128; d <<= 1) {
        int v = (t >= d) ? s[t - d] : 0;
        __syncthreads();
        s[t] += v;
        __syncthreads();
    }
    bbase[t] = (t > 0) ? s[t - 1] : 0;
    if (t == 127) offs_n[0] = s[127];
}

// final: exclusive offsets for each element; writes offs AND cursor copies
__global__ __launch_bounds__(256) void scan_final(const int* __restrict__ deg,
                                                  const int* __restrict__ bbase,
                                                  int* __restrict__ offs,
                                                  int* __restrict__ cursor, int n) {
    __shared__ int red[256];
    int b = blockIdx.x, t = threadIdx.x;
    int base = b * 1024 + t * 4;
    int d0 = 0, d1 = 0, d2 = 0, d3 = 0;
    if (base + 3 < n) {
        int4 v = *(const int4*)&deg[base];
        d0 = v.x; d1 = v.y; d2 = v.z; d3 = v.w;
    } else {
        if (base < n) d0 = deg[base];
        if (base + 1 < n) d1 = deg[base + 1];
        if (base + 2 < n) d2 = deg[base + 2];
    }
    red[t] = d0 + d1 + d2 + d3;
    __syncthreads();
    for (int d = 1; d < 256; d <<= 1) {
        int v = (t >= d) ? red[t - d] : 0;
        __syncthreads();
        red[t] += v;
        __syncthreads();
    }
    int ex = bbase[b] + ((t > 0) ? red[t - 1] : 0);
    int o0 = ex, o1 = ex + d0, o2 = o1 + d1, o3 = o2 + d2;
    if (base + 3 < n) {
        *(int4*)&offs[base] = make_int4(o0, o1, o2, o3);
        *(int4*)&cursor[base] = make_int4(o0, o1, o2, o3);
    } else {
        if (base < n) { offs[base] = o0; cursor[base] = o0; }
        if (base + 1 < n) { offs[base + 1] = o1; cursor[base + 1] = o1; }
        if (base + 2 < n) { offs[base + 2] = o2; cursor[base + 2] = o2; }
    }
}

// 8 range-partitioned passes: pass p only handles dst in [p*per, p*per+per).
// col write window per pass ~800KB -> L2-resident -> compact writebacks.
// Regions are disjoint across passes, so no inter-pass sync is needed.
__global__ __launch_bounds__(256) void fill_kernel(const int* __restrict__ src,
                                                   const int* __restrict__ dst,
                                                   int* __restrict__ cursor,
                                                   int* __restrict__ col, int E, int N,
                                                   int npass) {
    int stride = gridDim.x * blockDim.x;
    int per = (N + npass - 1) / npass;
    for (int pass = 0; pass < npass; ++pass) {
        int lo = pass * per;
        int hi = min(lo + per, N);
        for (int e = blockIdx.x * blockDim.x + threadIdx.x; e < E; e += stride) {
            int d = dst[e];
            if (d >= lo && d < hi) {
                int p = atomicAdd(&cursor[d], 1);
                col[p] = src[e];
            }
        }
    }
}

// ---------------- fp32 -> f16 conversions ----------------
__global__ void cvt4_kernel(const float* __restrict__ in, f16* __restrict__ out, int nq) {
    int stride = gridDim.x * blockDim.x;
    for (int i = blockIdx.x * blockDim.x + threadIdx.x; i < nq; i += stride) {
        float4 v = *(const float4*)(in + (size_t)i * 4);
        f16x4 o = {(f16)v.x, (f16)v.y, (f16)v.z, (f16)v.w};
        *(f16x4*)(out + (size_t)i * 4) = o;
    }
}

struct CvtPack {
    const float* s[7];
    f16* d[7];
    int nq[7];
};
__global__ void cvt_pack_kernel(CvtPack p) {
    int seg = blockIdx.y;
    int nq = p.nq[seg];
    const float* in = p.s[seg];
    f16* out = p.d[seg];
    int stride = gridDim.x * blockDim.x;
    for (int i = blockIdx.x * blockDim.x + threadIdx.x; i < nq; i += stride) {
        float4 v = *(const float4*)(in + (size_t)i * 4);
        f16x4 o = {(f16)v.x, (f16)v.y, (f16)v.z, (f16)v.w};
        *(f16x4*)(out + (size_t)i * 4) = o;
    }
}

// ---------------- aggregation: z[n] = (1+eps)*h[n] + sum h[nbr] ----------------
// One wave per node; lane half (0/1) owns alternating neighbors; f16x4 (8B)
// per lane so 32 lanes cover one 256B row. 8 rows in flight per lane.
__global__ __launch_bounds__(256) void agg_kernel(const f16* __restrict__ h,
                                                  const int* __restrict__ offs,
                                                  const int* __restrict__ col,
                                                  const float* __restrict__ epsp,
                                                  f16* __restrict__ z, int n) {
    int wid = blockIdx.x * 4 + (threadIdx.x >> 6);
    if (wid >= n) return;
    int lane = threadIdx.x & 63;
    int half = lane >> 5, li = lane & 31;
    const f16x4* hp = (const f16x4*)h;  // row stride = 32 f16x4
    float e1 = 1.0f + epsp[0];
    f16x4 self = hp[(size_t)wid * 32 + li];
    float sc = half ? 0.f : e1;
    float a0 = (float)self.x * sc, a1 = (float)self.y * sc;
    float a2 = (float)self.z * sc, a3 = (float)self.w * sc;
    int lo = offs[wid], hi = offs[wid + 1];
    int e = lo + half;
    for (; e + 14 < hi; e += 16) {
        f16x4 v[8];
#pragma unroll
        for (int j = 0; j < 8; ++j) v[j] = hp[(size_t)col[e + 2 * j] * 32 + li];
#pragma unroll
        for (int j = 0; j < 8; ++j) {
            a0 += (float)v[j].x; a1 += (float)v[j].y;
            a2 += (float)v[j].z; a3 += (float)v[j].w;
        }
    }
    for (; e + 6 < hi; e += 8) {
        f16x4 v[4];
#pragma unroll
        for (int j = 0; j < 4; ++j) v[j] = hp[(size_t)col[e + 2 * j] * 32 + li];
#pragma unroll
        for (int j = 0; j < 4; ++j) {
            a0 += (float)v[j].x; a1 += (float)v[j].y;
            a2 += (float)v[j].z; a3 += (float)v[j].w;
        }
    }
    for (; e < hi; e += 2) {
        f16x4 v = hp[(size_t)col[e] * 32 + li];
        a0 += (float)v.x; a1 += (float)v.y; a2 += (float)v.z; a3 += (float)v.w;
    }
    a0 += __shfl_xor(a0, 32, 64);
    a1 += __shfl_xor(a1, 32, 64);
    a2 += __shfl_xor(a2, 32, 64);
    a3 += __shfl_xor(a3, 32, 64);
    if (half == 0) {
        f16x4 o = {(f16)a0, (f16)a1, (f16)a2, (f16)a3};
        ((f16x4*)z)[(size_t)wid * 32 + li] = o;
    }
}

// ---------------- fused conv MLP (+ optional fc tail) ----------------
// Hout = relu( relu(Z@W1^T+b1) @ W2^T + b2 )   [128 rows per block]
// LAST: out = sigmoid( relu(Hout@fc1^T+fc1b) . fc2w + fc2b )
// LDS: As(32KB) + Ws(32KB); W2 / fc1w re-staged into Ws mid-kernel.
// XOR swizzle on 16B units: LDS[r][u] = G[r][u ^ (r&7)].
template <bool LAST>
__global__ __launch_bounds__(256) void conv_mlp_kernel(
    const f16* __restrict__ Z, const f16* __restrict__ W1f,
    const float* __restrict__ b1, const f16* __restrict__ W2f,
    const float* __restrict__ b2, f16* __restrict__ Hout, int M,
    const f16* __restrict__ fc1wf, const float* __restrict__ fc1b,
    const float* __restrict__ fc2w, const float* __restrict__ fc2b,
    float* __restrict__ out) {
    __shared__ __align__(16) f16 As[128 * 128];
    __shared__ __align__(16) f16 Ws[128 * 128];
    __shared__ float Red[LAST ? 128 * 17 : 1];

    const int tid = threadIdx.x;
    const int w = tid >> 6, lane = tid & 63;
    const int frow = lane & 15, kgrp = lane >> 4;
    const int m0 = blockIdx.x * 128;
    const int u = lane & 15, rsub = lane >> 4;

    // stage Z tile + W1 (both swizzled via pre-swizzled global source)
#pragma unroll
    for (int i = 0; i < 8; ++i) {
        int rowbase = (w * 8 + i) * 4;
        int r = rowbase + rsub;
        int gr = m0 + r;
        if (gr >= M) gr = M - 1;
        glds16(Z + (size_t)gr * 128 + ((u ^ (r & 7)) << 3), &As[rowbase * 128]);
    }
#pragma unroll
    for (int i = 0; i < 8; ++i) {
        int rowbase = (w * 8 + i) * 4;
        int r = rowbase + rsub;
        glds16(W1f + (size_t)r * 128 + ((u ^ (r & 7)) << 3), &Ws[rowbase * 128]);
    }
    __syncthreads();

    const int arow0 = w * 32 + frow;
    f32x4 acc[2][8];
#pragma unroll
    for (int mi = 0; mi < 2; ++mi)
#pragma unroll
        for (int nj = 0; nj < 8; ++nj) acc[mi][nj] = (f32x4){0.f, 0.f, 0.f, 0.f};

    // ---- GEMM1 ----
#pragma unroll
    for (int kk = 0; kk < 4; ++kk) {
        int kb = kk * 4 + kgrp;
        f16x8 a[2], b[8];
#pragma unroll
        for (int mi = 0; mi < 2; ++mi) {
            int r = arow0 + mi * 16;
            a[mi] = *(const f16x8*)&As[r * 128 + ((kb ^ (r & 7)) << 3)];
        }
#pragma unroll
        for (int nj = 0; nj < 8; ++nj) {
            int r = nj * 16 + frow;
            b[nj] = *(const f16x8*)&Ws[r * 128 + ((kb ^ (r & 7)) << 3)];
        }
#pragma unroll
        for (int mi = 0; mi < 2; ++mi)
#pragma unroll
            for (int nj = 0; nj < 8; ++nj)
                acc[mi][nj] = __builtin_amdgcn_mfma_f32_16x16x32_f16(a[mi], b[nj],
                                                                     acc[mi][nj], 0, 0, 0);
    }
    __syncthreads();  // all As/Ws reads done

    // re-stage W2 into Ws (overlaps with the As epilogue writes below)
#pragma unroll
    for (int i = 0; i < 8; ++i) {
        int rowbase = (w * 8 + i) * 4;
        int r = rowbase + rsub;
        glds16(W2f + (size_t)r * 128 + ((u ^ (r & 7)) << 3), &Ws[rowbase * 128]);
    }
    // relu(acc + b1) -> As (swizzled, so GEMM2 fragment reads reuse the pattern)
    {
        float bv[8];
#pragma unroll
        for (int nj = 0; nj < 8; ++nj) bv[nj] = b1[nj * 16 + frow];
#pragma unroll
        for (int mi = 0; mi < 2; ++mi)
#pragma unroll
            for (int nj = 0; nj < 8; ++nj) {
                int row0 = w * 32 + mi * 16 + kgrp * 4;
                int c = nj * 16 + frow;
                int cu = c >> 3, cl = c & 7;
#pragma unroll
                for (int r = 0; r < 4; ++r) {
                    int rr = row0 + r;
                    As[rr * 128 + ((cu ^ (rr & 7)) << 3) + cl] =
                        (f16)fmaxf(acc[mi][nj][r] + bv[nj], 0.f);
                }
            }
    }
    __syncthreads();  // W2 staged + As epilogue visible

    // ---- GEMM2 ----
#pragma unroll
    for (int mi = 0; mi < 2; ++mi)
#pragma unroll
        for (int nj = 0; nj < 8; ++nj) acc[mi][nj] = (f32x4){0.f, 0.f, 0.f, 0.f};
#pragma unroll
    for (int kk = 0; kk < 4; ++kk) {
        int kb = kk * 4 + kgrp;
        f16x8 a[2], b[8];
#pragma unroll
        for (int mi = 0; mi < 2; ++mi) {
            int r = arow0 + mi * 16;
            a[mi] = *(const f16x8*)&As[r * 128 + ((kb ^ (r & 7)) << 3)];
        }
#pragma unroll
        for (int nj = 0; nj < 8; ++nj) {
            int r = nj * 16 + frow;
            b[nj] = *(const f16x8*)&Ws[r * 128 + ((kb ^ (r & 7)) << 3)];
        }
#pragma unroll
        for (int mi = 0; mi < 2; ++mi)
#pragma unroll
            for (int nj = 0; nj < 8; ++nj)
                acc[mi][nj] = __builtin_amdgcn_mfma_f32_16x16x32_f16(a[mi], b[nj],
                                                                     acc[mi][nj], 0, 0, 0);
    }

    float bv2[8];
#pragma unroll
    for (int nj = 0; nj < 8; ++nj) bv2[nj] = b2[nj * 16 + frow];

    if (!LAST) {
        __syncthreads();  // done reading As
        // relu(acc + b2) -> As linear -> coalesced store
#pragma unroll
        for (int mi = 0; mi < 2; ++mi)
#pragma unroll
            for (int nj = 0; nj < 8; ++nj) {
                int row0 = w * 32 + mi * 16 + kgrp * 4;
                int c = nj * 16 + frow;
#pragma unroll
                for (int r = 0; r < 4; ++r)
                    As[(row0 + r) * 128 + c] = (f16)fmaxf(acc[mi][nj][r] + bv2[nj], 0.f);
            }
        __syncthreads();
        for (int idx = tid; idx < 128 * 16; idx += 256) {
            int r = idx >> 4, q = idx & 15;
            int gm = m0 + r;
            if (gm < M)
                *(float4*)(Hout + (size_t)gm * 128 + q * 8) = *(const float4*)&As[r * 128 + q * 8];
        }
    } else {
        __syncthreads();  // done reading As/Ws
        // stage fc1w (64 rows) into Ws
#pragma unroll
        for (int i = 0; i < 4; ++i) {
            int rowbase = (w * 4 + i) * 4;
            int r = rowbase + rsub;
            glds16(fc1wf + (size_t)r * 128 + ((u ^ (r & 7)) << 3), &Ws[rowbase * 128]);
        }
        // h = relu(acc + b2) -> As swizzled
#pragma unroll
        for (int mi = 0; mi < 2; ++mi)
#pragma unroll
            for (int nj = 0; nj < 8; ++nj) {
                int row0 = w * 32 + mi * 16 + kgrp * 4;
                int c = nj * 16 + frow;
                int cu = c >> 3, cl = c & 7;
#pragma unroll
                for (int r = 0; r < 4; ++r) {
                    int rr = row0 + r;
                    As[rr * 128 + ((cu ^ (rr & 7)) << 3) + cl] =
                        (f16)fmaxf(acc[mi][nj][r] + bv2[nj], 0.f);
                }
            }
        __syncthreads();

        // ---- GEMM3: h @ fc1^T (NCOL=64) ----
        f32x4 acc3[2][4];
#pragma unroll
        for (int mi = 0; mi < 2; ++mi)
#pragma unroll
            for (int nj = 0; nj < 4; ++nj) acc3[mi][nj] = (f32x4){0.f, 0.f, 0.f, 0.f};
#pragma unroll
        for (int kk = 0; kk < 4; ++kk) {
            int kb = kk * 4 + kgrp;
            f16x8 a[2], b[4];
#pragma unroll
            for (int mi = 0; mi < 2; ++mi) {
                int r = arow0 + mi * 16;
                a[mi] = *(const f16x8*)&As[r * 128 + ((kb ^ (r & 7)) << 3)];
            }
#pragma unroll
            for (int nj = 0; nj < 4; ++nj) {
                int r = nj * 16 + frow;
                b[nj] = *(const f16x8*)&Ws[r * 128 + ((kb ^ (r & 7)) << 3)];
            }
#pragma unroll
            for (int mi = 0; mi < 2; ++mi)
#pragma unroll
                for (int nj = 0; nj < 4; ++nj)
                    acc3[mi][nj] = __builtin_amdgcn_mfma_f32_16x16x32_f16(a[mi], b[nj],
                                                                          acc3[mi][nj], 0, 0, 0);
        }
        float bvf[4], f2[4];
#pragma unroll
        for (int nj = 0; nj < 4; ++nj) {
            bvf[nj] = fc1b[nj * 16 + frow];
            f2[nj] = fc2w[nj * 16 + frow];
        }
        float part[2][4];
#pragma unroll
        for (int mi = 0; mi < 2; ++mi)
#pragma unroll
            for (int r = 0; r < 4; ++r) part[mi][r] = 0.f;
#pragma unroll
        for (int mi = 0; mi < 2; ++mi)
#pragma unroll
            for (int nj = 0; nj < 4; ++nj)
#pragma unroll
                for (int r = 0; r < 4; ++r)
                    part[mi][r] += fmaxf(acc3[mi][nj][r] + bvf[nj], 0.f) * f2[nj];
#pragma unroll
        for (int mi = 0; mi < 2; ++mi)
#pragma unroll
            for (int r = 0; r < 4; ++r)
                Red[(w * 32 + mi * 16 + kgrp * 4 + r) * 17 + frow] = part[mi][r];
        __syncthreads();
        if (tid < 128) {
            float s = fc2b[0];
#pragma unroll
            for (int q = 0; q < 16; ++q) s += Red[tid * 17 + q];
            int m = m0 + tid;
            if (m < M) out[m] = 1.f / (1.f + expf(-s));
        }
    }
}

// ---------------------------------------------------------------------------
extern "C" void kernel_launch(void* const* d_in, const int* in_sizes, int n_in,
                              void* d_out, int out_size, void* d_ws, size_t ws_size,
                              hipStream_t stream) {
    const float* x = (const float*)d_in[0];
    const int* ei = (const int*)d_in[1];
    const int N = in_sizes[0] / 128;
    const int E = in_sizes[1] / 2;
    const int* srcIdx = ei;
    const int* dstIdx = ei + E;

    const float* w1[3] = {(const float*)d_in[2], (const float*)d_in[7], (const float*)d_in[12]};
    const float* b1[3] = {(const float*)d_in[3], (const float*)d_in[8], (const float*)d_in[13]};
    const float* w2[3] = {(const float*)d_in[4], (const float*)d_in[9], (const float*)d_in[14]};
    const float* b2[3] = {(const float*)d_in[5], (const float*)d_in[10], (const float*)d_in[15]};
    const float* eps[3] = {(const float*)d_in[6], (const float*)d_in[11], (const float*)d_in[16]};
    const float* fc1w = (const float*)d_in[17];
    const float* fc1b = (const float*)d_in[18];
    const float* fc2w = (const float*)d_in[19];
    const float* fc2b = (const float*)d_in[20];

    // workspace carve
    char* ws = (char*)d_ws;
    size_t p = 0;
    auto carve = [&](size_t bytes) -> char* {
        char* r = ws + p;
        p = (p + bytes + 255) & ~(size_t)255;
        return r;
    };
    int* deg = (int*)carve((size_t)N * 4);
    int* offs = (int*)carve((size_t)(N + 1) * 4);
    int* cursor = (int*)carve((size_t)N * 4);
    int* col = (int*)carve((size_t)E * 4);
    int* bsum = (int*)carve(128 * 4);
    int* bbase = (int*)carve(128 * 4);
    f16* H0 = (f16*)carve((size_t)N * 128 * 2);
    f16* H1 = (f16*)carve((size_t)N * 128 * 2);
    f16* Z = (f16*)carve((size_t)N * 128 * 2);
    f16* w1f[3], *w2f[3];
    for (int i = 0; i < 3; ++i) {
        w1f[i] = (f16*)carve(128 * 128 * 2);
        w2f[i] = (f16*)carve(128 * 128 * 2);
    }
    f16* fc1wf = (f16*)carve(64 * 128 * 2);
    (void)ws_size;

    const int SB = (N + 1023) / 1024;  // scan chunks (<=128)

    // ---- build CSR (once; shared by all 3 convs) ----
    hipMemsetAsync(deg, 0, (size_t)N * 4, stream);
    count_kernel<<<1024, 256, 0, stream>>>(dstIdx, deg, E);
    scan_partial<<<SB, 256, 0, stream>>>(deg, bsum, N);
    scan_bsum<<<1, 128, 0, stream>>>(bsum, bbase, SB, offs + N);
    scan_final<<<SB, 256, 0, stream>>>(deg, bbase, offs, cursor, N);
    fill_kernel<<<2048, 256, 0, stream>>>(srcIdx, dstIdx, cursor, col, E, N, 8);

    // ---- fp32 -> f16: x and all MFMA weights ----
    cvt4_kernel<<<2048, 256, 0, stream>>>(x, H0, N * 128 / 4);
    CvtPack cp;
    for (int i = 0; i < 3; ++i) {
        cp.s[i] = w1[i];     cp.d[i] = w1f[i];     cp.nq[i] = 128 * 128 / 4;
        cp.s[3 + i] = w2[i]; cp.d[3 + i] = w2f[i]; cp.nq[3 + i] = 128 * 128 / 4;
    }
    cp.s[6] = fc1w; cp.d[6] = fc1wf; cp.nq[6] = 64 * 128 / 4;
    cvt_pack_kernel<<<dim3(16, 7), 256, 0, stream>>>(cp);

    const int aggGrid = (N + 3) / 4;
    const int gemmGrid = (N + 127) / 128;

    // conv0: H0 -> Z -> H1 ; conv1: H1 -> Z -> H0 ; conv2: H0 -> Z -> out
    agg_kernel<<<aggGrid, 256, 0, stream>>>(H0, offs, col, eps[0], Z, N);
    conv_mlp_kernel<false><<<gemmGrid, 256, 0, stream>>>(
        Z, w1f[0], b1[0], w2f[0], b2[0], H1, N, nullptr, nullptr, nullptr, nullptr, nullptr);
    agg_kernel<<<aggGrid, 256, 0, stream>>>(H1, offs, col, eps[1], Z, N);
    conv_mlp_kernel<false><<<gemmGrid, 256, 0, stream>>>(
        Z, w1f[1], b1[1], w2f[1], b2[1], H0, N, nullptr, nullptr, nullptr, nullptr, nullptr);
    agg_kernel<<<aggGrid, 256, 0, stream>>>(H0, offs, col, eps[2], Z, N);
    conv_mlp_kernel<true><<<gemmGrid, 256, 0, stream>>>(
        Z, w1f[2], b1[2], w2f[2], b2[2], nullptr, N, fc1wf, fc1b, fc2w, fc2b, (float*)d_out);
}

// Round 5
// 409.518 us; speedup vs baseline: 3.6850x; 1.0357x over previous
//
#include <hip/hip_runtime.h>
#include <math.h>

// ---------------------------------------------------------------------------
// GIN network on MI355X — round 5.
//  - fill_kernel: XCD-grouped single pass. Blocks with blockIdx%8==g form a
//    group (lands on one XCD under round-robin dispatch); group g exclusively
//    fills dst range [g*N/8,(g+1)*N/8). Every col[] 64B line is then written
//    by ONE XCD's L2 -> accumulates fully dirty -> one writeback. Kills the
//    cross-XCD partial-writeback amplification (90MB -> ~10MB).
//  - Everything else as round 4.
// ---------------------------------------------------------------------------

using f16   = _Float16;
using f16x4 = __attribute__((ext_vector_type(4))) _Float16;
using f16x8 = __attribute__((ext_vector_type(8))) _Float16;
using f32x4 = __attribute__((ext_vector_type(4))) float;

__device__ inline void glds16(const void* g, void* l) {
    __builtin_amdgcn_global_load_lds(
        (const __attribute__((address_space(1))) void*)g,
        (__attribute__((address_space(3))) void*)l, 16, 0, 0);
}

// ---------------- CSR build ----------------
__global__ void count_kernel(const int* __restrict__ dst, int* __restrict__ deg, int E) {
    int stride = gridDim.x * blockDim.x;
    for (int e = blockIdx.x * blockDim.x + threadIdx.x; e < E; e += stride)
        atomicAdd(&deg[dst[e]], 1);
}

// per-1024-chunk sums
__global__ __launch_bounds__(256) void scan_partial(const int* __restrict__ deg,
                                                    int* __restrict__ bsum, int n) {
    __shared__ int red[256];
    int b = blockIdx.x, t = threadIdx.x;
    int base = b * 1024;
    int s = 0;
#pragma unroll
    for (int j = 0; j < 4; ++j) {
        int idx = base + j * 256 + t;
        if (idx < n) s += deg[idx];
    }
    red[t] = s;
    __syncthreads();
    for (int d = 128; d > 0; d >>= 1) {
        if (t < d) red[t] += red[t + d];
        __syncthreads();
    }
    if (t == 0) bsum[b] = red[0];
}

// scan the (<=128) chunk sums; also writes offs[n] = total
__global__ __launch_bounds__(128) void scan_bsum(const int* __restrict__ bsum,
                                                 int* __restrict__ bbase, int nb,
                                                 int* __restrict__ offs_n) {
    __shared__ int s[128];
    int t = threadIdx.x;
    s[t] = (t < nb) ? bsum[t] : 0;
    __syncthreads();
    for (int d = 1; d < 128; d <<= 1) {
        int v = (t >= d) ? s[t - d] : 0;
        __syncthreads();
        s[t] += v;
        __syncthreads();
    }
    bbase[t] = (t > 0) ? s[t - 1] : 0;
    if (t == 127) offs_n[0] = s[127];
}

// final: exclusive offsets for each element; writes offs AND cursor copies
__global__ __launch_bounds__(256) void scan_final(const int* __restrict__ deg,
                                                  const int* __restrict__ bbase,
                                                  int* __restrict__ offs,
                                                  int* __restrict__ cursor, int n) {
    __shared__ int red[256];
    int b = blockIdx.x, t = threadIdx.x;
    int base = b * 1024 + t * 4;
    int d0 = 0, d1 = 0, d2 = 0, d3 = 0;
    if (base + 3 < n) {
        int4 v = *(const int4*)&deg[base];
        d0 = v.x; d1 = v.y; d2 = v.z; d3 = v.w;
    } else {
        if (base < n) d0 = deg[base];
        if (base + 1 < n) d1 = deg[base + 1];
        if (base + 2 < n) d2 = deg[base + 2];
    }
    red[t] = d0 + d1 + d2 + d3;
    __syncthreads();
    for (int d = 1; d < 256; d <<= 1) {
        int v = (t >= d) ? red[t - d] : 0;
        __syncthreads();
        red[t] += v;
        __syncthreads();
    }
    int ex = bbase[b] + ((t > 0) ? red[t - 1] : 0);
    int o0 = ex, o1 = ex + d0, o2 = o1 + d1, o3 = o2 + d2;
    if (base + 3 < n) {
        *(int4*)&offs[base] = make_int4(o0, o1, o2, o3);
        *(int4*)&cursor[base] = make_int4(o0, o1, o2, o3);
    } else {
        if (base < n) { offs[base] = o0; cursor[base] = o0; }
        if (base + 1 < n) { offs[base + 1] = o1; cursor[base + 1] = o1; }
        if (base + 2 < n) { offs[base + 2] = o2; cursor[base + 2] = o2; }
    }
}

// XCD-grouped fill: blocks with blockIdx%8==g handle dst in [g*per,(g+1)*per).
// Under round-robin dispatch a group lives on one XCD, so each col line is
// written (and kept dirty) by exactly one L2 before a single full writeback.
__global__ __launch_bounds__(256) void fill_kernel(const int* __restrict__ src,
                                                   const int* __restrict__ dst,
                                                   int* __restrict__ cursor,
                                                   int* __restrict__ col, int E, int N) {
    int group = blockIdx.x & 7;
    int gblk = blockIdx.x >> 3;
    int nblk = gridDim.x >> 3;
    int per = (N + 7) / 8;
    int lo = group * per;
    int hi = min(lo + per, N);
    int stride = nblk * blockDim.x;
    for (int e = gblk * blockDim.x + threadIdx.x; e < E; e += stride) {
        int d = dst[e];
        if (d >= lo && d < hi) {
            int p = atomicAdd(&cursor[d], 1);
            col[p] = src[e];
        }
    }
}

// ---------------- fp32 -> f16 conversions ----------------
__global__ void cvt4_kernel(const float* __restrict__ in, f16* __restrict__ out, int nq) {
    int stride = gridDim.x * blockDim.x;
    for (int i = blockIdx.x * blockDim.x + threadIdx.x; i < nq; i += stride) {
        float4 v = *(const float4*)(in + (size_t)i * 4);
        f16x4 o = {(f16)v.x, (f16)v.y, (f16)v.z, (f16)v.w};
        *(f16x4*)(out + (size_t)i * 4) = o;
    }
}

struct CvtPack {
    const float* s[7];
    f16* d[7];
    int nq[7];
};
__global__ void cvt_pack_kernel(CvtPack p) {
    int seg = blockIdx.y;
    int nq = p.nq[seg];
    const float* in = p.s[seg];
    f16* out = p.d[seg];
    int stride = gridDim.x * blockDim.x;
    for (int i = blockIdx.x * blockDim.x + threadIdx.x; i < nq; i += stride) {
        float4 v = *(const float4*)(in + (size_t)i * 4);
        f16x4 o = {(f16)v.x, (f16)v.y, (f16)v.z, (f16)v.w};
        *(f16x4*)(out + (size_t)i * 4) = o;
    }
}

// ---------------- aggregation: z[n] = (1+eps)*h[n] + sum h[nbr] ----------------
// One wave per node; lane half (0/1) owns alternating neighbors; f16x4 (8B)
// per lane so 32 lanes cover one 256B row. 8 rows in flight per lane.
__global__ __launch_bounds__(256) void agg_kernel(const f16* __restrict__ h,
                                                  const int* __restrict__ offs,
                                                  const int* __restrict__ col,
                                                  const float* __restrict__ epsp,
                                                  f16* __restrict__ z, int n) {
    int wid = blockIdx.x * 4 + (threadIdx.x >> 6);
    if (wid >= n) return;
    int lane = threadIdx.x & 63;
    int half = lane >> 5, li = lane & 31;
    const f16x4* hp = (const f16x4*)h;  // row stride = 32 f16x4
    float e1 = 1.0f + epsp[0];
    f16x4 self = hp[(size_t)wid * 32 + li];
    float sc = half ? 0.f : e1;
    float a0 = (float)self.x * sc, a1 = (float)self.y * sc;
    float a2 = (float)self.z * sc, a3 = (float)self.w * sc;
    int lo = offs[wid], hi = offs[wid + 1];
    int e = lo + half;
    for (; e + 14 < hi; e += 16) {
        f16x4 v[8];
#pragma unroll
        for (int j = 0; j < 8; ++j) v[j] = hp[(size_t)col[e + 2 * j] * 32 + li];
#pragma unroll
        for (int j = 0; j < 8; ++j) {
            a0 += (float)v[j].x; a1 += (float)v[j].y;
            a2 += (float)v[j].z; a3 += (float)v[j].w;
        }
    }
    for (; e + 6 < hi; e += 8) {
        f16x4 v[4];
#pragma unroll
        for (int j = 0; j < 4; ++j) v[j] = hp[(size_t)col[e + 2 * j] * 32 + li];
#pragma unroll
        for (int j = 0; j < 4; ++j) {
            a0 += (float)v[j].x; a1 += (float)v[j].y;
            a2 += (float)v[j].z; a3 += (float)v[j].w;
        }
    }
    for (; e < hi; e += 2) {
        f16x4 v = hp[(size_t)col[e] * 32 + li];
        a0 += (float)v.x; a1 += (float)v.y; a2 += (float)v.z; a3 += (float)v.w;
    }
    a0 += __shfl_xor(a0, 32, 64);
    a1 += __shfl_xor(a1, 32, 64);
    a2 += __shfl_xor(a2, 32, 64);
    a3 += __shfl_xor(a3, 32, 64);
    if (half == 0) {
        f16x4 o = {(f16)a0, (f16)a1, (f16)a2, (f16)a3};
        ((f16x4*)z)[(size_t)wid * 32 + li] = o;
    }
}

// ---------------- fused conv MLP (+ optional fc tail) ----------------
// Hout = relu( relu(Z@W1^T+b1) @ W2^T + b2 )   [128 rows per block]
// LAST: out = sigmoid( relu(Hout@fc1^T+fc1b) . fc2w + fc2b )
// LDS: As(32KB) + Ws(32KB); W2 / fc1w re-staged into Ws mid-kernel.
// XOR swizzle on 16B units: LDS[r][u] = G[r][u ^ (r&7)].
template <bool LAST>
__global__ __launch_bounds__(256) void conv_mlp_kernel(
    const f16* __restrict__ Z, const f16* __restrict__ W1f,
    const float* __restrict__ b1, const f16* __restrict__ W2f,
    const float* __restrict__ b2, f16* __restrict__ Hout, int M,
    const f16* __restrict__ fc1wf, const float* __restrict__ fc1b,
    const float* __restrict__ fc2w, const float* __restrict__ fc2b,
    float* __restrict__ out) {
    __shared__ __align__(16) f16 As[128 * 128];
    __shared__ __align__(16) f16 Ws[128 * 128];
    __shared__ float Red[LAST ? 128 * 17 : 1];

    const int tid = threadIdx.x;
    const int w = tid >> 6, lane = tid & 63;
    const int frow = lane & 15, kgrp = lane >> 4;
    const int m0 = blockIdx.x * 128;
    const int u = lane & 15, rsub = lane >> 4;

    // stage Z tile + W1 (both swizzled via pre-swizzled global source)
#pragma unroll
    for (int i = 0; i < 8; ++i) {
        int rowbase = (w * 8 + i) * 4;
        int r = rowbase + rsub;
        int gr = m0 + r;
        if (gr >= M) gr = M - 1;
        glds16(Z + (size_t)gr * 128 + ((u ^ (r & 7)) << 3), &As[rowbase * 128]);
    }
#pragma unroll
    for (int i = 0; i < 8; ++i) {
        int rowbase = (w * 8 + i) * 4;
        int r = rowbase + rsub;
        glds16(W1f + (size_t)r * 128 + ((u ^ (r & 7)) << 3), &Ws[rowbase * 128]);
    }
    __syncthreads();

    const int arow0 = w * 32 + frow;
    f32x4 acc[2][8];
#pragma unroll
    for (int mi = 0; mi < 2; ++mi)
#pragma unroll
        for (int nj = 0; nj < 8; ++nj) acc[mi][nj] = (f32x4){0.f, 0.f, 0.f, 0.f};

    // ---- GEMM1 ----
#pragma unroll
    for (int kk = 0; kk < 4; ++kk) {
        int kb = kk * 4 + kgrp;
        f16x8 a[2], b[8];
#pragma unroll
        for (int mi = 0; mi < 2; ++mi) {
            int r = arow0 + mi * 16;
            a[mi] = *(const f16x8*)&As[r * 128 + ((kb ^ (r & 7)) << 3)];
        }
#pragma unroll
        for (int nj = 0; nj < 8; ++nj) {
            int r = nj * 16 + frow;
            b[nj] = *(const f16x8*)&Ws[r * 128 + ((kb ^ (r & 7)) << 3)];
        }
#pragma unroll
        for (int mi = 0; mi < 2; ++mi)
#pragma unroll
            for (int nj = 0; nj < 8; ++nj)
                acc[mi][nj] = __builtin_amdgcn_mfma_f32_16x16x32_f16(a[mi], b[nj],
                                                                     acc[mi][nj], 0, 0, 0);
    }
    __syncthreads();  // all As/Ws reads done

    // re-stage W2 into Ws (overlaps with the As epilogue writes below)
#pragma unroll
    for (int i = 0; i < 8; ++i) {
        int rowbase = (w * 8 + i) * 4;
        int r = rowbase + rsub;
        glds16(W2f + (size_t)r * 128 + ((u ^ (r & 7)) << 3), &Ws[rowbase * 128]);
    }
    // relu(acc + b1) -> As (swizzled, so GEMM2 fragment reads reuse the pattern)
    {
        float bv[8];
#pragma unroll
        for (int nj = 0; nj < 8; ++nj) bv[nj] = b1[nj * 16 + frow];
#pragma unroll
        for (int mi = 0; mi < 2; ++mi)
#pragma unroll
            for (int nj = 0; nj < 8; ++nj) {
                int row0 = w * 32 + mi * 16 + kgrp * 4;
                int c = nj * 16 + frow;
                int cu = c >> 3, cl = c & 7;
#pragma unroll
                for (int r = 0; r < 4; ++r) {
                    int rr = row0 + r;
                    As[rr * 128 + ((cu ^ (rr & 7)) << 3) + cl] =
                        (f16)fmaxf(acc[mi][nj][r] + bv[nj], 0.f);
                }
            }
    }
    __syncthreads();  // W2 staged + As epilogue visible

    // ---- GEMM2 ----
#pragma unroll
    for (int mi = 0; mi < 2; ++mi)
#pragma unroll
        for (int nj = 0; nj < 8; ++nj) acc[mi][nj] = (f32x4){0.f, 0.f, 0.f, 0.f};
#pragma unroll
    for (int kk = 0; kk < 4; ++kk) {
        int kb = kk * 4 + kgrp;
        f16x8 a[2], b[8];
#pragma unroll
        for (int mi = 0; mi < 2; ++mi) {
            int r = arow0 + mi * 16;
            a[mi] = *(const f16x8*)&As[r * 128 + ((kb ^ (r & 7)) << 3)];
        }
#pragma unroll
        for (int nj = 0; nj < 8; ++nj) {
            int r = nj * 16 + frow;
            b[nj] = *(const f16x8*)&Ws[r * 128 + ((kb ^ (r & 7)) << 3)];
        }
#pragma unroll
        for (int mi = 0; mi < 2; ++mi)
#pragma unroll
            for (int nj = 0; nj < 8; ++nj)
                acc[mi][nj] = __builtin_amdgcn_mfma_f32_16x16x32_f16(a[mi], b[nj],
                                                                     acc[mi][nj], 0, 0, 0);
    }

    float bv2[8];
#pragma unroll
    for (int nj = 0; nj < 8; ++nj) bv2[nj] = b2[nj * 16 + frow];

    if (!LAST) {
        __syncthreads();  // done reading As
        // relu(acc + b2) -> As linear -> coalesced store
#pragma unroll
        for (int mi = 0; mi < 2; ++mi)
#pragma unroll
            for (int nj = 0; nj < 8; ++nj) {
                int row0 = w * 32 + mi * 16 + kgrp * 4;
                int c = nj * 16 + frow;
#pragma unroll
                for (int r = 0; r < 4; ++r)
                    As[(row0 + r) * 128 + c] = (f16)fmaxf(acc[mi][nj][r] + bv2[nj], 0.f);
            }
        __syncthreads();
        for (int idx = tid; idx < 128 * 16; idx += 256) {
            int r = idx >> 4, q = idx & 15;
            int gm = m0 + r;
            if (gm < M)
                *(float4*)(Hout + (size_t)gm * 128 + q * 8) = *(const float4*)&As[r * 128 + q * 8];
        }
    } else {
        __syncthreads();  // done reading As/Ws
        // stage fc1w (64 rows) into Ws
#pragma unroll
        for (int i = 0; i < 4; ++i) {
            int rowbase = (w * 4 + i) * 4;
            int r = rowbase + rsub;
            glds16(fc1wf + (size_t)r * 128 + ((u ^ (r & 7)) << 3), &Ws[rowbase * 128]);
        }
        // h = relu(acc + b2) -> As swizzled
#pragma unroll
        for (int mi = 0; mi < 2; ++mi)
#pragma unroll
            for (int nj = 0; nj < 8; ++nj) {
                int row0 = w * 32 + mi * 16 + kgrp * 4;
                int c = nj * 16 + frow;
                int cu = c >> 3, cl = c & 7;
#pragma unroll
                for (int r = 0; r < 4; ++r) {
                    int rr = row0 + r;
                    As[rr * 128 + ((cu ^ (rr & 7)) << 3) + cl] =
                        (f16)fmaxf(acc[mi][nj][r] + bv2[nj], 0.f);
                }
            }
        __syncthreads();

        // ---- GEMM3: h @ fc1^T (NCOL=64) ----
        f32x4 acc3[2][4];
#pragma unroll
        for (int mi = 0; mi < 2; ++mi)
#pragma unroll
            for (int nj = 0; nj < 4; ++nj) acc3[mi][nj] = (f32x4){0.f, 0.f, 0.f, 0.f};
#pragma unroll
        for (int kk = 0; kk < 4; ++kk) {
            int kb = kk * 4 + kgrp;
            f16x8 a[2], b[4];
#pragma unroll
            for (int mi = 0; mi < 2; ++mi) {
                int r = arow0 + mi * 16;
                a[mi] = *(const f16x8*)&As[r * 128 + ((kb ^ (r & 7)) << 3)];
            }
#pragma unroll
            for (int nj = 0; nj < 4; ++nj) {
                int r = nj * 16 + frow;
                b[nj] = *(const f16x8*)&Ws[r * 128 + ((kb ^ (r & 7)) << 3)];
            }
#pragma unroll
            for (int mi = 0; mi < 2; ++mi)
#pragma unroll
                for (int nj = 0; nj < 4; ++nj)
                    acc3[mi][nj] = __builtin_amdgcn_mfma_f32_16x16x32_f16(a[mi], b[nj],
                                                                          acc3[mi][nj], 0, 0, 0);
        }
        float bvf[4], f2[4];
#pragma unroll
        for (int nj = 0; nj < 4; ++nj) {
            bvf[nj] = fc1b[nj * 16 + frow];
            f2[nj] = fc2w[nj * 16 + frow];
        }
        float part[2][4];
#pragma unroll
        for (int mi = 0; mi < 2; ++mi)
#pragma unroll
            for (int r = 0; r < 4; ++r) part[mi][r] = 0.f;
#pragma unroll
        for (int mi = 0; mi < 2; ++mi)
#pragma unroll
            for (int nj = 0; nj < 4; ++nj)
#pragma unroll
                for (int r = 0; r < 4; ++r)
                    part[mi][r] += fmaxf(acc3[mi][nj][r] + bvf[nj], 0.f) * f2[nj];
#pragma unroll
        for (int mi = 0; mi < 2; ++mi)
#pragma unroll
            for (int r = 0; r < 4; ++r)
                Red[(w * 32 + mi * 16 + kgrp * 4 + r) * 17 + frow] = part[mi][r];
        __syncthreads();
        if (tid < 128) {
            float s = fc2b[0];
#pragma unroll
            for (int q = 0; q < 16; ++q) s += Red[tid * 17 + q];
            int m = m0 + tid;
            if (m < M) out[m] = 1.f / (1.f + expf(-s));
        }
    }
}

// ---------------------------------------------------------------------------
extern "C" void kernel_launch(void* const* d_in, const int* in_sizes, int n_in,
                              void* d_out, int out_size, void* d_ws, size_t ws_size,
                              hipStream_t stream) {
    const float* x = (const float*)d_in[0];
    const int* ei = (const int*)d_in[1];
    const int N = in_sizes[0] / 128;
    const int E = in_sizes[1] / 2;
    const int* srcIdx = ei;
    const int* dstIdx = ei + E;

    const float* w1[3] = {(const float*)d_in[2], (const float*)d_in[7], (const float*)d_in[12]};
    const float* b1[3] = {(const float*)d_in[3], (const float*)d_in[8], (const float*)d_in[13]};
    const float* w2[3] = {(const float*)d_in[4], (const float*)d_in[9], (const float*)d_in[14]};
    const float* b2[3] = {(const float*)d_in[5], (const float*)d_in[10], (const float*)d_in[15]};
    const float* eps[3] = {(const float*)d_in[6], (const float*)d_in[11], (const float*)d_in[16]};
    const float* fc1w = (const float*)d_in[17];
    const float* fc1b = (const float*)d_in[18];
    const float* fc2w = (const float*)d_in[19];
    const float* fc2b = (const float*)d_in[20];

    // workspace carve
    char* ws = (char*)d_ws;
    size_t p = 0;
    auto carve = [&](size_t bytes) -> char* {
        char* r = ws + p;
        p = (p + bytes + 255) & ~(size_t)255;
        return r;
    };
    int* deg = (int*)carve((size_t)N * 4);
    int* offs = (int*)carve((size_t)(N + 1) * 4);
    int* cursor = (int*)carve((size_t)N * 4);
    int* col = (int*)carve((size_t)E * 4);
    int* bsum = (int*)carve(128 * 4);
    int* bbase = (int*)carve(128 * 4);
    f16* H0 = (f16*)carve((size_t)N * 128 * 2);
    f16* H1 = (f16*)carve((size_t)N * 128 * 2);
    f16* Z = (f16*)carve((size_t)N * 128 * 2);
    f16* w1f[3], *w2f[3];
    for (int i = 0; i < 3; ++i) {
        w1f[i] = (f16*)carve(128 * 128 * 2);
        w2f[i] = (f16*)carve(128 * 128 * 2);
    }
    f16* fc1wf = (f16*)carve(64 * 128 * 2);
    (void)ws_size;

    const int SB = (N + 1023) / 1024;  // scan chunks (<=128)

    // ---- build CSR (once; shared by all 3 convs) ----
    hipMemsetAsync(deg, 0, (size_t)N * 4, stream);
    count_kernel<<<1024, 256, 0, stream>>>(dstIdx, deg, E);
    scan_partial<<<SB, 256, 0, stream>>>(deg, bsum, N);
    scan_bsum<<<1, 128, 0, stream>>>(bsum, bbase, SB, offs + N);
    scan_final<<<SB, 256, 0, stream>>>(deg, bbase, offs, cursor, N);
    fill_kernel<<<2048, 256, 0, stream>>>(srcIdx, dstIdx, cursor, col, E, N);

    // ---- fp32 -> f16: x and all MFMA weights ----
    cvt4_kernel<<<2048, 256, 0, stream>>>(x, H0, N * 128 / 4);
    CvtPack cp;
    for (int i = 0; i < 3; ++i) {
        cp.s[i] = w1[i];     cp.d[i] = w1f[i];     cp.nq[i] = 128 * 128 / 4;
        cp.s[3 + i] = w2[i]; cp.d[3 + i] = w2f[i]; cp.nq[3 + i] = 128 * 128 / 4;
    }
    cp.s[6] = fc1w; cp.d[6] = fc1wf; cp.nq[6] = 64 * 128 / 4;
    cvt_pack_kernel<<<dim3(16, 7), 256, 0, stream>>>(cp);

    const int aggGrid = (N + 3) / 4;
    const int gemmGrid = (N + 127) / 128;

    // conv0: H0 -> Z -> H1 ; conv1: H1 -> Z -> H0 ; conv2: H0 -> Z -> out
    agg_kernel<<<aggGrid, 256, 0, stream>>>(H0, offs, col, eps[0], Z, N);
    conv_mlp_kernel<false><<<gemmGrid, 256, 0, stream>>>(
        Z, w1f[0], b1[0], w2f[0], b2[0], H1, N, nullptr, nullptr, nullptr, nullptr, nullptr);
    agg_kernel<<<aggGrid, 256, 0, stream>>>(H1, offs, col, eps[1], Z, N);
    conv_mlp_kernel<false><<<gemmGrid, 256, 0, stream>>>(
        Z, w1f[1], b1[1], w2f[1], b2[1], H0, N, nullptr, nullptr, nullptr, nullptr, nullptr);
    agg_kernel<<<aggGrid, 256, 0, stream>>>(H0, offs, col, eps[2], Z, N);
    conv_mlp_kernel<true><<<gemmGrid, 256, 0, stream>>>(
        Z, w1f[2], b1[2], w2f[2], b2[2], nullptr, N, fc1wf, fc1b, fc2w, fc2b, (float*)d_out);
}

// Round 6
// 302.416 us; speedup vs baseline: 4.9901x; 1.3542x over previous
//
#include <hip/hip_runtime.h>
#include <math.h>

// ---------------------------------------------------------------------------
// GIN network on MI355X — round 6.
//  - CSR build rewritten as deterministic two-level binning (no random-scatter
//    atomics): per-block bucket counts -> exact scan -> private-slice binning
//    (coalesced 128B runs) -> per-bucket LDS assembly with fully coalesced
//    col/offs writes. Replaces count/fill (was ~100us, 73MB write amp).
//  - agg / fused conv MLP unchanged from round 5.
// ---------------------------------------------------------------------------

using f16   = _Float16;
using f16x4 = __attribute__((ext_vector_type(4))) _Float16;
using f16x8 = __attribute__((ext_vector_type(8))) _Float16;
using f32x4 = __attribute__((ext_vector_type(4))) float;

constexpr int BINBLK = 256;   // binning grid (blocks); count matrix columns

__device__ inline void glds16(const void* g, void* l) {
    __builtin_amdgcn_global_load_lds(
        (const __attribute__((address_space(1))) void*)g,
        (__attribute__((address_space(3))) void*)l, 16, 0, 0);
}

// ---------------- CSR build: two-level binning ----------------
// bucket = dst >> 8  (256 nodes per bucket)

__global__ __launch_bounds__(512) void bucket_count_kernel(const int* __restrict__ dst,
                                                           int* __restrict__ cntM,
                                                           int E, int nbuck) {
    __shared__ int cnt[512];
    for (int i = threadIdx.x; i < nbuck; i += 512) cnt[i] = 0;
    __syncthreads();
    int chunk = (E + gridDim.x - 1) / gridDim.x;
    int lo = blockIdx.x * chunk, hi = min(lo + chunk, E);
    for (int e = lo + threadIdx.x; e < hi; e += 512)
        atomicAdd(&cnt[dst[e] >> 8], 1);
    __syncthreads();
    for (int i = threadIdx.x; i < nbuck; i += 512)
        cntM[(size_t)i * gridDim.x + blockIdx.x] = cnt[i];
}

// per-1024-chunk sums (generic scan, n up to 128*1024)
__global__ __launch_bounds__(256) void scan_partial(const int* __restrict__ deg,
                                                    int* __restrict__ bsum, int n) {
    __shared__ int red[256];
    int b = blockIdx.x, t = threadIdx.x;
    int base = b * 1024;
    int s = 0;
#pragma unroll
    for (int j = 0; j < 4; ++j) {
        int idx = base + j * 256 + t;
        if (idx < n) s += deg[idx];
    }
    red[t] = s;
    __syncthreads();
    for (int d = 128; d > 0; d >>= 1) {
        if (t < d) red[t] += red[t + d];
        __syncthreads();
    }
    if (t == 0) bsum[b] = red[0];
}

__global__ __launch_bounds__(128) void scan_bsum(const int* __restrict__ bsum,
                                                 int* __restrict__ bbase, int nb,
                                                 int* __restrict__ total_out) {
    __shared__ int s[128];
    int t = threadIdx.x;
    s[t] = (t < nb) ? bsum[t] : 0;
    __syncthreads();
    for (int d = 1; d < 128; d <<= 1) {
        int v = (t >= d) ? s[t - d] : 0;
        __syncthreads();
        s[t] += v;
        __syncthreads();
    }
    bbase[t] = (t > 0) ? s[t - 1] : 0;
    if (t == 127) total_out[0] = s[127];
}

__global__ __launch_bounds__(256) void scan_final(const int* __restrict__ deg,
                                                  const int* __restrict__ bbase,
                                                  int* __restrict__ outA,
                                                  int* __restrict__ outB, int n) {
    __shared__ int red[256];
    int b = blockIdx.x, t = threadIdx.x;
    int base = b * 1024 + t * 4;
    int d0 = 0, d1 = 0, d2 = 0, d3 = 0;
    if (base + 3 < n) {
        int4 v = *(const int4*)&deg[base];
        d0 = v.x; d1 = v.y; d2 = v.z; d3 = v.w;
    } else {
        if (base < n) d0 = deg[base];
        if (base + 1 < n) d1 = deg[base + 1];
        if (base + 2 < n) d2 = deg[base + 2];
    }
    red[t] = d0 + d1 + d2 + d3;
    __syncthreads();
    for (int d = 1; d < 256; d <<= 1) {
        int v = (t >= d) ? red[t - d] : 0;
        __syncthreads();
        red[t] += v;
        __syncthreads();
    }
    int ex = bbase[b] + ((t > 0) ? red[t - 1] : 0);
    int o0 = ex, o1 = ex + d0, o2 = o1 + d1, o3 = o2 + d2;
    if (base + 3 < n) {
        *(int4*)&outA[base] = make_int4(o0, o1, o2, o3);
        *(int4*)&outB[base] = make_int4(o0, o1, o2, o3);
    } else {
        if (base < n) { outA[base] = o0; outB[base] = o0; }
        if (base + 1 < n) { outA[base + 1] = o1; outB[base + 1] = o1; }
        if (base + 2 < n) { outA[base + 2] = o2; outB[base + 2] = o2; }
    }
}

// bin edges into bucket-major staging; each block appends only into its own
// exact-sized [bucket][block] slice -> sequential ~128B runs, no global atomics.
__global__ __launch_bounds__(512) void bin_kernel(const int* __restrict__ src,
                                                  const int* __restrict__ dst,
                                                  const int* __restrict__ baseM,
                                                  int2* __restrict__ stage, int E, int nbuck) {
    __shared__ int cur[512];
    for (int i = threadIdx.x; i < nbuck; i += 512)
        cur[i] = baseM[(size_t)i * gridDim.x + blockIdx.x];
    __syncthreads();
    int chunk = (E + gridDim.x - 1) / gridDim.x;
    int lo = blockIdx.x * chunk, hi = min(lo + chunk, E);
    for (int e = lo + threadIdx.x; e < hi; e += 512) {
        int d = dst[e];
        int p = atomicAdd(&cur[d >> 8], 1);
        stage[p] = make_int2(src[e], d);
    }
}

// per-bucket assembly: LDS count+scan -> offs (coalesced), LDS colbuf -> col
// (coalesced). Fallback path for >CAP buckets keeps correctness always.
__global__ __launch_bounds__(256) void csr_kernel(const int2* __restrict__ stage,
                                                  const int* __restrict__ baseM,
                                                  int* __restrict__ offs,
                                                  int* __restrict__ col,
                                                  int E, int N, int nbuck, int binblk) {
    constexpr int CAP = 10240;
    __shared__ int cnt[256];
    __shared__ int sc[256];
    __shared__ int colbuf[CAP];
    int b = blockIdx.x, t = threadIdx.x;
    int base = baseM[(size_t)b * binblk];
    int end = (b + 1 < nbuck) ? baseM[(size_t)(b + 1) * binblk] : E;
    cnt[t] = 0;
    __syncthreads();
    for (int e = base + t; e < end; e += 256)
        atomicAdd(&cnt[stage[e].y & 255], 1);
    __syncthreads();
    int myCnt = cnt[t];
    sc[t] = myCnt;
    __syncthreads();
    for (int d = 1; d < 256; d <<= 1) {
        int u = (t >= d) ? sc[t - d] : 0;
        __syncthreads();
        sc[t] += u;
        __syncthreads();
    }
    int myExcl = sc[t] - myCnt;
    int node = b * 256 + t;
    if (node <= N) offs[node] = base + myExcl;
    cnt[t] = myExcl;  // reuse as cursor
    __syncthreads();
    for (int e = base + t; e < end; e += 256) {
        int2 sd = stage[e];
        int p = atomicAdd(&cnt[sd.y & 255], 1);
        if (p < CAP) colbuf[p] = sd.x;
        else col[base + p] = sd.x;
    }
    __syncthreads();
    int lim = min(end - base, CAP);
    for (int i = t; i < lim; i += 256) col[base + i] = colbuf[i];
}

// ---------------- fp32 -> f16 conversions ----------------
__global__ void cvt4_kernel(const float* __restrict__ in, f16* __restrict__ out, int nq) {
    int stride = gridDim.x * blockDim.x;
    for (int i = blockIdx.x * blockDim.x + threadIdx.x; i < nq; i += stride) {
        float4 v = *(const float4*)(in + (size_t)i * 4);
        f16x4 o = {(f16)v.x, (f16)v.y, (f16)v.z, (f16)v.w};
        *(f16x4*)(out + (size_t)i * 4) = o;
    }
}

struct CvtPack {
    const float* s[7];
    f16* d[7];
    int nq[7];
};
__global__ void cvt_pack_kernel(CvtPack p) {
    int seg = blockIdx.y;
    int nq = p.nq[seg];
    const float* in = p.s[seg];
    f16* out = p.d[seg];
    int stride = gridDim.x * blockDim.x;
    for (int i = blockIdx.x * blockDim.x + threadIdx.x; i < nq; i += stride) {
        float4 v = *(const float4*)(in + (size_t)i * 4);
        f16x4 o = {(f16)v.x, (f16)v.y, (f16)v.z, (f16)v.w};
        *(f16x4*)(out + (size_t)i * 4) = o;
    }
}

// ---------------- aggregation: z[n] = (1+eps)*h[n] + sum h[nbr] ----------------
__global__ __launch_bounds__(256) void agg_kernel(const f16* __restrict__ h,
                                                  const int* __restrict__ offs,
                                                  const int* __restrict__ col,
                                                  const float* __restrict__ epsp,
                                                  f16* __restrict__ z, int n) {
    int wid = blockIdx.x * 4 + (threadIdx.x >> 6);
    if (wid >= n) return;
    int lane = threadIdx.x & 63;
    int half = lane >> 5, li = lane & 31;
    const f16x4* hp = (const f16x4*)h;  // row stride = 32 f16x4
    float e1 = 1.0f + epsp[0];
    f16x4 self = hp[(size_t)wid * 32 + li];
    float sc = half ? 0.f : e1;
    float a0 = (float)self.x * sc, a1 = (float)self.y * sc;
    float a2 = (float)self.z * sc, a3 = (float)self.w * sc;
    int lo = offs[wid], hi = offs[wid + 1];
    int e = lo + half;
    for (; e + 14 < hi; e += 16) {
        f16x4 v[8];
#pragma unroll
        for (int j = 0; j < 8; ++j) v[j] = hp[(size_t)col[e + 2 * j] * 32 + li];
#pragma unroll
        for (int j = 0; j < 8; ++j) {
            a0 += (float)v[j].x; a1 += (float)v[j].y;
            a2 += (float)v[j].z; a3 += (float)v[j].w;
        }
    }
    for (; e + 6 < hi; e += 8) {
        f16x4 v[4];
#pragma unroll
        for (int j = 0; j < 4; ++j) v[j] = hp[(size_t)col[e + 2 * j] * 32 + li];
#pragma unroll
        for (int j = 0; j < 4; ++j) {
            a0 += (float)v[j].x; a1 += (float)v[j].y;
            a2 += (float)v[j].z; a3 += (float)v[j].w;
        }
    }
    for (; e < hi; e += 2) {
        f16x4 v = hp[(size_t)col[e] * 32 + li];
        a0 += (float)v.x; a1 += (float)v.y; a2 += (float)v.z; a3 += (float)v.w;
    }
    a0 += __shfl_xor(a0, 32, 64);
    a1 += __shfl_xor(a1, 32, 64);
    a2 += __shfl_xor(a2, 32, 64);
    a3 += __shfl_xor(a3, 32, 64);
    if (half == 0) {
        f16x4 o = {(f16)a0, (f16)a1, (f16)a2, (f16)a3};
        ((f16x4*)z)[(size_t)wid * 32 + li] = o;
    }
}

// ---------------- fused conv MLP (+ optional fc tail) ----------------
template <bool LAST>
__global__ __launch_bounds__(256) void conv_mlp_kernel(
    const f16* __restrict__ Z, const f16* __restrict__ W1f,
    const float* __restrict__ b1, const f16* __restrict__ W2f,
    const float* __restrict__ b2, f16* __restrict__ Hout, int M,
    const f16* __restrict__ fc1wf, const float* __restrict__ fc1b,
    const float* __restrict__ fc2w, const float* __restrict__ fc2b,
    float* __restrict__ out) {
    __shared__ __align__(16) f16 As[128 * 128];
    __shared__ __align__(16) f16 Ws[128 * 128];
    __shared__ float Red[LAST ? 128 * 17 : 1];

    const int tid = threadIdx.x;
    const int w = tid >> 6, lane = tid & 63;
    const int frow = lane & 15, kgrp = lane >> 4;
    const int m0 = blockIdx.x * 128;
    const int u = lane & 15, rsub = lane >> 4;

#pragma unroll
    for (int i = 0; i < 8; ++i) {
        int rowbase = (w * 8 + i) * 4;
        int r = rowbase + rsub;
        int gr = m0 + r;
        if (gr >= M) gr = M - 1;
        glds16(Z + (size_t)gr * 128 + ((u ^ (r & 7)) << 3), &As[rowbase * 128]);
    }
#pragma unroll
    for (int i = 0; i < 8; ++i) {
        int rowbase = (w * 8 + i) * 4;
        int r = rowbase + rsub;
        glds16(W1f + (size_t)r * 128 + ((u ^ (r & 7)) << 3), &Ws[rowbase * 128]);
    }
    __syncthreads();

    const int arow0 = w * 32 + frow;
    f32x4 acc[2][8];
#pragma unroll
    for (int mi = 0; mi < 2; ++mi)
#pragma unroll
        for (int nj = 0; nj < 8; ++nj) acc[mi][nj] = (f32x4){0.f, 0.f, 0.f, 0.f};

    // ---- GEMM1 ----
#pragma unroll
    for (int kk = 0; kk < 4; ++kk) {
        int kb = kk * 4 + kgrp;
        f16x8 a[2], b[8];
#pragma unroll
        for (int mi = 0; mi < 2; ++mi) {
            int r = arow0 + mi * 16;
            a[mi] = *(const f16x8*)&As[r * 128 + ((kb ^ (r & 7)) << 3)];
        }
#pragma unroll
        for (int nj = 0; nj < 8; ++nj) {
            int r = nj * 16 + frow;
            b[nj] = *(const f16x8*)&Ws[r * 128 + ((kb ^ (r & 7)) << 3)];
        }
#pragma unroll
        for (int mi = 0; mi < 2; ++mi)
#pragma unroll
            for (int nj = 0; nj < 8; ++nj)
                acc[mi][nj] = __builtin_amdgcn_mfma_f32_16x16x32_f16(a[mi], b[nj],
                                                                     acc[mi][nj], 0, 0, 0);
    }
    __syncthreads();

#pragma unroll
    for (int i = 0; i < 8; ++i) {
        int rowbase = (w * 8 + i) * 4;
        int r = rowbase + rsub;
        glds16(W2f + (size_t)r * 128 + ((u ^ (r & 7)) << 3), &Ws[rowbase * 128]);
    }
    {
        float bv[8];
#pragma unroll
        for (int nj = 0; nj < 8; ++nj) bv[nj] = b1[nj * 16 + frow];
#pragma unroll
        for (int mi = 0; mi < 2; ++mi)
#pragma unroll
            for (int nj = 0; nj < 8; ++nj) {
                int row0 = w * 32 + mi * 16 + kgrp * 4;
                int c = nj * 16 + frow;
                int cu = c >> 3, cl = c & 7;
#pragma unroll
                for (int r = 0; r < 4; ++r) {
                    int rr = row0 + r;
                    As[rr * 128 + ((cu ^ (rr & 7)) << 3) + cl] =
                        (f16)fmaxf(acc[mi][nj][r] + bv[nj], 0.f);
                }
            }
    }
    __syncthreads();

    // ---- GEMM2 ----
#pragma unroll
    for (int mi = 0; mi < 2; ++mi)
#pragma unroll
        for (int nj = 0; nj < 8; ++nj) acc[mi][nj] = (f32x4){0.f, 0.f, 0.f, 0.f};
#pragma unroll
    for (int kk = 0; kk < 4; ++kk) {
        int kb = kk * 4 + kgrp;
        f16x8 a[2], b[8];
#pragma unroll
        for (int mi = 0; mi < 2; ++mi) {
            int r = arow0 + mi * 16;
            a[mi] = *(const f16x8*)&As[r * 128 + ((kb ^ (r & 7)) << 3)];
        }
#pragma unroll
        for (int nj = 0; nj < 8; ++nj) {
            int r = nj * 16 + frow;
            b[nj] = *(const f16x8*)&Ws[r * 128 + ((kb ^ (r & 7)) << 3)];
        }
#pragma unroll
        for (int mi = 0; mi < 2; ++mi)
#pragma unroll
            for (int nj = 0; nj < 8; ++nj)
                acc[mi][nj] = __builtin_amdgcn_mfma_f32_16x16x32_f16(a[mi], b[nj],
                                                                     acc[mi][nj], 0, 0, 0);
    }

    float bv2[8];
#pragma unroll
    for (int nj = 0; nj < 8; ++nj) bv2[nj] = b2[nj * 16 + frow];

    if (!LAST) {
        __syncthreads();
#pragma unroll
        for (int mi = 0; mi < 2; ++mi)
#pragma unroll
            for (int nj = 0; nj < 8; ++nj) {
                int row0 = w * 32 + mi * 16 + kgrp * 4;
                int c = nj * 16 + frow;
#pragma unroll
                for (int r = 0; r < 4; ++r)
                    As[(row0 + r) * 128 + c] = (f16)fmaxf(acc[mi][nj][r] + bv2[nj], 0.f);
            }
        __syncthreads();
        for (int idx = tid; idx < 128 * 16; idx += 256) {
            int r = idx >> 4, q = idx & 15;
            int gm = m0 + r;
            if (gm < M)
                *(float4*)(Hout + (size_t)gm * 128 + q * 8) = *(const float4*)&As[r * 128 + q * 8];
        }
    } else {
        __syncthreads();
#pragma unroll
        for (int i = 0; i < 4; ++i) {
            int rowbase = (w * 4 + i) * 4;
            int r = rowbase + rsub;
            glds16(fc1wf + (size_t)r * 128 + ((u ^ (r & 7)) << 3), &Ws[rowbase * 128]);
        }
#pragma unroll
        for (int mi = 0; mi < 2; ++mi)
#pragma unroll
            for (int nj = 0; nj < 8; ++nj) {
                int row0 = w * 32 + mi * 16 + kgrp * 4;
                int c = nj * 16 + frow;
                int cu = c >> 3, cl = c & 7;
#pragma unroll
                for (int r = 0; r < 4; ++r) {
                    int rr = row0 + r;
                    As[rr * 128 + ((cu ^ (rr & 7)) << 3) + cl] =
                        (f16)fmaxf(acc[mi][nj][r] + bv2[nj], 0.f);
                }
            }
        __syncthreads();

        f32x4 acc3[2][4];
#pragma unroll
        for (int mi = 0; mi < 2; ++mi)
#pragma unroll
            for (int nj = 0; nj < 4; ++nj) acc3[mi][nj] = (f32x4){0.f, 0.f, 0.f, 0.f};
#pragma unroll
        for (int kk = 0; kk < 4; ++kk) {
            int kb = kk * 4 + kgrp;
            f16x8 a[2], b[4];
#pragma unroll
            for (int mi = 0; mi < 2; ++mi) {
                int r = arow0 + mi * 16;
                a[mi] = *(const f16x8*)&As[r * 128 + ((kb ^ (r & 7)) << 3)];
            }
#pragma unroll
            for (int nj = 0; nj < 4; ++nj) {
                int r = nj * 16 + frow;
                b[nj] = *(const f16x8*)&Ws[r * 128 + ((kb ^ (r & 7)) << 3)];
            }
#pragma unroll
            for (int mi = 0; mi < 2; ++mi)
#pragma unroll
                for (int nj = 0; nj < 4; ++nj)
                    acc3[mi][nj] = __builtin_amdgcn_mfma_f32_16x16x32_f16(a[mi], b[nj],
                                                                          acc3[mi][nj], 0, 0, 0);
        }
        float bvf[4], f2[4];
#pragma unroll
        for (int nj = 0; nj < 4; ++nj) {
            bvf[nj] = fc1b[nj * 16 + frow];
            f2[nj] = fc2w[nj * 16 + frow];
        }
        float part[2][4];
#pragma unroll
        for (int mi = 0; mi < 2; ++mi)
#pragma unroll
            for (int r = 0; r < 4; ++r) part[mi][r] = 0.f;
#pragma unroll
        for (int mi = 0; mi < 2; ++mi)
#pragma unroll
            for (int nj = 0; nj < 4; ++nj)
#pragma unroll
                for (int r = 0; r < 4; ++r)
                    part[mi][r] += fmaxf(acc3[mi][nj][r] + bvf[nj], 0.f) * f2[nj];
#pragma unroll
        for (int mi = 0; mi < 2; ++mi)
#pragma unroll
            for (int r = 0; r < 4; ++r)
                Red[(w * 32 + mi * 16 + kgrp * 4 + r) * 17 + frow] = part[mi][r];
        __syncthreads();
        if (tid < 128) {
            float s = fc2b[0];
#pragma unroll
            for (int q = 0; q < 16; ++q) s += Red[tid * 17 + q];
            int m = m0 + tid;
            if (m < M) out[m] = 1.f / (1.f + expf(-s));
        }
    }
}

// ---------------------------------------------------------------------------
extern "C" void kernel_launch(void* const* d_in, const int* in_sizes, int n_in,
                              void* d_out, int out_size, void* d_ws, size_t ws_size,
                              hipStream_t stream) {
    const float* x = (const float*)d_in[0];
    const int* ei = (const int*)d_in[1];
    const int N = in_sizes[0] / 128;
    const int E = in_sizes[1] / 2;
    const int* srcIdx = ei;
    const int* dstIdx = ei + E;

    const float* w1[3] = {(const float*)d_in[2], (const float*)d_in[7], (const float*)d_in[12]};
    const float* b1[3] = {(const float*)d_in[3], (const float*)d_in[8], (const float*)d_in[13]};
    const float* w2[3] = {(const float*)d_in[4], (const float*)d_in[9], (const float*)d_in[14]};
    const float* b2[3] = {(const float*)d_in[5], (const float*)d_in[10], (const float*)d_in[15]};
    const float* eps[3] = {(const float*)d_in[6], (const float*)d_in[11], (const float*)d_in[16]};
    const float* fc1w = (const float*)d_in[17];
    const float* fc1b = (const float*)d_in[18];
    const float* fc2w = (const float*)d_in[19];
    const float* fc2b = (const float*)d_in[20];

    // workspace carve
    char* ws = (char*)d_ws;
    size_t p = 0;
    auto carve = [&](size_t bytes) -> char* {
        char* r = ws + p;
        p = (p + bytes + 255) & ~(size_t)255;
        return r;
    };
    const int nbuck = (N + 255) >> 8;          // 256-node buckets
    const int nm = nbuck * BINBLK;             // count-matrix size
    int* offs = (int*)carve((size_t)(N + 1) * 4);
    int* col = (int*)carve((size_t)E * 4);
    int* cntM = (int*)carve((size_t)nm * 4);
    int* baseM = (int*)carve((size_t)nm * 4);
    int* baseM2 = (int*)carve((size_t)nm * 4);  // scan scratch (unused copy)
    int* bsum = (int*)carve(128 * 4);
    int* bbase = (int*)carve(128 * 4);
    int* tot = (int*)carve(4);
    int2* stage = (int2*)carve((size_t)E * 8);
    f16* H0 = (f16*)carve((size_t)N * 128 * 2);
    f16* H1 = (f16*)carve((size_t)N * 128 * 2);
    f16* Z = (f16*)carve((size_t)N * 128 * 2);
    f16* w1f[3], *w2f[3];
    for (int i = 0; i < 3; ++i) {
        w1f[i] = (f16*)carve(128 * 128 * 2);
        w2f[i] = (f16*)carve(128 * 128 * 2);
    }
    f16* fc1wf = (f16*)carve(64 * 128 * 2);
    (void)ws_size;

    // ---- build CSR (deterministic two-level binning) ----
    const int SB2 = (nm + 1023) / 1024;  // <=128 for nbuck*256 <= 128K
    bucket_count_kernel<<<BINBLK, 512, 0, stream>>>(dstIdx, cntM, E, nbuck);
    scan_partial<<<SB2, 256, 0, stream>>>(cntM, bsum, nm);
    scan_bsum<<<1, 128, 0, stream>>>(bsum, bbase, SB2, tot);
    scan_final<<<SB2, 256, 0, stream>>>(cntM, bbase, baseM, baseM2, nm);
    bin_kernel<<<BINBLK, 512, 0, stream>>>(srcIdx, dstIdx, baseM, stage, E, nbuck);
    csr_kernel<<<nbuck, 256, 0, stream>>>(stage, baseM, offs, col, E, N, nbuck, BINBLK);

    // ---- fp32 -> f16: x and all MFMA weights ----
    cvt4_kernel<<<2048, 256, 0, stream>>>(x, H0, N * 128 / 4);
    CvtPack cp;
    for (int i = 0; i < 3; ++i) {
        cp.s[i] = w1[i];     cp.d[i] = w1f[i];     cp.nq[i] = 128 * 128 / 4;
        cp.s[3 + i] = w2[i]; cp.d[3 + i] = w2f[i]; cp.nq[3 + i] = 128 * 128 / 4;
    }
    cp.s[6] = fc1w; cp.d[6] = fc1wf; cp.nq[6] = 64 * 128 / 4;
    cvt_pack_kernel<<<dim3(16, 7), 256, 0, stream>>>(cp);

    const int aggGrid = (N + 3) / 4;
    const int gemmGrid = (N + 127) / 128;

    // conv0: H0 -> Z -> H1 ; conv1: H1 -> Z -> H0 ; conv2: H0 -> Z -> out
    agg_kernel<<<aggGrid, 256, 0, stream>>>(H0, offs, col, eps[0], Z, N);
    conv_mlp_kernel<false><<<gemmGrid, 256, 0, stream>>>(
        Z, w1f[0], b1[0], w2f[0], b2[0], H1, N, nullptr, nullptr, nullptr, nullptr, nullptr);
    agg_kernel<<<aggGrid, 256, 0, stream>>>(H1, offs, col, eps[1], Z, N);
    conv_mlp_kernel<false><<<gemmGrid, 256, 0, stream>>>(
        Z, w1f[1], b1[1], w2f[1], b2[1], H0, N, nullptr, nullptr, nullptr, nullptr, nullptr);
    agg_kernel<<<aggGrid, 256, 0, stream>>>(H0, offs, col, eps[2], Z, N);
    conv_mlp_kernel<true><<<gemmGrid, 256, 0, stream>>>(
        Z, w1f[2], b1[2], w2f[2], b2[2], nullptr, N, fc1wf, fc1b, fc2w, fc2b, (float*)d_out);
}

// Round 7
// 299.917 us; speedup vs baseline: 5.0317x; 1.0083x over previous
//
#include <hip/hip_runtime.h>
#include <math.h>

// ---------------------------------------------------------------------------
// GIN network on MI355X — round 7.
//  - agg_kernel v3: 2 nodes per wave (one per 32-lane half), each half walks
//    its own edge list with 8-deep index prefetch + 8-deep row gather
//    (16 rows in flight per wave), nontemporal z stores. No cross-half
//    combine; store is 512B contiguous per wave.
//  - CSR two-level binning + fused conv MLP unchanged from round 6.
// ---------------------------------------------------------------------------

using f16   = _Float16;
using f16x4 = __attribute__((ext_vector_type(4))) _Float16;
using f16x8 = __attribute__((ext_vector_type(8))) _Float16;
using f32x4 = __attribute__((ext_vector_type(4))) float;

constexpr int BINBLK = 256;   // binning grid (blocks); count matrix columns

__device__ inline void glds16(const void* g, void* l) {
    __builtin_amdgcn_global_load_lds(
        (const __attribute__((address_space(1))) void*)g,
        (__attribute__((address_space(3))) void*)l, 16, 0, 0);
}

// ---------------- CSR build: two-level binning ----------------
// bucket = dst >> 8  (256 nodes per bucket)

__global__ __launch_bounds__(512) void bucket_count_kernel(const int* __restrict__ dst,
                                                           int* __restrict__ cntM,
                                                           int E, int nbuck) {
    __shared__ int cnt[512];
    for (int i = threadIdx.x; i < nbuck; i += 512) cnt[i] = 0;
    __syncthreads();
    int chunk = (E + gridDim.x - 1) / gridDim.x;
    int lo = blockIdx.x * chunk, hi = min(lo + chunk, E);
    for (int e = lo + threadIdx.x; e < hi; e += 512)
        atomicAdd(&cnt[dst[e] >> 8], 1);
    __syncthreads();
    for (int i = threadIdx.x; i < nbuck; i += 512)
        cntM[(size_t)i * gridDim.x + blockIdx.x] = cnt[i];
}

// per-1024-chunk sums (generic scan, n up to 128*1024)
__global__ __launch_bounds__(256) void scan_partial(const int* __restrict__ deg,
                                                    int* __restrict__ bsum, int n) {
    __shared__ int red[256];
    int b = blockIdx.x, t = threadIdx.x;
    int base = b * 1024;
    int s = 0;
#pragma unroll
    for (int j = 0; j < 4; ++j) {
        int idx = base + j * 256 + t;
        if (idx < n) s += deg[idx];
    }
    red[t] = s;
    __syncthreads();
    for (int d = 128; d > 0; d >>= 1) {
        if (t < d) red[t] += red[t + d];
        __syncthreads();
    }
    if (t == 0) bsum[b] = red[0];
}

__global__ __launch_bounds__(128) void scan_bsum(const int* __restrict__ bsum,
                                                 int* __restrict__ bbase, int nb,
                                                 int* __restrict__ total_out) {
    __shared__ int s[128];
    int t = threadIdx.x;
    s[t] = (t < nb) ? bsum[t] : 0;
    __syncthreads();
    for (int d = 1; d < 128; d <<= 1) {
        int v = (t >= d) ? s[t - d] : 0;
        __syncthreads();
        s[t] += v;
        __syncthreads();
    }
    bbase[t] = (t > 0) ? s[t - 1] : 0;
    if (t == 127) total_out[0] = s[127];
}

__global__ __launch_bounds__(256) void scan_final(const int* __restrict__ deg,
                                                  const int* __restrict__ bbase,
                                                  int* __restrict__ outA,
                                                  int* __restrict__ outB, int n) {
    __shared__ int red[256];
    int b = blockIdx.x, t = threadIdx.x;
    int base = b * 1024 + t * 4;
    int d0 = 0, d1 = 0, d2 = 0, d3 = 0;
    if (base + 3 < n) {
        int4 v = *(const int4*)&deg[base];
        d0 = v.x; d1 = v.y; d2 = v.z; d3 = v.w;
    } else {
        if (base < n) d0 = deg[base];
        if (base + 1 < n) d1 = deg[base + 1];
        if (base + 2 < n) d2 = deg[base + 2];
    }
    red[t] = d0 + d1 + d2 + d3;
    __syncthreads();
    for (int d = 1; d < 256; d <<= 1) {
        int v = (t >= d) ? red[t - d] : 0;
        __syncthreads();
        red[t] += v;
        __syncthreads();
    }
    int ex = bbase[b] + ((t > 0) ? red[t - 1] : 0);
    int o0 = ex, o1 = ex + d0, o2 = o1 + d1, o3 = o2 + d2;
    if (base + 3 < n) {
        *(int4*)&outA[base] = make_int4(o0, o1, o2, o3);
        *(int4*)&outB[base] = make_int4(o0, o1, o2, o3);
    } else {
        if (base < n) { outA[base] = o0; outB[base] = o0; }
        if (base + 1 < n) { outA[base + 1] = o1; outB[base + 1] = o1; }
        if (base + 2 < n) { outA[base + 2] = o2; outB[base + 2] = o2; }
    }
}

// bin edges into bucket-major staging; each block appends only into its own
// exact-sized [bucket][block] slice -> sequential ~128B runs, no global atomics.
__global__ __launch_bounds__(512) void bin_kernel(const int* __restrict__ src,
                                                  const int* __restrict__ dst,
                                                  const int* __restrict__ baseM,
                                                  int2* __restrict__ stage, int E, int nbuck) {
    __shared__ int cur[512];
    for (int i = threadIdx.x; i < nbuck; i += 512)
        cur[i] = baseM[(size_t)i * gridDim.x + blockIdx.x];
    __syncthreads();
    int chunk = (E + gridDim.x - 1) / gridDim.x;
    int lo = blockIdx.x * chunk, hi = min(lo + chunk, E);
    for (int e = lo + threadIdx.x; e < hi; e += 512) {
        int d = dst[e];
        int p = atomicAdd(&cur[d >> 8], 1);
        stage[p] = make_int2(src[e], d);
    }
}

// per-bucket assembly: LDS count+scan -> offs (coalesced), LDS colbuf -> col
// (coalesced). Fallback path for >CAP buckets keeps correctness always.
__global__ __launch_bounds__(256) void csr_kernel(const int2* __restrict__ stage,
                                                  const int* __restrict__ baseM,
                                                  int* __restrict__ offs,
                                                  int* __restrict__ col,
                                                  int E, int N, int nbuck, int binblk) {
    constexpr int CAP = 10240;
    __shared__ int cnt[256];
    __shared__ int sc[256];
    __shared__ int colbuf[CAP];
    int b = blockIdx.x, t = threadIdx.x;
    int base = baseM[(size_t)b * binblk];
    int end = (b + 1 < nbuck) ? baseM[(size_t)(b + 1) * binblk] : E;
    cnt[t] = 0;
    __syncthreads();
    for (int e = base + t; e < end; e += 256)
        atomicAdd(&cnt[stage[e].y & 255], 1);
    __syncthreads();
    int myCnt = cnt[t];
    sc[t] = myCnt;
    __syncthreads();
    for (int d = 1; d < 256; d <<= 1) {
        int u = (t >= d) ? sc[t - d] : 0;
        __syncthreads();
        sc[t] += u;
        __syncthreads();
    }
    int myExcl = sc[t] - myCnt;
    int node = b * 256 + t;
    if (node <= N) offs[node] = base + myExcl;
    cnt[t] = myExcl;  // reuse as cursor
    __syncthreads();
    for (int e = base + t; e < end; e += 256) {
        int2 sd = stage[e];
        int p = atomicAdd(&cnt[sd.y & 255], 1);
        if (p < CAP) colbuf[p] = sd.x;
        else col[base + p] = sd.x;
    }
    __syncthreads();
    int lim = min(end - base, CAP);
    for (int i = t; i < lim; i += 256) col[base + i] = colbuf[i];
}

// ---------------- fp32 -> f16 conversions ----------------
__global__ void cvt4_kernel(const float* __restrict__ in, f16* __restrict__ out, int nq) {
    int stride = gridDim.x * blockDim.x;
    for (int i = blockIdx.x * blockDim.x + threadIdx.x; i < nq; i += stride) {
        float4 v = *(const float4*)(in + (size_t)i * 4);
        f16x4 o = {(f16)v.x, (f16)v.y, (f16)v.z, (f16)v.w};
        *(f16x4*)(out + (size_t)i * 4) = o;
    }
}

struct CvtPack {
    const float* s[7];
    f16* d[7];
    int nq[7];
};
__global__ void cvt_pack_kernel(CvtPack p) {
    int seg = blockIdx.y;
    int nq = p.nq[seg];
    const float* in = p.s[seg];
    f16* out = p.d[seg];
    int stride = gridDim.x * blockDim.x;
    for (int i = blockIdx.x * blockDim.x + threadIdx.x; i < nq; i += stride) {
        float4 v = *(const float4*)(in + (size_t)i * 4);
        f16x4 o = {(f16)v.x, (f16)v.y, (f16)v.z, (f16)v.w};
        *(f16x4*)(out + (size_t)i * 4) = o;
    }
}

// ---------------- aggregation: z[n] = (1+eps)*h[n] + sum h[nbr] ----------------
// Two nodes per wave: each 32-lane half owns one node (f16x4 = 8B per lane,
// 32 lanes cover the 256B row) and walks its own edge list. 8-deep index
// prefetch + 8-deep row gather => 16 rows in flight per wave. Nontemporal z.
__global__ __launch_bounds__(256) void agg_kernel(const f16* __restrict__ h,
                                                  const int* __restrict__ offs,
                                                  const int* __restrict__ col,
                                                  const float* __restrict__ epsp,
                                                  f16* __restrict__ z, int n) {
    int node = blockIdx.x * 8 + (threadIdx.x >> 5);
    int li = threadIdx.x & 31;
    bool valid = node < n;
    int nd = valid ? node : (n - 1);
    const f16x4* hp = (const f16x4*)h;  // row stride = 32 f16x4
    float e1 = 1.0f + epsp[0];
    f16x4 self = hp[(size_t)nd * 32 + li];
    float a0 = (float)self.x * e1, a1 = (float)self.y * e1;
    float a2 = (float)self.z * e1, a3 = (float)self.w * e1;
    int lo = offs[nd], hi = valid ? offs[nd + 1] : lo;

    int e = lo;
    for (; e + 8 <= hi; e += 8) {
        int idx[8];
#pragma unroll
        for (int j = 0; j < 8; ++j) idx[j] = col[e + j];
        f16x4 v[8];
#pragma unroll
        for (int j = 0; j < 8; ++j) v[j] = hp[(size_t)idx[j] * 32 + li];
#pragma unroll
        for (int j = 0; j < 8; ++j) {
            a0 += (float)v[j].x; a1 += (float)v[j].y;
            a2 += (float)v[j].z; a3 += (float)v[j].w;
        }
    }
    if (e + 4 <= hi) {
        int idx[4];
#pragma unroll
        for (int j = 0; j < 4; ++j) idx[j] = col[e + j];
        f16x4 v[4];
#pragma unroll
        for (int j = 0; j < 4; ++j) v[j] = hp[(size_t)idx[j] * 32 + li];
#pragma unroll
        for (int j = 0; j < 4; ++j) {
            a0 += (float)v[j].x; a1 += (float)v[j].y;
            a2 += (float)v[j].z; a3 += (float)v[j].w;
        }
        e += 4;
    }
    for (; e < hi; ++e) {
        f16x4 v = hp[(size_t)col[e] * 32 + li];
        a0 += (float)v.x; a1 += (float)v.y; a2 += (float)v.z; a3 += (float)v.w;
    }
    if (valid) {
        f16x4 o = {(f16)a0, (f16)a1, (f16)a2, (f16)a3};
        __builtin_nontemporal_store(o, (f16x4*)z + (size_t)nd * 32 + li);
    }
}

// ---------------- fused conv MLP (+ optional fc tail) ----------------
template <bool LAST>
__global__ __launch_bounds__(256) void conv_mlp_kernel(
    const f16* __restrict__ Z, const f16* __restrict__ W1f,
    const float* __restrict__ b1, const f16* __restrict__ W2f,
    const float* __restrict__ b2, f16* __restrict__ Hout, int M,
    const f16* __restrict__ fc1wf, const float* __restrict__ fc1b,
    const float* __restrict__ fc2w, const float* __restrict__ fc2b,
    float* __restrict__ out) {
    __shared__ __align__(16) f16 As[128 * 128];
    __shared__ __align__(16) f16 Ws[128 * 128];
    __shared__ float Red[LAST ? 128 * 17 : 1];

    const int tid = threadIdx.x;
    const int w = tid >> 6, lane = tid & 63;
    const int frow = lane & 15, kgrp = lane >> 4;
    const int m0 = blockIdx.x * 128;
    const int u = lane & 15, rsub = lane >> 4;

#pragma unroll
    for (int i = 0; i < 8; ++i) {
        int rowbase = (w * 8 + i) * 4;
        int r = rowbase + rsub;
        int gr = m0 + r;
        if (gr >= M) gr = M - 1;
        glds16(Z + (size_t)gr * 128 + ((u ^ (r & 7)) << 3), &As[rowbase * 128]);
    }
#pragma unroll
    for (int i = 0; i < 8; ++i) {
        int rowbase = (w * 8 + i) * 4;
        int r = rowbase + rsub;
        glds16(W1f + (size_t)r * 128 + ((u ^ (r & 7)) << 3), &Ws[rowbase * 128]);
    }
    __syncthreads();

    const int arow0 = w * 32 + frow;
    f32x4 acc[2][8];
#pragma unroll
    for (int mi = 0; mi < 2; ++mi)
#pragma unroll
        for (int nj = 0; nj < 8; ++nj) acc[mi][nj] = (f32x4){0.f, 0.f, 0.f, 0.f};

    // ---- GEMM1 ----
#pragma unroll
    for (int kk = 0; kk < 4; ++kk) {
        int kb = kk * 4 + kgrp;
        f16x8 a[2], b[8];
#pragma unroll
        for (int mi = 0; mi < 2; ++mi) {
            int r = arow0 + mi * 16;
            a[mi] = *(const f16x8*)&As[r * 128 + ((kb ^ (r & 7)) << 3)];
        }
#pragma unroll
        for (int nj = 0; nj < 8; ++nj) {
            int r = nj * 16 + frow;
            b[nj] = *(const f16x8*)&Ws[r * 128 + ((kb ^ (r & 7)) << 3)];
        }
#pragma unroll
        for (int mi = 0; mi < 2; ++mi)
#pragma unroll
            for (int nj = 0; nj < 8; ++nj)
                acc[mi][nj] = __builtin_amdgcn_mfma_f32_16x16x32_f16(a[mi], b[nj],
                                                                     acc[mi][nj], 0, 0, 0);
    }
    __syncthreads();

#pragma unroll
    for (int i = 0; i < 8; ++i) {
        int rowbase = (w * 8 + i) * 4;
        int r = rowbase + rsub;
        glds16(W2f + (size_t)r * 128 + ((u ^ (r & 7)) << 3), &Ws[rowbase * 128]);
    }
    {
        float bv[8];
#pragma unroll
        for (int nj = 0; nj < 8; ++nj) bv[nj] = b1[nj * 16 + frow];
#pragma unroll
        for (int mi = 0; mi < 2; ++mi)
#pragma unroll
            for (int nj = 0; nj < 8; ++nj) {
                int row0 = w * 32 + mi * 16 + kgrp * 4;
                int c = nj * 16 + frow;
                int cu = c >> 3, cl = c & 7;
#pragma unroll
                for (int r = 0; r < 4; ++r) {
                    int rr = row0 + r;
                    As[rr * 128 + ((cu ^ (rr & 7)) << 3) + cl] =
                        (f16)fmaxf(acc[mi][nj][r] + bv[nj], 0.f);
                }
            }
    }
    __syncthreads();

    // ---- GEMM2 ----
#pragma unroll
    for (int mi = 0; mi < 2; ++mi)
#pragma unroll
        for (int nj = 0; nj < 8; ++nj) acc[mi][nj] = (f32x4){0.f, 0.f, 0.f, 0.f};
#pragma unroll
    for (int kk = 0; kk < 4; ++kk) {
        int kb = kk * 4 + kgrp;
        f16x8 a[2], b[8];
#pragma unroll
        for (int mi = 0; mi < 2; ++mi) {
            int r = arow0 + mi * 16;
            a[mi] = *(const f16x8*)&As[r * 128 + ((kb ^ (r & 7)) << 3)];
        }
#pragma unroll
        for (int nj = 0; nj < 8; ++nj) {
            int r = nj * 16 + frow;
            b[nj] = *(const f16x8*)&Ws[r * 128 + ((kb ^ (r & 7)) << 3)];
        }
#pragma unroll
        for (int mi = 0; mi < 2; ++mi)
#pragma unroll
            for (int nj = 0; nj < 8; ++nj)
                acc[mi][nj] = __builtin_amdgcn_mfma_f32_16x16x32_f16(a[mi], b[nj],
                                                                     acc[mi][nj], 0, 0, 0);
    }

    float bv2[8];
#pragma unroll
    for (int nj = 0; nj < 8; ++nj) bv2[nj] = b2[nj * 16 + frow];

    if (!LAST) {
        __syncthreads();
#pragma unroll
        for (int mi = 0; mi < 2; ++mi)
#pragma unroll
            for (int nj = 0; nj < 8; ++nj) {
                int row0 = w * 32 + mi * 16 + kgrp * 4;
                int c = nj * 16 + frow;
#pragma unroll
                for (int r = 0; r < 4; ++r)
                    As[(row0 + r) * 128 + c] = (f16)fmaxf(acc[mi][nj][r] + bv2[nj], 0.f);
            }
        __syncthreads();
        for (int idx = tid; idx < 128 * 16; idx += 256) {
            int r = idx >> 4, q = idx & 15;
            int gm = m0 + r;
            if (gm < M)
                *(float4*)(Hout + (size_t)gm * 128 + q * 8) = *(const float4*)&As[r * 128 + q * 8];
        }
    } else {
        __syncthreads();
#pragma unroll
        for (int i = 0; i < 4; ++i) {
            int rowbase = (w * 4 + i) * 4;
            int r = rowbase + rsub;
            glds16(fc1wf + (size_t)r * 128 + ((u ^ (r & 7)) << 3), &Ws[rowbase * 128]);
        }
#pragma unroll
        for (int mi = 0; mi < 2; ++mi)
#pragma unroll
            for (int nj = 0; nj < 8; ++nj) {
                int row0 = w * 32 + mi * 16 + kgrp * 4;
                int c = nj * 16 + frow;
                int cu = c >> 3, cl = c & 7;
#pragma unroll
                for (int r = 0; r < 4; ++r) {
                    int rr = row0 + r;
                    As[rr * 128 + ((cu ^ (rr & 7)) << 3) + cl] =
                        (f16)fmaxf(acc[mi][nj][r] + bv2[nj], 0.f);
                }
            }
        __syncthreads();

        f32x4 acc3[2][4];
#pragma unroll
        for (int mi = 0; mi < 2; ++mi)
#pragma unroll
            for (int nj = 0; nj < 4; ++nj) acc3[mi][nj] = (f32x4){0.f, 0.f, 0.f, 0.f};
#pragma unroll
        for (int kk = 0; kk < 4; ++kk) {
            int kb = kk * 4 + kgrp;
            f16x8 a[2], b[4];
#pragma unroll
            for (int mi = 0; mi < 2; ++mi) {
                int r = arow0 + mi * 16;
                a[mi] = *(const f16x8*)&As[r * 128 + ((kb ^ (r & 7)) << 3)];
            }
#pragma unroll
            for (int nj = 0; nj < 4; ++nj) {
                int r = nj * 16 + frow;
                b[nj] = *(const f16x8*)&Ws[r * 128 + ((kb ^ (r & 7)) << 3)];
            }
#pragma unroll
            for (int mi = 0; mi < 2; ++mi)
#pragma unroll
                for (int nj = 0; nj < 4; ++nj)
                    acc3[mi][nj] = __builtin_amdgcn_mfma_f32_16x16x32_f16(a[mi], b[nj],
                                                                          acc3[mi][nj], 0, 0, 0);
        }
        float bvf[4], f2[4];
#pragma unroll
        for (int nj = 0; nj < 4; ++nj) {
            bvf[nj] = fc1b[nj * 16 + frow];
            f2[nj] = fc2w[nj * 16 + frow];
        }
        float part[2][4];
#pragma unroll
        for (int mi = 0; mi < 2; ++mi)
#pragma unroll
            for (int r = 0; r < 4; ++r) part[mi][r] = 0.f;
#pragma unroll
        for (int mi = 0; mi < 2; ++mi)
#pragma unroll
            for (int nj = 0; nj < 4; ++nj)
#pragma unroll
                for (int r = 0; r < 4; ++r)
                    part[mi][r] += fmaxf(acc3[mi][nj][r] + bvf[nj], 0.f) * f2[nj];
#pragma unroll
        for (int mi = 0; mi < 2; ++mi)
#pragma unroll
            for (int r = 0; r < 4; ++r)
                Red[(w * 32 + mi * 16 + kgrp * 4 + r) * 17 + frow] = part[mi][r];
        __syncthreads();
        if (tid < 128) {
            float s = fc2b[0];
#pragma unroll
            for (int q = 0; q < 16; ++q) s += Red[tid * 17 + q];
            int m = m0 + tid;
            if (m < M) out[m] = 1.f / (1.f + expf(-s));
        }
    }
}

// ---------------------------------------------------------------------------
extern "C" void kernel_launch(void* const* d_in, const int* in_sizes, int n_in,
                              void* d_out, int out_size, void* d_ws, size_t ws_size,
                              hipStream_t stream) {
    const float* x = (const float*)d_in[0];
    const int* ei = (const int*)d_in[1];
    const int N = in_sizes[0] / 128;
    const int E = in_sizes[1] / 2;
    const int* srcIdx = ei;
    const int* dstIdx = ei + E;

    const float* w1[3] = {(const float*)d_in[2], (const float*)d_in[7], (const float*)d_in[12]};
    const float* b1[3] = {(const float*)d_in[3], (const float*)d_in[8], (const float*)d_in[13]};
    const float* w2[3] = {(const float*)d_in[4], (const float*)d_in[9], (const float*)d_in[14]};
    const float* b2[3] = {(const float*)d_in[5], (const float*)d_in[10], (const float*)d_in[15]};
    const float* eps[3] = {(const float*)d_in[6], (const float*)d_in[11], (const float*)d_in[16]};
    const float* fc1w = (const float*)d_in[17];
    const float* fc1b = (const float*)d_in[18];
    const float* fc2w = (const float*)d_in[19];
    const float* fc2b = (const float*)d_in[20];

    // workspace carve
    char* ws = (char*)d_ws;
    size_t p = 0;
    auto carve = [&](size_t bytes) -> char* {
        char* r = ws + p;
        p = (p + bytes + 255) & ~(size_t)255;
        return r;
    };
    const int nbuck = (N + 255) >> 8;          // 256-node buckets
    const int nm = nbuck * BINBLK;             // count-matrix size
    int* offs = (int*)carve((size_t)(N + 1) * 4);
    int* col = (int*)carve((size_t)E * 4);
    int* cntM = (int*)carve((size_t)nm * 4);
    int* baseM = (int*)carve((size_t)nm * 4);
    int* baseM2 = (int*)carve((size_t)nm * 4);  // scan scratch (unused copy)
    int* bsum = (int*)carve(128 * 4);
    int* bbase = (int*)carve(128 * 4);
    int* tot = (int*)carve(4);
    int2* stage = (int2*)carve((size_t)E * 8);
    f16* H0 = (f16*)carve((size_t)N * 128 * 2);
    f16* H1 = (f16*)carve((size_t)N * 128 * 2);
    f16* Z = (f16*)carve((size_t)N * 128 * 2);
    f16* w1f[3], *w2f[3];
    for (int i = 0; i < 3; ++i) {
        w1f[i] = (f16*)carve(128 * 128 * 2);
        w2f[i] = (f16*)carve(128 * 128 * 2);
    }
    f16* fc1wf = (f16*)carve(64 * 128 * 2);
    (void)ws_size;

    // ---- build CSR (deterministic two-level binning) ----
    const int SB2 = (nm + 1023) / 1024;  // <=128 for nbuck*256 <= 128K
    bucket_count_kernel<<<BINBLK, 512, 0, stream>>>(dstIdx, cntM, E, nbuck);
    scan_partial<<<SB2, 256, 0, stream>>>(cntM, bsum, nm);
    scan_bsum<<<1, 128, 0, stream>>>(bsum, bbase, SB2, tot);
    scan_final<<<SB2, 256, 0, stream>>>(cntM, bbase, baseM, baseM2, nm);
    bin_kernel<<<BINBLK, 512, 0, stream>>>(srcIdx, dstIdx, baseM, stage, E, nbuck);
    csr_kernel<<<nbuck, 256, 0, stream>>>(stage, baseM, offs, col, E, N, nbuck, BINBLK);

    // ---- fp32 -> f16: x and all MFMA weights ----
    cvt4_kernel<<<2048, 256, 0, stream>>>(x, H0, N * 128 / 4);
    CvtPack cp;
    for (int i = 0; i < 3; ++i) {
        cp.s[i] = w1[i];     cp.d[i] = w1f[i];     cp.nq[i] = 128 * 128 / 4;
        cp.s[3 + i] = w2[i]; cp.d[3 + i] = w2f[i]; cp.nq[3 + i] = 128 * 128 / 4;
    }
    cp.s[6] = fc1w; cp.d[6] = fc1wf; cp.nq[6] = 64 * 128 / 4;
    cvt_pack_kernel<<<dim3(16, 7), 256, 0, stream>>>(cp);

    const int aggGrid = (N + 7) / 8;   // 2 nodes per wave, 4 waves per block
    const int gemmGrid = (N + 127) / 128;

    // conv0: H0 -> Z -> H1 ; conv1: H1 -> Z -> H0 ; conv2: H0 -> Z -> out
    agg_kernel<<<aggGrid, 256, 0, stream>>>(H0, offs, col, eps[0], Z, N);
    conv_mlp_kernel<false><<<gemmGrid, 256, 0, stream>>>(
        Z, w1f[0], b1[0], w2f[0], b2[0], H1, N, nullptr, nullptr, nullptr, nullptr, nullptr);
    agg_kernel<<<aggGrid, 256, 0, stream>>>(H1, offs, col, eps[1], Z, N);
    conv_mlp_kernel<false><<<gemmGrid, 256, 0, stream>>>(
        Z, w1f[1], b1[1], w2f[1], b2[1], H0, N, nullptr, nullptr, nullptr, nullptr, nullptr);
    agg_kernel<<<aggGrid, 256, 0, stream>>>(H0, offs, col, eps[2], Z, N);
    conv_mlp_kernel<true><<<gemmGrid, 256, 0, stream>>>(
        Z, w1f[2], b1[2], w2f[2], b2[2], nullptr, N, fc1wf, fc1b, fc2w, fc2b, (float*)d_out);
}

// Round 8
// 296.517 us; speedup vs baseline: 5.0894x; 1.0115x over previous
//
#include <hip/hip_runtime.h>
#include <math.h>

// ---------------------------------------------------------------------------
// GIN network on MI355X — round 8.
//  - agg_kernel v4: 4 nodes per wave (16-lane groups, f16x8 = 16B/lane so one
//    dwordx4 per row), 8-deep row pipeline => 32 rows (8KB) in flight per
//    wave (2x round 7). Kernel is latency-bound (VALUBusy 30%, 3.5 TB/s);
//    doubling per-wave MLP targets the gather rate, not volume.
//  - CSR two-level binning + fused conv MLP unchanged.
// ---------------------------------------------------------------------------

using f16   = _Float16;
using f16x4 = __attribute__((ext_vector_type(4))) _Float16;
using f16x8 = __attribute__((ext_vector_type(8))) _Float16;
using f32x4 = __attribute__((ext_vector_type(4))) float;

constexpr int BINBLK = 256;   // binning grid (blocks); count matrix columns

__device__ inline void glds16(const void* g, void* l) {
    __builtin_amdgcn_global_load_lds(
        (const __attribute__((address_space(1))) void*)g,
        (__attribute__((address_space(3))) void*)l, 16, 0, 0);
}

// ---------------- CSR build: two-level binning ----------------
// bucket = dst >> 8  (256 nodes per bucket)

__global__ __launch_bounds__(512) void bucket_count_kernel(const int* __restrict__ dst,
                                                           int* __restrict__ cntM,
                                                           int E, int nbuck) {
    __shared__ int cnt[512];
    for (int i = threadIdx.x; i < nbuck; i += 512) cnt[i] = 0;
    __syncthreads();
    int chunk = (E + gridDim.x - 1) / gridDim.x;
    int lo = blockIdx.x * chunk, hi = min(lo + chunk, E);
    for (int e = lo + threadIdx.x; e < hi; e += 512)
        atomicAdd(&cnt[dst[e] >> 8], 1);
    __syncthreads();
    for (int i = threadIdx.x; i < nbuck; i += 512)
        cntM[(size_t)i * gridDim.x + blockIdx.x] = cnt[i];
}

// per-1024-chunk sums (generic scan, n up to 128*1024)
__global__ __launch_bounds__(256) void scan_partial(const int* __restrict__ deg,
                                                    int* __restrict__ bsum, int n) {
    __shared__ int red[256];
    int b = blockIdx.x, t = threadIdx.x;
    int base = b * 1024;
    int s = 0;
#pragma unroll
    for (int j = 0; j < 4; ++j) {
        int idx = base + j * 256 + t;
        if (idx < n) s += deg[idx];
    }
    red[t] = s;
    __syncthreads();
    for (int d = 128; d > 0; d >>= 1) {
        if (t < d) red[t] += red[t + d];
        __syncthreads();
    }
    if (t == 0) bsum[b] = red[0];
}

__global__ __launch_bounds__(128) void scan_bsum(const int* __restrict__ bsum,
                                                 int* __restrict__ bbase, int nb,
                                                 int* __restrict__ total_out) {
    __shared__ int s[128];
    int t = threadIdx.x;
    s[t] = (t < nb) ? bsum[t] : 0;
    __syncthreads();
    for (int d = 1; d < 128; d <<= 1) {
        int v = (t >= d) ? s[t - d] : 0;
        __syncthreads();
        s[t] += v;
        __syncthreads();
    }
    bbase[t] = (t > 0) ? s[t - 1] : 0;
    if (t == 127) total_out[0] = s[127];
}

__global__ __launch_bounds__(256) void scan_final(const int* __restrict__ deg,
                                                  const int* __restrict__ bbase,
                                                  int* __restrict__ outA,
                                                  int* __restrict__ outB, int n) {
    __shared__ int red[256];
    int b = blockIdx.x, t = threadIdx.x;
    int base = b * 1024 + t * 4;
    int d0 = 0, d1 = 0, d2 = 0, d3 = 0;
    if (base + 3 < n) {
        int4 v = *(const int4*)&deg[base];
        d0 = v.x; d1 = v.y; d2 = v.z; d3 = v.w;
    } else {
        if (base < n) d0 = deg[base];
        if (base + 1 < n) d1 = deg[base + 1];
        if (base + 2 < n) d2 = deg[base + 2];
    }
    red[t] = d0 + d1 + d2 + d3;
    __syncthreads();
    for (int d = 1; d < 256; d <<= 1) {
        int v = (t >= d) ? red[t - d] : 0;
        __syncthreads();
        red[t] += v;
        __syncthreads();
    }
    int ex = bbase[b] + ((t > 0) ? red[t - 1] : 0);
    int o0 = ex, o1 = ex + d0, o2 = o1 + d1, o3 = o2 + d2;
    if (base + 3 < n) {
        *(int4*)&outA[base] = make_int4(o0, o1, o2, o3);
        *(int4*)&outB[base] = make_int4(o0, o1, o2, o3);
    } else {
        if (base < n) { outA[base] = o0; outB[base] = o0; }
        if (base + 1 < n) { outA[base + 1] = o1; outB[base + 1] = o1; }
        if (base + 2 < n) { outA[base + 2] = o2; outB[base + 2] = o2; }
    }
}

// bin edges into bucket-major staging; each block appends only into its own
// exact-sized [bucket][block] slice -> sequential ~128B runs, no global atomics.
__global__ __launch_bounds__(512) void bin_kernel(const int* __restrict__ src,
                                                  const int* __restrict__ dst,
                                                  const int* __restrict__ baseM,
                                                  int2* __restrict__ stage, int E, int nbuck) {
    __shared__ int cur[512];
    for (int i = threadIdx.x; i < nbuck; i += 512)
        cur[i] = baseM[(size_t)i * gridDim.x + blockIdx.x];
    __syncthreads();
    int chunk = (E + gridDim.x - 1) / gridDim.x;
    int lo = blockIdx.x * chunk, hi = min(lo + chunk, E);
    for (int e = lo + threadIdx.x; e < hi; e += 512) {
        int d = dst[e];
        int p = atomicAdd(&cur[d >> 8], 1);
        stage[p] = make_int2(src[e], d);
    }
}

// per-bucket assembly: LDS count+scan -> offs (coalesced), LDS colbuf -> col
// (coalesced). Fallback path for >CAP buckets keeps correctness always.
__global__ __launch_bounds__(256) void csr_kernel(const int2* __restrict__ stage,
                                                  const int* __restrict__ baseM,
                                                  int* __restrict__ offs,
                                                  int* __restrict__ col,
                                                  int E, int N, int nbuck, int binblk) {
    constexpr int CAP = 10240;
    __shared__ int cnt[256];
    __shared__ int sc[256];
    __shared__ int colbuf[CAP];
    int b = blockIdx.x, t = threadIdx.x;
    int base = baseM[(size_t)b * binblk];
    int end = (b + 1 < nbuck) ? baseM[(size_t)(b + 1) * binblk] : E;
    cnt[t] = 0;
    __syncthreads();
    for (int e = base + t; e < end; e += 256)
        atomicAdd(&cnt[stage[e].y & 255], 1);
    __syncthreads();
    int myCnt = cnt[t];
    sc[t] = myCnt;
    __syncthreads();
    for (int d = 1; d < 256; d <<= 1) {
        int u = (t >= d) ? sc[t - d] : 0;
        __syncthreads();
        sc[t] += u;
        __syncthreads();
    }
    int myExcl = sc[t] - myCnt;
    int node = b * 256 + t;
    if (node <= N) offs[node] = base + myExcl;
    cnt[t] = myExcl;  // reuse as cursor
    __syncthreads();
    for (int e = base + t; e < end; e += 256) {
        int2 sd = stage[e];
        int p = atomicAdd(&cnt[sd.y & 255], 1);
        if (p < CAP) colbuf[p] = sd.x;
        else col[base + p] = sd.x;
    }
    __syncthreads();
    int lim = min(end - base, CAP);
    for (int i = t; i < lim; i += 256) col[base + i] = colbuf[i];
}

// ---------------- fp32 -> f16 conversions ----------------
__global__ void cvt4_kernel(const float* __restrict__ in, f16* __restrict__ out, int nq) {
    int stride = gridDim.x * blockDim.x;
    for (int i = blockIdx.x * blockDim.x + threadIdx.x; i < nq; i += stride) {
        float4 v = *(const float4*)(in + (size_t)i * 4);
        f16x4 o = {(f16)v.x, (f16)v.y, (f16)v.z, (f16)v.w};
        *(f16x4*)(out + (size_t)i * 4) = o;
    }
}

struct CvtPack {
    const float* s[7];
    f16* d[7];
    int nq[7];
};
__global__ void cvt_pack_kernel(CvtPack p) {
    int seg = blockIdx.y;
    int nq = p.nq[seg];
    const float* in = p.s[seg];
    f16* out = p.d[seg];
    int stride = gridDim.x * blockDim.x;
    for (int i = blockIdx.x * blockDim.x + threadIdx.x; i < nq; i += stride) {
        float4 v = *(const float4*)(in + (size_t)i * 4);
        f16x4 o = {(f16)v.x, (f16)v.y, (f16)v.z, (f16)v.w};
        *(f16x4*)(out + (size_t)i * 4) = o;
    }
}

// ---------------- aggregation: z[n] = (1+eps)*h[n] + sum h[nbr] ----------------
// Four nodes per wave: each 16-lane group owns one node; lane holds f16x8
// (16B) so 16 lanes cover the 256B row with one dwordx4. 8-deep pipeline =>
// 32 rows in flight per wave. Nontemporal contiguous stores.
__global__ __launch_bounds__(256) void agg_kernel(const f16* __restrict__ h,
                                                  const int* __restrict__ offs,
                                                  const int* __restrict__ col,
                                                  const float* __restrict__ epsp,
                                                  f16* __restrict__ z, int n) {
    int node = blockIdx.x * 16 + (threadIdx.x >> 4);
    int li = threadIdx.x & 15;
    bool valid = node < n;
    int nd = valid ? node : (n - 1);
    const f16x8* hp = (const f16x8*)h;  // row stride = 16 f16x8
    float e1 = 1.0f + epsp[0];
    f16x8 self = hp[(size_t)nd * 16 + li];
    float a[8];
#pragma unroll
    for (int c = 0; c < 8; ++c) a[c] = (float)self[c] * e1;
    int lo = offs[nd], hi = valid ? offs[nd + 1] : lo;

    int e = lo;
    for (; e + 8 <= hi; e += 8) {
        int idx[8];
#pragma unroll
        for (int j = 0; j < 8; ++j) idx[j] = col[e + j];
        f16x8 v[8];
#pragma unroll
        for (int j = 0; j < 8; ++j) v[j] = hp[(size_t)idx[j] * 16 + li];
#pragma unroll
        for (int j = 0; j < 8; ++j)
#pragma unroll
            for (int c = 0; c < 8; ++c) a[c] += (float)v[j][c];
    }
    if (e + 4 <= hi) {
        int idx[4];
#pragma unroll
        for (int j = 0; j < 4; ++j) idx[j] = col[e + j];
        f16x8 v[4];
#pragma unroll
        for (int j = 0; j < 4; ++j) v[j] = hp[(size_t)idx[j] * 16 + li];
#pragma unroll
        for (int j = 0; j < 4; ++j)
#pragma unroll
            for (int c = 0; c < 8; ++c) a[c] += (float)v[j][c];
        e += 4;
    }
    for (; e < hi; ++e) {
        f16x8 v = hp[(size_t)col[e] * 16 + li];
#pragma unroll
        for (int c = 0; c < 8; ++c) a[c] += (float)v[c];
    }
    if (valid) {
        f16x8 o;
#pragma unroll
        for (int c = 0; c < 8; ++c) o[c] = (f16)a[c];
        __builtin_nontemporal_store(o, (f16x8*)z + (size_t)nd * 16 + li);
    }
}

// ---------------- fused conv MLP (+ optional fc tail) ----------------
template <bool LAST>
__global__ __launch_bounds__(256) void conv_mlp_kernel(
    const f16* __restrict__ Z, const f16* __restrict__ W1f,
    const float* __restrict__ b1, const f16* __restrict__ W2f,
    const float* __restrict__ b2, f16* __restrict__ Hout, int M,
    const f16* __restrict__ fc1wf, const float* __restrict__ fc1b,
    const float* __restrict__ fc2w, const float* __restrict__ fc2b,
    float* __restrict__ out) {
    __shared__ __align__(16) f16 As[128 * 128];
    __shared__ __align__(16) f16 Ws[128 * 128];
    __shared__ float Red[LAST ? 128 * 17 : 1];

    const int tid = threadIdx.x;
    const int w = tid >> 6, lane = tid & 63;
    const int frow = lane & 15, kgrp = lane >> 4;
    const int m0 = blockIdx.x * 128;
    const int u = lane & 15, rsub = lane >> 4;

#pragma unroll
    for (int i = 0; i < 8; ++i) {
        int rowbase = (w * 8 + i) * 4;
        int r = rowbase + rsub;
        int gr = m0 + r;
        if (gr >= M) gr = M - 1;
        glds16(Z + (size_t)gr * 128 + ((u ^ (r & 7)) << 3), &As[rowbase * 128]);
    }
#pragma unroll
    for (int i = 0; i < 8; ++i) {
        int rowbase = (w * 8 + i) * 4;
        int r = rowbase + rsub;
        glds16(W1f + (size_t)r * 128 + ((u ^ (r & 7)) << 3), &Ws[rowbase * 128]);
    }
    __syncthreads();

    const int arow0 = w * 32 + frow;
    f32x4 acc[2][8];
#pragma unroll
    for (int mi = 0; mi < 2; ++mi)
#pragma unroll
        for (int nj = 0; nj < 8; ++nj) acc[mi][nj] = (f32x4){0.f, 0.f, 0.f, 0.f};

    // ---- GEMM1 ----
#pragma unroll
    for (int kk = 0; kk < 4; ++kk) {
        int kb = kk * 4 + kgrp;
        f16x8 a[2], b[8];
#pragma unroll
        for (int mi = 0; mi < 2; ++mi) {
            int r = arow0 + mi * 16;
            a[mi] = *(const f16x8*)&As[r * 128 + ((kb ^ (r & 7)) << 3)];
        }
#pragma unroll
        for (int nj = 0; nj < 8; ++nj) {
            int r = nj * 16 + frow;
            b[nj] = *(const f16x8*)&Ws[r * 128 + ((kb ^ (r & 7)) << 3)];
        }
#pragma unroll
        for (int mi = 0; mi < 2; ++mi)
#pragma unroll
            for (int nj = 0; nj < 8; ++nj)
                acc[mi][nj] = __builtin_amdgcn_mfma_f32_16x16x32_f16(a[mi], b[nj],
                                                                     acc[mi][nj], 0, 0, 0);
    }
    __syncthreads();

#pragma unroll
    for (int i = 0; i < 8; ++i) {
        int rowbase = (w * 8 + i) * 4;
        int r = rowbase + rsub;
        glds16(W2f + (size_t)r * 128 + ((u ^ (r & 7)) << 3), &Ws[rowbase * 128]);
    }
    {
        float bv[8];
#pragma unroll
        for (int nj = 0; nj < 8; ++nj) bv[nj] = b1[nj * 16 + frow];
#pragma unroll
        for (int mi = 0; mi < 2; ++mi)
#pragma unroll
            for (int nj = 0; nj < 8; ++nj) {
                int row0 = w * 32 + mi * 16 + kgrp * 4;
                int c = nj * 16 + frow;
                int cu = c >> 3, cl = c & 7;
#pragma unroll
                for (int r = 0; r < 4; ++r) {
                    int rr = row0 + r;
                    As[rr * 128 + ((cu ^ (rr & 7)) << 3) + cl] =
                        (f16)fmaxf(acc[mi][nj][r] + bv[nj], 0.f);
                }
            }
    }
    __syncthreads();

    // ---- GEMM2 ----
#pragma unroll
    for (int mi = 0; mi < 2; ++mi)
#pragma unroll
        for (int nj = 0; nj < 8; ++nj) acc[mi][nj] = (f32x4){0.f, 0.f, 0.f, 0.f};
#pragma unroll
    for (int kk = 0; kk < 4; ++kk) {
        int kb = kk * 4 + kgrp;
        f16x8 a[2], b[8];
#pragma unroll
        for (int mi = 0; mi < 2; ++mi) {
            int r = arow0 + mi * 16;
            a[mi] = *(const f16x8*)&As[r * 128 + ((kb ^ (r & 7)) << 3)];
        }
#pragma unroll
        for (int nj = 0; nj < 8; ++nj) {
            int r = nj * 16 + frow;
            b[nj] = *(const f16x8*)&Ws[r * 128 + ((kb ^ (r & 7)) << 3)];
        }
#pragma unroll
        for (int mi = 0; mi < 2; ++mi)
#pragma unroll
            for (int nj = 0; nj < 8; ++nj)
                acc[mi][nj] = __builtin_amdgcn_mfma_f32_16x16x32_f16(a[mi], b[nj],
                                                                     acc[mi][nj], 0, 0, 0);
    }

    float bv2[8];
#pragma unroll
    for (int nj = 0; nj < 8; ++nj) bv2[nj] = b2[nj * 16 + frow];

    if (!LAST) {
        __syncthreads();
#pragma unroll
        for (int mi = 0; mi < 2; ++mi)
#pragma unroll
            for (int nj = 0; nj < 8; ++nj) {
                int row0 = w * 32 + mi * 16 + kgrp * 4;
                int c = nj * 16 + frow;
#pragma unroll
                for (int r = 0; r < 4; ++r)
                    As[(row0 + r) * 128 + c] = (f16)fmaxf(acc[mi][nj][r] + bv2[nj], 0.f);
            }
        __syncthreads();
        for (int idx = tid; idx < 128 * 16; idx += 256) {
            int r = idx >> 4, q = idx & 15;
            int gm = m0 + r;
            if (gm < M)
                *(float4*)(Hout + (size_t)gm * 128 + q * 8) = *(const float4*)&As[r * 128 + q * 8];
        }
    } else {
        __syncthreads();
#pragma unroll
        for (int i = 0; i < 4; ++i) {
            int rowbase = (w * 4 + i) * 4;
            int r = rowbase + rsub;
            glds16(fc1wf + (size_t)r * 128 + ((u ^ (r & 7)) << 3), &Ws[rowbase * 128]);
        }
#pragma unroll
        for (int mi = 0; mi < 2; ++mi)
#pragma unroll
            for (int nj = 0; nj < 8; ++nj) {
                int row0 = w * 32 + mi * 16 + kgrp * 4;
                int c = nj * 16 + frow;
                int cu = c >> 3, cl = c & 7;
#pragma unroll
                for (int r = 0; r < 4; ++r) {
                    int rr = row0 + r;
                    As[rr * 128 + ((cu ^ (rr & 7)) << 3) + cl] =
                        (f16)fmaxf(acc[mi][nj][r] + bv2[nj], 0.f);
                }
            }
        __syncthreads();

        f32x4 acc3[2][4];
#pragma unroll
        for (int mi = 0; mi < 2; ++mi)
#pragma unroll
            for (int nj = 0; nj < 4; ++nj) acc3[mi][nj] = (f32x4){0.f, 0.f, 0.f, 0.f};
#pragma unroll
        for (int kk = 0; kk < 4; ++kk) {
            int kb = kk * 4 + kgrp;
            f16x8 a[2], b[4];
#pragma unroll
            for (int mi = 0; mi < 2; ++mi) {
                int r = arow0 + mi * 16;
                a[mi] = *(const f16x8*)&As[r * 128 + ((kb ^ (r & 7)) << 3)];
            }
#pragma unroll
            for (int nj = 0; nj < 4; ++nj) {
                int r = nj * 16 + frow;
                b[nj] = *(const f16x8*)&Ws[r * 128 + ((kb ^ (r & 7)) << 3)];
            }
#pragma unroll
            for (int mi = 0; mi < 2; ++mi)
#pragma unroll
                for (int nj = 0; nj < 4; ++nj)
                    acc3[mi][nj] = __builtin_amdgcn_mfma_f32_16x16x32_f16(a[mi], b[nj],
                                                                          acc3[mi][nj], 0, 0, 0);
        }
        float bvf[4], f2[4];
#pragma unroll
        for (int nj = 0; nj < 4; ++nj) {
            bvf[nj] = fc1b[nj * 16 + frow];
            f2[nj] = fc2w[nj * 16 + frow];
        }
        float part[2][4];
#pragma unroll
        for (int mi = 0; mi < 2; ++mi)
#pragma unroll
            for (int r = 0; r < 4; ++r) part[mi][r] = 0.f;
#pragma unroll
        for (int mi = 0; mi < 2; ++mi)
#pragma unroll
            for (int nj = 0; nj < 4; ++nj)
#pragma unroll
                for (int r = 0; r < 4; ++r)
                    part[mi][r] += fmaxf(acc3[mi][nj][r] + bvf[nj], 0.f) * f2[nj];
#pragma unroll
        for (int mi = 0; mi < 2; ++mi)
#pragma unroll
            for (int r = 0; r < 4; ++r)
                Red[(w * 32 + mi * 16 + kgrp * 4 + r) * 17 + frow] = part[mi][r];
        __syncthreads();
        if (tid < 128) {
            float s = fc2b[0];
#pragma unroll
            for (int q = 0; q < 16; ++q) s += Red[tid * 17 + q];
            int m = m0 + tid;
            if (m < M) out[m] = 1.f / (1.f + expf(-s));
        }
    }
}

// ---------------------------------------------------------------------------
extern "C" void kernel_launch(void* const* d_in, const int* in_sizes, int n_in,
                              void* d_out, int out_size, void* d_ws, size_t ws_size,
                              hipStream_t stream) {
    const float* x = (const float*)d_in[0];
    const int* ei = (const int*)d_in[1];
    const int N = in_sizes[0] / 128;
    const int E = in_sizes[1] / 2;
    const int* srcIdx = ei;
    const int* dstIdx = ei + E;

    const float* w1[3] = {(const float*)d_in[2], (const float*)d_in[7], (const float*)d_in[12]};
    const float* b1[3] = {(const float*)d_in[3], (const float*)d_in[8], (const float*)d_in[13]};
    const float* w2[3] = {(const float*)d_in[4], (const float*)d_in[9], (const float*)d_in[14]};
    const float* b2[3] = {(const float*)d_in[5], (const float*)d_in[10], (const float*)d_in[15]};
    const float* eps[3] = {(const float*)d_in[6], (const float*)d_in[11], (const float*)d_in[16]};
    const float* fc1w = (const float*)d_in[17];
    const float* fc1b = (const float*)d_in[18];
    const float* fc2w = (const float*)d_in[19];
    const float* fc2b = (const float*)d_in[20];

    // workspace carve
    char* ws = (char*)d_ws;
    size_t p = 0;
    auto carve = [&](size_t bytes) -> char* {
        char* r = ws + p;
        p = (p + bytes + 255) & ~(size_t)255;
        return r;
    };
    const int nbuck = (N + 255) >> 8;          // 256-node buckets
    const int nm = nbuck * BINBLK;             // count-matrix size
    int* offs = (int*)carve((size_t)(N + 1) * 4);
    int* col = (int*)carve((size_t)E * 4);
    int* cntM = (int*)carve((size_t)nm * 4);
    int* baseM = (int*)carve((size_t)nm * 4);
    int* baseM2 = (int*)carve((size_t)nm * 4);  // scan scratch (unused copy)
    int* bsum = (int*)carve(128 * 4);
    int* bbase = (int*)carve(128 * 4);
    int* tot = (int*)carve(4);
    int2* stage = (int2*)carve((size_t)E * 8);
    f16* H0 = (f16*)carve((size_t)N * 128 * 2);
    f16* H1 = (f16*)carve((size_t)N * 128 * 2);
    f16* Z = (f16*)carve((size_t)N * 128 * 2);
    f16* w1f[3], *w2f[3];
    for (int i = 0; i < 3; ++i) {
        w1f[i] = (f16*)carve(128 * 128 * 2);
        w2f[i] = (f16*)carve(128 * 128 * 2);
    }
    f16* fc1wf = (f16*)carve(64 * 128 * 2);
    (void)ws_size;

    // ---- build CSR (deterministic two-level binning) ----
    const int SB2 = (nm + 1023) / 1024;  // <=128 for nbuck*256 <= 128K
    bucket_count_kernel<<<BINBLK, 512, 0, stream>>>(dstIdx, cntM, E, nbuck);
    scan_partial<<<SB2, 256, 0, stream>>>(cntM, bsum, nm);
    scan_bsum<<<1, 128, 0, stream>>>(bsum, bbase, SB2, tot);
    scan_final<<<SB2, 256, 0, stream>>>(cntM, bbase, baseM, baseM2, nm);
    bin_kernel<<<BINBLK, 512, 0, stream>>>(srcIdx, dstIdx, baseM, stage, E, nbuck);
    csr_kernel<<<nbuck, 256, 0, stream>>>(stage, baseM, offs, col, E, N, nbuck, BINBLK);

    // ---- fp32 -> f16: x and all MFMA weights ----
    cvt4_kernel<<<2048, 256, 0, stream>>>(x, H0, N * 128 / 4);
    CvtPack cp;
    for (int i = 0; i < 3; ++i) {
        cp.s[i] = w1[i];     cp.d[i] = w1f[i];     cp.nq[i] = 128 * 128 / 4;
        cp.s[3 + i] = w2[i]; cp.d[3 + i] = w2f[i]; cp.nq[3 + i] = 128 * 128 / 4;
    }
    cp.s[6] = fc1w; cp.d[6] = fc1wf; cp.nq[6] = 64 * 128 / 4;
    cvt_pack_kernel<<<dim3(16, 7), 256, 0, stream>>>(cp);

    const int aggGrid = (N + 15) / 16;  // 4 nodes per wave, 4 waves per block
    const int gemmGrid = (N + 127) / 128;

    // conv0: H0 -> Z -> H1 ; conv1: H1 -> Z -> H0 ; conv2: H0 -> Z -> out
    agg_kernel<<<aggGrid, 256, 0, stream>>>(H0, offs, col, eps[0], Z, N);
    conv_mlp_kernel<false><<<gemmGrid, 256, 0, stream>>>(
        Z, w1f[0], b1[0], w2f[0], b2[0], H1, N, nullptr, nullptr, nullptr, nullptr, nullptr);
    agg_kernel<<<aggGrid, 256, 0, stream>>>(H1, offs, col, eps[1], Z, N);
    conv_mlp_kernel<false><<<gemmGrid, 256, 0, stream>>>(
        Z, w1f[1], b1[1], w2f[1], b2[1], H0, N, nullptr, nullptr, nullptr, nullptr, nullptr);
    agg_kernel<<<aggGrid, 256, 0, stream>>>(H0, offs, col, eps[2], Z, N);
    conv_mlp_kernel<true><<<gemmGrid, 256, 0, stream>>>(
        Z, w1f[2], b1[2], w2f[2], b2[2], nullptr, N, fc1wf, fc1b, fc2w, fc2b, (float*)d_out);
}

// Round 9
// 289.266 us; speedup vs baseline: 5.2170x; 1.0251x over previous
//
#include <hip/hip_runtime.h>
#include <math.h>

// ---------------------------------------------------------------------------
// GIN network on MI355X — round 9.
//  - agg_kernel v5: two-phase feature-split gather. Block = 32 nodes; its
//    contiguous col window is LDS-staged (coalesced, nontemporal). Phase A
//    gathers feats 0-63 for all nodes, phase B feats 64-127 (reusing LDS
//    indices). Device-wide active gather footprint halves (25.6 -> 12.8 MB)
//    => higher L2 hit rate => less fabric traffic. Half-row = one 128B line.
//  - CSR two-level binning + fused conv MLP unchanged.
// ---------------------------------------------------------------------------

using f16   = _Float16;
using f16x4 = __attribute__((ext_vector_type(4))) _Float16;
using f16x8 = __attribute__((ext_vector_type(8))) _Float16;
using f32x4 = __attribute__((ext_vector_type(4))) float;

constexpr int BINBLK = 256;   // binning grid (blocks); count matrix columns

__device__ inline void glds16(const void* g, void* l) {
    __builtin_amdgcn_global_load_lds(
        (const __attribute__((address_space(1))) void*)g,
        (__attribute__((address_space(3))) void*)l, 16, 0, 0);
}

// ---------------- CSR build: two-level binning ----------------
// bucket = dst >> 8  (256 nodes per bucket)

__global__ __launch_bounds__(512) void bucket_count_kernel(const int* __restrict__ dst,
                                                           int* __restrict__ cntM,
                                                           int E, int nbuck) {
    __shared__ int cnt[512];
    for (int i = threadIdx.x; i < nbuck; i += 512) cnt[i] = 0;
    __syncthreads();
    int chunk = (E + gridDim.x - 1) / gridDim.x;
    int lo = blockIdx.x * chunk, hi = min(lo + chunk, E);
    for (int e = lo + threadIdx.x; e < hi; e += 512)
        atomicAdd(&cnt[dst[e] >> 8], 1);
    __syncthreads();
    for (int i = threadIdx.x; i < nbuck; i += 512)
        cntM[(size_t)i * gridDim.x + blockIdx.x] = cnt[i];
}

// per-1024-chunk sums (generic scan, n up to 128*1024)
__global__ __launch_bounds__(256) void scan_partial(const int* __restrict__ deg,
                                                    int* __restrict__ bsum, int n) {
    __shared__ int red[256];
    int b = blockIdx.x, t = threadIdx.x;
    int base = b * 1024;
    int s = 0;
#pragma unroll
    for (int j = 0; j < 4; ++j) {
        int idx = base + j * 256 + t;
        if (idx < n) s += deg[idx];
    }
    red[t] = s;
    __syncthreads();
    for (int d = 128; d > 0; d >>= 1) {
        if (t < d) red[t] += red[t + d];
        __syncthreads();
    }
    if (t == 0) bsum[b] = red[0];
}

__global__ __launch_bounds__(128) void scan_bsum(const int* __restrict__ bsum,
                                                 int* __restrict__ bbase, int nb,
                                                 int* __restrict__ total_out) {
    __shared__ int s[128];
    int t = threadIdx.x;
    s[t] = (t < nb) ? bsum[t] : 0;
    __syncthreads();
    for (int d = 1; d < 128; d <<= 1) {
        int v = (t >= d) ? s[t - d] : 0;
        __syncthreads();
        s[t] += v;
        __syncthreads();
    }
    bbase[t] = (t > 0) ? s[t - 1] : 0;
    if (t == 127) total_out[0] = s[127];
}

__global__ __launch_bounds__(256) void scan_final(const int* __restrict__ deg,
                                                  const int* __restrict__ bbase,
                                                  int* __restrict__ outA,
                                                  int* __restrict__ outB, int n) {
    __shared__ int red[256];
    int b = blockIdx.x, t = threadIdx.x;
    int base = b * 1024 + t * 4;
    int d0 = 0, d1 = 0, d2 = 0, d3 = 0;
    if (base + 3 < n) {
        int4 v = *(const int4*)&deg[base];
        d0 = v.x; d1 = v.y; d2 = v.z; d3 = v.w;
    } else {
        if (base < n) d0 = deg[base];
        if (base + 1 < n) d1 = deg[base + 1];
        if (base + 2 < n) d2 = deg[base + 2];
    }
    red[t] = d0 + d1 + d2 + d3;
    __syncthreads();
    for (int d = 1; d < 256; d <<= 1) {
        int v = (t >= d) ? red[t - d] : 0;
        __syncthreads();
        red[t] += v;
        __syncthreads();
    }
    int ex = bbase[b] + ((t > 0) ? red[t - 1] : 0);
    int o0 = ex, o1 = ex + d0, o2 = o1 + d1, o3 = o2 + d2;
    if (base + 3 < n) {
        *(int4*)&outA[base] = make_int4(o0, o1, o2, o3);
        *(int4*)&outB[base] = make_int4(o0, o1, o2, o3);
    } else {
        if (base < n) { outA[base] = o0; outB[base] = o0; }
        if (base + 1 < n) { outA[base + 1] = o1; outB[base + 1] = o1; }
        if (base + 2 < n) { outA[base + 2] = o2; outB[base + 2] = o2; }
    }
}

// bin edges into bucket-major staging; each block appends only into its own
// exact-sized [bucket][block] slice -> sequential ~128B runs, no global atomics.
__global__ __launch_bounds__(512) void bin_kernel(const int* __restrict__ src,
                                                  const int* __restrict__ dst,
                                                  const int* __restrict__ baseM,
                                                  int2* __restrict__ stage, int E, int nbuck) {
    __shared__ int cur[512];
    for (int i = threadIdx.x; i < nbuck; i += 512)
        cur[i] = baseM[(size_t)i * gridDim.x + blockIdx.x];
    __syncthreads();
    int chunk = (E + gridDim.x - 1) / gridDim.x;
    int lo = blockIdx.x * chunk, hi = min(lo + chunk, E);
    for (int e = lo + threadIdx.x; e < hi; e += 512) {
        int d = dst[e];
        int p = atomicAdd(&cur[d >> 8], 1);
        stage[p] = make_int2(src[e], d);
    }
}

// per-bucket assembly: LDS count+scan -> offs (coalesced), LDS colbuf -> col
// (coalesced). Fallback path for >CAP buckets keeps correctness always.
__global__ __launch_bounds__(256) void csr_kernel(const int2* __restrict__ stage,
                                                  const int* __restrict__ baseM,
                                                  int* __restrict__ offs,
                                                  int* __restrict__ col,
                                                  int E, int N, int nbuck, int binblk) {
    constexpr int CAP = 10240;
    __shared__ int cnt[256];
    __shared__ int sc[256];
    __shared__ int colbuf[CAP];
    int b = blockIdx.x, t = threadIdx.x;
    int base = baseM[(size_t)b * binblk];
    int end = (b + 1 < nbuck) ? baseM[(size_t)(b + 1) * binblk] : E;
    cnt[t] = 0;
    __syncthreads();
    for (int e = base + t; e < end; e += 256)
        atomicAdd(&cnt[stage[e].y & 255], 1);
    __syncthreads();
    int myCnt = cnt[t];
    sc[t] = myCnt;
    __syncthreads();
    for (int d = 1; d < 256; d <<= 1) {
        int u = (t >= d) ? sc[t - d] : 0;
        __syncthreads();
        sc[t] += u;
        __syncthreads();
    }
    int myExcl = sc[t] - myCnt;
    int node = b * 256 + t;
    if (node <= N) offs[node] = base + myExcl;
    cnt[t] = myExcl;  // reuse as cursor
    __syncthreads();
    for (int e = base + t; e < end; e += 256) {
        int2 sd = stage[e];
        int p = atomicAdd(&cnt[sd.y & 255], 1);
        if (p < CAP) colbuf[p] = sd.x;
        else col[base + p] = sd.x;
    }
    __syncthreads();
    int lim = min(end - base, CAP);
    for (int i = t; i < lim; i += 256) col[base + i] = colbuf[i];
}

// ---------------- fp32 -> f16 conversions ----------------
__global__ void cvt4_kernel(const float* __restrict__ in, f16* __restrict__ out, int nq) {
    int stride = gridDim.x * blockDim.x;
    for (int i = blockIdx.x * blockDim.x + threadIdx.x; i < nq; i += stride) {
        float4 v = *(const float4*)(in + (size_t)i * 4);
        f16x4 o = {(f16)v.x, (f16)v.y, (f16)v.z, (f16)v.w};
        *(f16x4*)(out + (size_t)i * 4) = o;
    }
}

struct CvtPack {
    const float* s[7];
    f16* d[7];
    int nq[7];
};
__global__ void cvt_pack_kernel(CvtPack p) {
    int seg = blockIdx.y;
    int nq = p.nq[seg];
    const float* in = p.s[seg];
    f16* out = p.d[seg];
    int stride = gridDim.x * blockDim.x;
    for (int i = blockIdx.x * blockDim.x + threadIdx.x; i < nq; i += stride) {
        float4 v = *(const float4*)(in + (size_t)i * 4);
        f16x4 o = {(f16)v.x, (f16)v.y, (f16)v.z, (f16)v.w};
        *(f16x4*)(out + (size_t)i * 4) = o;
    }
}

// ---------------- aggregation: z[n] = (1+eps)*h[n] + sum h[nbr] ----------------
// v5: block = 32 consecutive nodes; contiguous col window LDS-staged
// (coalesced + nontemporal). Two phases over the feature dim (64 feats =
// 128B = one L2 line each): all blocks gather feats 0-63 first, then 64-127
// reusing LDS indices -> active h footprint halves -> better L2 hit rate.
// Per node: 8 lanes * f16x8(16B) cover the 128B half-row; 8-deep pipeline.
__global__ __launch_bounds__(256) void agg_kernel(const f16* __restrict__ h,
                                                  const int* __restrict__ offs,
                                                  const int* __restrict__ col,
                                                  const float* __restrict__ epsp,
                                                  f16* __restrict__ z, int n) {
    __shared__ int colLDS[2048];
    __shared__ int sOffs[33];
    const int tid = threadIdx.x;
    const int nb = blockIdx.x * 32;
    if (tid < 33) sOffs[tid] = offs[min(nb + tid, n)];
    __syncthreads();
    const int base = sOffs[0];
    const int len = sOffs[32] - base;
    const bool useLds = len <= 2048;
    if (useLds) {
        for (int i = tid; i < len; i += 256)
            colLDS[i] = __builtin_nontemporal_load(&col[base + i]);
    }
    __syncthreads();

    const int grp = tid >> 3;   // node within block (0..31)
    const int li = tid & 7;     // lane in 8-lane group (16B each)
    const int node = nb + grp;
    const bool valid = node < n;
    const int nd = valid ? node : (n - 1);
    const int lo = sOffs[grp] - base;
    const int hi = valid ? (sOffs[grp + 1] - base) : lo;
    const f16x8* hp = (const f16x8*)h;  // row = 16 f16x8
    const float e1 = 1.0f + epsp[0];

#pragma unroll
    for (int ph = 0; ph < 2; ++ph) {
        const int co = ph * 8 + li;  // f16x8 index within row
        f16x8 self = hp[(size_t)nd * 16 + co];
        float a[8];
#pragma unroll
        for (int c = 0; c < 8; ++c) a[c] = (float)self[c] * e1;
        int e = lo;
        for (; e + 8 <= hi; e += 8) {
            int idx[8];
#pragma unroll
            for (int j = 0; j < 8; ++j)
                idx[j] = useLds ? colLDS[e + j] : col[base + e + j];
            f16x8 v[8];
#pragma unroll
            for (int j = 0; j < 8; ++j) v[j] = hp[(size_t)idx[j] * 16 + co];
#pragma unroll
            for (int j = 0; j < 8; ++j)
#pragma unroll
                for (int c = 0; c < 8; ++c) a[c] += (float)v[j][c];
        }
        if (e + 4 <= hi) {
            int idx[4];
#pragma unroll
            for (int j = 0; j < 4; ++j)
                idx[j] = useLds ? colLDS[e + j] : col[base + e + j];
            f16x8 v[4];
#pragma unroll
            for (int j = 0; j < 4; ++j) v[j] = hp[(size_t)idx[j] * 16 + co];
#pragma unroll
            for (int j = 0; j < 4; ++j)
#pragma unroll
                for (int c = 0; c < 8; ++c) a[c] += (float)v[j][c];
            e += 4;
        }
        for (; e < hi; ++e) {
            int idx = useLds ? colLDS[e] : col[base + e];
            f16x8 v = hp[(size_t)idx * 16 + co];
#pragma unroll
            for (int c = 0; c < 8; ++c) a[c] += (float)v[c];
        }
        if (valid) {
            f16x8 o;
#pragma unroll
            for (int c = 0; c < 8; ++c) o[c] = (f16)a[c];
            __builtin_nontemporal_store(o, (f16x8*)z + (size_t)nd * 16 + co);
        }
    }
}

// ---------------- fused conv MLP (+ optional fc tail) ----------------
template <bool LAST>
__global__ __launch_bounds__(256) void conv_mlp_kernel(
    const f16* __restrict__ Z, const f16* __restrict__ W1f,
    const float* __restrict__ b1, const f16* __restrict__ W2f,
    const float* __restrict__ b2, f16* __restrict__ Hout, int M,
    const f16* __restrict__ fc1wf, const float* __restrict__ fc1b,
    const float* __restrict__ fc2w, const float* __restrict__ fc2b,
    float* __restrict__ out) {
    __shared__ __align__(16) f16 As[128 * 128];
    __shared__ __align__(16) f16 Ws[128 * 128];
    __shared__ float Red[LAST ? 128 * 17 : 1];

    const int tid = threadIdx.x;
    const int w = tid >> 6, lane = tid & 63;
    const int frow = lane & 15, kgrp = lane >> 4;
    const int m0 = blockIdx.x * 128;
    const int u = lane & 15, rsub = lane >> 4;

#pragma unroll
    for (int i = 0; i < 8; ++i) {
        int rowbase = (w * 8 + i) * 4;
        int r = rowbase + rsub;
        int gr = m0 + r;
        if (gr >= M) gr = M - 1;
        glds16(Z + (size_t)gr * 128 + ((u ^ (r & 7)) << 3), &As[rowbase * 128]);
    }
#pragma unroll
    for (int i = 0; i < 8; ++i) {
        int rowbase = (w * 8 + i) * 4;
        int r = rowbase + rsub;
        glds16(W1f + (size_t)r * 128 + ((u ^ (r & 7)) << 3), &Ws[rowbase * 128]);
    }
    __syncthreads();

    const int arow0 = w * 32 + frow;
    f32x4 acc[2][8];
#pragma unroll
    for (int mi = 0; mi < 2; ++mi)
#pragma unroll
        for (int nj = 0; nj < 8; ++nj) acc[mi][nj] = (f32x4){0.f, 0.f, 0.f, 0.f};

    // ---- GEMM1 ----
#pragma unroll
    for (int kk = 0; kk < 4; ++kk) {
        int kb = kk * 4 + kgrp;
        f16x8 a[2], b[8];
#pragma unroll
        for (int mi = 0; mi < 2; ++mi) {
            int r = arow0 + mi * 16;
            a[mi] = *(const f16x8*)&As[r * 128 + ((kb ^ (r & 7)) << 3)];
        }
#pragma unroll
        for (int nj = 0; nj < 8; ++nj) {
            int r = nj * 16 + frow;
            b[nj] = *(const f16x8*)&Ws[r * 128 + ((kb ^ (r & 7)) << 3)];
        }
#pragma unroll
        for (int mi = 0; mi < 2; ++mi)
#pragma unroll
            for (int nj = 0; nj < 8; ++nj)
                acc[mi][nj] = __builtin_amdgcn_mfma_f32_16x16x32_f16(a[mi], b[nj],
                                                                     acc[mi][nj], 0, 0, 0);
    }
    __syncthreads();

#pragma unroll
    for (int i = 0; i < 8; ++i) {
        int rowbase = (w * 8 + i) * 4;
        int r = rowbase + rsub;
        glds16(W2f + (size_t)r * 128 + ((u ^ (r & 7)) << 3), &Ws[rowbase * 128]);
    }
    {
        float bv[8];
#pragma unroll
        for (int nj = 0; nj < 8; ++nj) bv[nj] = b1[nj * 16 + frow];
#pragma unroll
        for (int mi = 0; mi < 2; ++mi)
#pragma unroll
            for (int nj = 0; nj < 8; ++nj) {
                int row0 = w * 32 + mi * 16 + kgrp * 4;
                int c = nj * 16 + frow;
                int cu = c >> 3, cl = c & 7;
#pragma unroll
                for (int r = 0; r < 4; ++r) {
                    int rr = row0 + r;
                    As[rr * 128 + ((cu ^ (rr & 7)) << 3) + cl] =
                        (f16)fmaxf(acc[mi][nj][r] + bv[nj], 0.f);
                }
            }
    }
    __syncthreads();

    // ---- GEMM2 ----
#pragma unroll
    for (int mi = 0; mi < 2; ++mi)
#pragma unroll
        for (int nj = 0; nj < 8; ++nj) acc[mi][nj] = (f32x4){0.f, 0.f, 0.f, 0.f};
#pragma unroll
    for (int kk = 0; kk < 4; ++kk) {
        int kb = kk * 4 + kgrp;
        f16x8 a[2], b[8];
#pragma unroll
        for (int mi = 0; mi < 2; ++mi) {
            int r = arow0 + mi * 16;
            a[mi] = *(const f16x8*)&As[r * 128 + ((kb ^ (r & 7)) << 3)];
        }
#pragma unroll
        for (int nj = 0; nj < 8; ++nj) {
            int r = nj * 16 + frow;
            b[nj] = *(const f16x8*)&Ws[r * 128 + ((kb ^ (r & 7)) << 3)];
        }
#pragma unroll
        for (int mi = 0; mi < 2; ++mi)
#pragma unroll
            for (int nj = 0; nj < 8; ++nj)
                acc[mi][nj] = __builtin_amdgcn_mfma_f32_16x16x32_f16(a[mi], b[nj],
                                                                     acc[mi][nj], 0, 0, 0);
    }

    float bv2[8];
#pragma unroll
    for (int nj = 0; nj < 8; ++nj) bv2[nj] = b2[nj * 16 + frow];

    if (!LAST) {
        __syncthreads();
#pragma unroll
        for (int mi = 0; mi < 2; ++mi)
#pragma unroll
            for (int nj = 0; nj < 8; ++nj) {
                int row0 = w * 32 + mi * 16 + kgrp * 4;
                int c = nj * 16 + frow;
#pragma unroll
                for (int r = 0; r < 4; ++r)
                    As[(row0 + r) * 128 + c] = (f16)fmaxf(acc[mi][nj][r] + bv2[nj], 0.f);
            }
        __syncthreads();
        for (int idx = tid; idx < 128 * 16; idx += 256) {
            int r = idx >> 4, q = idx & 15;
            int gm = m0 + r;
            if (gm < M)
                *(float4*)(Hout + (size_t)gm * 128 + q * 8) = *(const float4*)&As[r * 128 + q * 8];
        }
    } else {
        __syncthreads();
#pragma unroll
        for (int i = 0; i < 4; ++i) {
            int rowbase = (w * 4 + i) * 4;
            int r = rowbase + rsub;
            glds16(fc1wf + (size_t)r * 128 + ((u ^ (r & 7)) << 3), &Ws[rowbase * 128]);
        }
#pragma unroll
        for (int mi = 0; mi < 2; ++mi)
#pragma unroll
            for (int nj = 0; nj < 8; ++nj) {
                int row0 = w * 32 + mi * 16 + kgrp * 4;
                int c = nj * 16 + frow;
                int cu = c >> 3, cl = c & 7;
#pragma unroll
                for (int r = 0; r < 4; ++r) {
                    int rr = row0 + r;
                    As[rr * 128 + ((cu ^ (rr & 7)) << 3) + cl] =
                        (f16)fmaxf(acc[mi][nj][r] + bv2[nj], 0.f);
                }
            }
        __syncthreads();

        f32x4 acc3[2][4];
#pragma unroll
        for (int mi = 0; mi < 2; ++mi)
#pragma unroll
            for (int nj = 0; nj < 4; ++nj) acc3[mi][nj] = (f32x4){0.f, 0.f, 0.f, 0.f};
#pragma unroll
        for (int kk = 0; kk < 4; ++kk) {
            int kb = kk * 4 + kgrp;
            f16x8 a[2], b[4];
#pragma unroll
            for (int mi = 0; mi < 2; ++mi) {
                int r = arow0 + mi * 16;
                a[mi] = *(const f16x8*)&As[r * 128 + ((kb ^ (r & 7)) << 3)];
            }
#pragma unroll
            for (int nj = 0; nj < 4; ++nj) {
                int r = nj * 16 + frow;
                b[nj] = *(const f16x8*)&Ws[r * 128 + ((kb ^ (r & 7)) << 3)];
            }
#pragma unroll
            for (int mi = 0; mi < 2; ++mi)
#pragma unroll
                for (int nj = 0; nj < 4; ++nj)
                    acc3[mi][nj] = __builtin_amdgcn_mfma_f32_16x16x32_f16(a[mi], b[nj],
                                                                          acc3[mi][nj], 0, 0, 0);
        }
        float bvf[4], f2[4];
#pragma unroll
        for (int nj = 0; nj < 4; ++nj) {
            bvf[nj] = fc1b[nj * 16 + frow];
            f2[nj] = fc2w[nj * 16 + frow];
        }
        float part[2][4];
#pragma unroll
        for (int mi = 0; mi < 2; ++mi)
#pragma unroll
            for (int r = 0; r < 4; ++r) part[mi][r] = 0.f;
#pragma unroll
        for (int mi = 0; mi < 2; ++mi)
#pragma unroll
            for (int nj = 0; nj < 4; ++nj)
#pragma unroll
                for (int r = 0; r < 4; ++r)
                    part[mi][r] += fmaxf(acc3[mi][nj][r] + bvf[nj], 0.f) * f2[nj];
#pragma unroll
        for (int mi = 0; mi < 2; ++mi)
#pragma unroll
            for (int r = 0; r < 4; ++r)
                Red[(w * 32 + mi * 16 + kgrp * 4 + r) * 17 + frow] = part[mi][r];
        __syncthreads();
        if (tid < 128) {
            float s = fc2b[0];
#pragma unroll
            for (int q = 0; q < 16; ++q) s += Red[tid * 17 + q];
            int m = m0 + tid;
            if (m < M) out[m] = 1.f / (1.f + expf(-s));
        }
    }
}

// ---------------------------------------------------------------------------
extern "C" void kernel_launch(void* const* d_in, const int* in_sizes, int n_in,
                              void* d_out, int out_size, void* d_ws, size_t ws_size,
                              hipStream_t stream) {
    const float* x = (const float*)d_in[0];
    const int* ei = (const int*)d_in[1];
    const int N = in_sizes[0] / 128;
    const int E = in_sizes[1] / 2;
    const int* srcIdx = ei;
    const int* dstIdx = ei + E;

    const float* w1[3] = {(const float*)d_in[2], (const float*)d_in[7], (const float*)d_in[12]};
    const float* b1[3] = {(const float*)d_in[3], (const float*)d_in[8], (const float*)d_in[13]};
    const float* w2[3] = {(const float*)d_in[4], (const float*)d_in[9], (const float*)d_in[14]};
    const float* b2[3] = {(const float*)d_in[5], (const float*)d_in[10], (const float*)d_in[15]};
    const float* eps[3] = {(const float*)d_in[6], (const float*)d_in[11], (const float*)d_in[16]};
    const float* fc1w = (const float*)d_in[17];
    const float* fc1b = (const float*)d_in[18];
    const float* fc2w = (const float*)d_in[19];
    const float* fc2b = (const float*)d_in[20];

    // workspace carve
    char* ws = (char*)d_ws;
    size_t p = 0;
    auto carve = [&](size_t bytes) -> char* {
        char* r = ws + p;
        p = (p + bytes + 255) & ~(size_t)255;
        return r;
    };
    const int nbuck = (N + 255) >> 8;          // 256-node buckets
    const int nm = nbuck * BINBLK;             // count-matrix size
    int* offs = (int*)carve((size_t)(N + 1) * 4);
    int* col = (int*)carve((size_t)E * 4);
    int* cntM = (int*)carve((size_t)nm * 4);
    int* baseM = (int*)carve((size_t)nm * 4);
    int* baseM2 = (int*)carve((size_t)nm * 4);  // scan scratch (unused copy)
    int* bsum = (int*)carve(128 * 4);
    int* bbase = (int*)carve(128 * 4);
    int* tot = (int*)carve(4);
    int2* stage = (int2*)carve((size_t)E * 8);
    f16* H0 = (f16*)carve((size_t)N * 128 * 2);
    f16* H1 = (f16*)carve((size_t)N * 128 * 2);
    f16* Z = (f16*)carve((size_t)N * 128 * 2);
    f16* w1f[3], *w2f[3];
    for (int i = 0; i < 3; ++i) {
        w1f[i] = (f16*)carve(128 * 128 * 2);
        w2f[i] = (f16*)carve(128 * 128 * 2);
    }
    f16* fc1wf = (f16*)carve(64 * 128 * 2);
    (void)ws_size;

    // ---- build CSR (deterministic two-level binning) ----
    const int SB2 = (nm + 1023) / 1024;  // <=128 for nbuck*256 <= 128K
    bucket_count_kernel<<<BINBLK, 512, 0, stream>>>(dstIdx, cntM, E, nbuck);
    scan_partial<<<SB2, 256, 0, stream>>>(cntM, bsum, nm);
    scan_bsum<<<1, 128, 0, stream>>>(bsum, bbase, SB2, tot);
    scan_final<<<SB2, 256, 0, stream>>>(cntM, bbase, baseM, baseM2, nm);
    bin_kernel<<<BINBLK, 512, 0, stream>>>(srcIdx, dstIdx, baseM, stage, E, nbuck);
    csr_kernel<<<nbuck, 256, 0, stream>>>(stage, baseM, offs, col, E, N, nbuck, BINBLK);

    // ---- fp32 -> f16: x and all MFMA weights ----
    cvt4_kernel<<<2048, 256, 0, stream>>>(x, H0, N * 128 / 4);
    CvtPack cp;
    for (int i = 0; i < 3; ++i) {
        cp.s[i] = w1[i];     cp.d[i] = w1f[i];     cp.nq[i] = 128 * 128 / 4;
        cp.s[3 + i] = w2[i]; cp.d[3 + i] = w2f[i]; cp.nq[3 + i] = 128 * 128 / 4;
    }
    cp.s[6] = fc1w; cp.d[6] = fc1wf; cp.nq[6] = 64 * 128 / 4;
    cvt_pack_kernel<<<dim3(16, 7), 256, 0, stream>>>(cp);

    const int aggGrid = (N + 31) / 32;  // 32 nodes per block (8 lanes/node)
    const int gemmGrid = (N + 127) / 128;

    // conv0: H0 -> Z -> H1 ; conv1: H1 -> Z -> H0 ; conv2: H0 -> Z -> out
    agg_kernel<<<aggGrid, 256, 0, stream>>>(H0, offs, col, eps[0], Z, N);
    conv_mlp_kernel<false><<<gemmGrid, 256, 0, stream>>>(
        Z, w1f[0], b1[0], w2f[0], b2[0], H1, N, nullptr, nullptr, nullptr, nullptr, nullptr);
    agg_kernel<<<aggGrid, 256, 0, stream>>>(H1, offs, col, eps[1], Z, N);
    conv_mlp_kernel<false><<<gemmGrid, 256, 0, stream>>>(
        Z, w1f[1], b1[1], w2f[1], b2[1], H0, N, nullptr, nullptr, nullptr, nullptr, nullptr);
    agg_kernel<<<aggGrid, 256, 0, stream>>>(H0, offs, col, eps[2], Z, N);
    conv_mlp_kernel<true><<<gemmGrid, 256, 0, stream>>>(
        Z, w1f[2], b1[2], w2f[2], b2[2], nullptr, N, fc1wf, fc1b, fc2w, fc2b, (float*)d_out);
}